// Round 2
// baseline (1334.547 us; speedup 1.0000x reference)
//
#include <hip/hip_runtime.h>
#include <hip/hip_bf16.h>

#define NV 8192
#define NF 4096
#define NM 12288
#define PFX 3
#define DOM 16
#define EMB 61
#define NN 36864
#define EE 262144
#define GG 8192
#define KK 16
#define OUT0 524288

typedef __hip_bfloat16 bf16;
__device__ __forceinline__ float b2f(bf16 x) { return __bfloat162float(x); }
__device__ __forceinline__ float lrelu(float x, float s) { return x > 0.f ? x : s * x; }
__device__ __forceinline__ float sigm(float x) { return 1.f / (1.f + expf(-x)); }
// flag-dispatched load/store: f=1 -> float32 buffers, f=0 -> bf16 buffers
__device__ __forceinline__ float LD(const void* p, int i, int f) {
  return f ? ((const float*)p)[i] : b2f(((const bf16*)p)[i]);
}
__device__ __forceinline__ void ST(void* p, int i, int f, float v) {
  if (f) ((float*)p)[i] = v; else ((bf16*)p)[i] = __float2bfloat16(v);
}
__device__ __forceinline__ int MK(const void* p, int i, int bytey) {
  return bytey ? (int)((const signed char*)p)[i] : ((const int*)p)[i];
}

// -------- dtype detector: flags[0]=floats are f32, flags[1]=mask is byte-bool --------
__global__ void k_detect(const void* fn, const void* mask, int* flags) {
  if (threadIdx.x || blockIdx.x) return;
  int wild = 0;
  const bf16* h = (const bf16*)fn;
  for (int i = 0; i < 128; ++i) {
    float x = b2f(h[i]);
    float a = fabsf(x);
    if (a != a || a > 1e4f || (x != 0.f && a < 1e-8f)) ++wild;
  }
  flags[0] = (wild >= 8) ? 1 : 0;
  const int* mi = (const int*)mask;
  int bytey = 0;
  for (int i = 0; i < 64; ++i) {
    unsigned v = (unsigned)mi[i];
    if (v > 1u) bytey = 1;
  }
  flags[1] = bytey;
}

// ---------------- GRU (both directions in one kernel) ----------------
__global__ void k_gru(const void* v2f_msgs, const void* v2f_hid,
                      const void* f2v_msgs, const void* f2v_hid,
                      const void* gv_wih, const void* gv_whh, const void* gv_bih, const void* gv_bhh,
                      const void* gf_wih, const void* gf_whh, const void* gf_bih, const void* gf_bhh,
                      float* hidcat, void* outv, const int* flg) {
  int f = flg[0];
  int b = blockIdx.x;          // 0..2*NM-1
  int lane = threadIdx.x;      // 64
  int half = b >= NM;
  int row = half ? b - NM : b;
  const void* msgs = half ? f2v_msgs : v2f_msgs;
  const void* hidp = half ? f2v_hid : v2f_hid;
  const void* wih = half ? gf_wih : gv_wih;
  const void* whh = half ? gf_whh : gv_whh;
  const void* bih = half ? gf_bih : gv_bih;
  const void* bhh = half ? gf_bhh : gv_bhh;
  __shared__ float xr[DOM], hr[EMB];
  if (lane < DOM) xr[lane] = LD(msgs, row * DOM + lane, f);
  if (lane < EMB) hr[lane] = LD(hidp, row * EMB + lane, f);
  __syncthreads();
  if (lane < EMB) {
    int j = lane;
    float gir = LD(bih, j, f), giz = LD(bih, EMB + j, f), gin = LD(bih, 2 * EMB + j, f);
    for (int d = 0; d < DOM; ++d) {
      float xv = xr[d];
      gir += xv * LD(wih, j * DOM + d, f);
      giz += xv * LD(wih, (EMB + j) * DOM + d, f);
      gin += xv * LD(wih, (2 * EMB + j) * DOM + d, f);
    }
    float ghr = LD(bhh, j, f), ghz = LD(bhh, EMB + j, f), ghn = LD(bhh, 2 * EMB + j, f);
    for (int d = 0; d < EMB; ++d) {
      float hv = hr[d];
      ghr += hv * LD(whh, j * EMB + d, f);
      ghz += hv * LD(whh, (EMB + j) * EMB + d, f);
      ghn += hv * LD(whh, (2 * EMB + j) * EMB + d, f);
    }
    float r = sigm(gir + ghr);
    float z = sigm(giz + ghz);
    float n = tanhf(gin + r * ghn);
    float hn = (1.f - z) * n + z * hr[j];
    hidcat[b * EMB + j] = hn;
    ST(outv, OUT0 + b * EMB + j, f, hn);
  }
}

// ---------------- assemble x (NN x 64 fp32) ----------------
__global__ void k_assemble(const void* vn_prefix, const int* vn_colors, const void* emb,
                           const void* fn_embed, const void* msg_prefix,
                           const float* hidcat, float* x, const int* flg) {
  int f = flg[0];
  int t = blockIdx.x * blockDim.x + threadIdx.x;
  if (t >= NN * 64) return;
  int i = t >> 6, c = t & 63;
  float v;
  if (i < NV) {
    v = (c < PFX) ? LD(vn_prefix, i * PFX + c, f) : LD(emb, vn_colors[i] * EMB + (c - PFX), f);
  } else if (i < NV + NF) {
    v = LD(fn_embed, (i - NV) * 64 + c, f);
  } else {
    int j = i - NV - NF;
    v = (c < PFX) ? LD(msg_prefix, j * PFX + c, f) : hidcat[j * EMB + (c - PFX)];
  }
  x[t] = v;
}

// ---------------- CSR build (by dst) ----------------
__global__ void k_deg(const int* dst, int* deg) {
  int e = blockIdx.x * blockDim.x + threadIdx.x;
  if (e < EE) atomicAdd(&deg[dst[e]], 1);
}
__global__ void k_scan1(const int* deg, int* rowptr, int* bsum) {
  __shared__ int s[512];
  int g = blockIdx.x * 512 + threadIdx.x;
  int v = (g < NN) ? deg[g] : 0;
  s[threadIdx.x] = v;
  __syncthreads();
  for (int off = 1; off < 512; off <<= 1) {
    int t = (threadIdx.x >= off) ? s[threadIdx.x - off] : 0;
    __syncthreads();
    s[threadIdx.x] += t;
    __syncthreads();
  }
  if (g < NN) rowptr[g] = s[threadIdx.x] - v;
  if (threadIdx.x == 511) bsum[blockIdx.x] = s[511];
}
__global__ void k_scan2(const int* bsum, int* boff, int nb) {
  __shared__ int s[128];
  int v = (threadIdx.x < nb) ? bsum[threadIdx.x] : 0;
  s[threadIdx.x] = v;
  __syncthreads();
  for (int off = 1; off < 128; off <<= 1) {
    int t = (threadIdx.x >= off) ? s[threadIdx.x - off] : 0;
    __syncthreads();
    s[threadIdx.x] += t;
    __syncthreads();
  }
  if (threadIdx.x < nb) boff[threadIdx.x] = s[threadIdx.x] - v;
}
__global__ void k_scan3(int* rowptr, const int* boff) {
  int g = blockIdx.x * blockDim.x + threadIdx.x;
  if (g < NN) rowptr[g] += boff[g >> 9];
  if (g == 0) rowptr[NN] = EE;
}
__global__ void k_fill(const int* src, const int* dst, const int* rowptr, int* cnt, int* col) {
  int e = blockIdx.x * blockDim.x + threadIdx.x;
  if (e < EE) {
    int d = dst[e];
    int pos = rowptr[d] + atomicAdd(&cnt[d], 1);
    col[pos] = src[e];
  }
}

// ---------------- xl = x @ W (IC -> 32), W staged in LDS ----------------
template <int IC>
__global__ void k_xl(const float* x, const void* W, float* xl, int n, const int* flg) {
  int f = flg[0];
  __shared__ float Wl[IC * 32];
  for (int t = threadIdx.x; t < IC * 32; t += blockDim.x) Wl[t] = LD(W, t, f);
  __syncthreads();
  int j = threadIdx.x & 31;
  int r = threadIdx.x >> 5;
  int i = blockIdx.x * 8 + r;
  if (i >= n) return;
  const float* xr = x + (size_t)i * IC;
  float acc = 0.f;
  for (int k = 0; k < IC; ++k) acc += xr[k] * Wl[k * 32 + j];
  xl[i * 32 + j] = acc;
}

// ---------------- attention coefficients ----------------
__global__ void k_coef13(const float* xl, const void* as_, const void* ad_,
                         float* a_s, float* a_d, const int* flg) {
  int f = flg[0];
  int t = blockIdx.x * blockDim.x + threadIdx.x;
  if (t >= NN * 4) return;
  int i = t >> 2, h = t & 3;
  float ss = 0.f, dd = 0.f;
  for (int c = 0; c < 8; ++c) {
    float v = xl[i * 32 + h * 8 + c];
    ss += v * LD(as_, h * 8 + c, f);
    dd += v * LD(ad_, h * 8 + c, f);
  }
  a_s[t] = ss;
  a_d[t] = dd;
}
__global__ void k_waSD(const void* W4, const void* a4s, const void* a4d, float* waS, float* waD,
                       const int* flg) {
  int f = flg[0];
  int t = threadIdx.x;  // 256
  int isD = t >= 128;
  int u = t & 127;
  int h = u >> 5, k = u & 31;
  const void* av = isD ? a4d : a4s;
  float acc = 0.f;
  for (int c = 0; c < 64; ++c) acc += LD(W4, k * 256 + h * 64 + c, f) * LD(av, h * 64 + c, f);
  (isD ? waD : waS)[h * 32 + k] = acc;
}
__global__ void k_coef4(const float* x, const float* waS, const float* waD, float* a_s, float* a_d) {
  int t = blockIdx.x * blockDim.x + threadIdx.x;
  if (t >= NN * 4) return;
  int i = t >> 2, h = t & 3;
  float ss = 0.f, dd = 0.f;
  for (int k = 0; k < 32; ++k) {
    float v = x[i * 32 + k];
    ss += v * waS[h * 32 + k];
    dd += v * waD[h * 32 + k];
  }
  a_s[t] = ss;
  a_d[t] = dd;
}

// ---------------- GAT gather, layers 1-3 (concat, ch=8) ----------------
__global__ void k_gather13(const int* rowptr, const int* col, const float* a_s, const float* a_d,
                           const float* xl, const void* bias, float* xout, const int* flg) {
  int f = flg[0];
  int i = blockIdx.x;
  int lane = threadIdx.x;
  int beg = rowptr[i], end = rowptr[i + 1];
  float ad[4], es[4], mx[4];
  for (int h = 0; h < 4; ++h) ad[h] = a_d[i * 4 + h];
  for (int h = 0; h < 4; ++h) {
    float e = a_s[i * 4 + h] + ad[h];
    es[h] = lrelu(e, 0.2f);
    mx[h] = es[h];
  }
  for (int p = beg + lane; p < end; p += 64) {
    int j = col[p];
    for (int h = 0; h < 4; ++h) {
      float e = lrelu(a_s[j * 4 + h] + ad[h], 0.2f);
      mx[h] = fmaxf(mx[h], e);
    }
  }
  for (int off = 1; off < 64; off <<= 1)
    for (int h = 0; h < 4; ++h) mx[h] = fmaxf(mx[h], __shfl_xor(mx[h], off));
  float den[4];
  for (int h = 0; h < 4; ++h) den[h] = expf(es[h] - mx[h]);  // self contribution
  int hl = (lane >> 3) & 3;
  float acc = 0.f;
  if (lane < 32) acc = den[hl] * xl[i * 32 + lane];
  for (int p = beg; p < end; ++p) {
    int j = col[p];
    float ex[4];
    for (int h = 0; h < 4; ++h) {
      float e = lrelu(a_s[j * 4 + h] + ad[h], 0.2f);
      ex[h] = expf(e - mx[h]);
      den[h] += ex[h];
    }
    if (lane < 32) acc += ex[hl] * xl[j * 32 + lane];
  }
  if (lane < 32) {
    float v = acc / den[hl] + LD(bias, lane, f);
    xout[i * 32 + lane] = lrelu(v, 0.01f);
  }
}

// ---------------- GAT gather, layer 4: aggregate x rows per head ----------------
__global__ void k_gather4(const int* rowptr, const int* col, const float* a_s, const float* a_d,
                          const float* x, float* agg) {
  int i = blockIdx.x;
  int lane = threadIdx.x;
  int kk = lane & 31;
  int h0 = lane >> 5;  // 0/1
  int h1 = h0 + 2;
  int beg = rowptr[i], end = rowptr[i + 1];
  float ad[4], es[4], mx[4];
  for (int h = 0; h < 4; ++h) ad[h] = a_d[i * 4 + h];
  for (int h = 0; h < 4; ++h) {
    float e = a_s[i * 4 + h] + ad[h];
    es[h] = lrelu(e, 0.2f);
    mx[h] = es[h];
  }
  for (int p = beg + lane; p < end; p += 64) {
    int j = col[p];
    for (int h = 0; h < 4; ++h) {
      float e = lrelu(a_s[j * 4 + h] + ad[h], 0.2f);
      mx[h] = fmaxf(mx[h], e);
    }
  }
  for (int off = 1; off < 64; off <<= 1)
    for (int h = 0; h < 4; ++h) mx[h] = fmaxf(mx[h], __shfl_xor(mx[h], off));
  float den[4];
  for (int h = 0; h < 4; ++h) den[h] = expf(es[h] - mx[h]);
  float xv = x[i * 32 + kk];
  float acc0 = den[h0] * xv;
  float acc1 = den[h1] * xv;
  for (int p = beg; p < end; ++p) {
    int j = col[p];
    float ex[4];
    for (int h = 0; h < 4; ++h) {
      float e = lrelu(a_s[j * 4 + h] + ad[h], 0.2f);
      ex[h] = expf(e - mx[h]);
      den[h] += ex[h];
    }
    float xj = x[j * 32 + kk];
    acc0 += ex[h0] * xj;
    acc1 += ex[h1] * xj;
  }
  agg[i * 128 + h0 * 32 + kk] = acc0 / den[h0];
  agg[i * 128 + h1 * 32 + kk] = acc1 / den[h1];
}

// out[i,c] = lrelu( 0.25 * sum_h sum_k agg[i,h,k]*W4[k, h*64+c] + b4[c], 0.01 )
__global__ void k_l4_out(const float* agg, const void* W4, const void* b4, float* xout,
                         const int* flg) {
  int f = flg[0];
  __shared__ float Wl[32 * 256];
  for (int t = threadIdx.x; t < 32 * 256; t += blockDim.x) Wl[t] = LD(W4, t, f);
  __syncthreads();
  int c = threadIdx.x & 63;
  int r = threadIdx.x >> 6;
  int i = blockIdx.x * 4 + r;
  float acc = 0.f;
  for (int h = 0; h < 4; ++h) {
    const float* ag = agg + (size_t)i * 128 + h * 32;
    for (int k = 0; k < 32; ++k) acc += ag[k] * Wl[k * 256 + h * 64 + c];
  }
  float v = 0.25f * acc + LD(b4, c, f);
  xout[i * 64 + c] = lrelu(v, 0.01f);
}

// ---------------- pooling attention head ----------------
__global__ void k_wqk(const void* wq, const void* wk, const void* ws, float* wqv, float* wkv,
                      const int* flg) {
  int f = flg[0];
  int t = threadIdx.x;  // 256
  int h = t >> 6, d = t & 63;
  float q = 0.f, k = 0.f;
  for (int e = 0; e < 64; ++e) {
    q += LD(wq, h * 4096 + d * 64 + e, f) * LD(ws, h * 128 + e, f);
    k += LD(wk, h * 4096 + d * 64 + e, f) * LD(ws, h * 128 + 64 + e, f);
  }
  wqv[h * 64 + d] = q;
  wkv[h * 64 + d] = k;
}
__global__ void k_qk(const float* xfin, const float* wqv, const float* wkv, float* qs, float* ks) {
  int t = blockIdx.x * blockDim.x + threadIdx.x;
  if (t >= NF * 4) return;
  int n = t >> 2, h = t & 3;
  const float* row = xfin + (size_t)(NV + n) * 64;
  float q = 0.f, k = 0.f;
  for (int d = 0; d < 64; ++d) {
    float v = row[d];
    q += v * wqv[h * 64 + d];
    k += v * wkv[h * 64 + d];
  }
  qs[t] = q;
  ks[t] = k;
}

__global__ void k_groups(const int* full, const void* mask, const int* tgt, const int* mult,
                         const float* qs, const float* ks, const void* att_b, void* outv,
                         const int* flg) {
  int f = flg[0], mbyte = flg[1];
  int g = blockIdx.x;
  int lane = threadIdx.x;  // 64 = 16 k * 4 h
  int k = lane >> 2, h = lane & 3;
  int t = tgt[g];
  int idx = full[g * KK + k];
  int mk = MK(mask, g * KK + k, mbyte);
  float bh = LD(att_b, h, f);
  float qt = qs[t * 4 + h];
  float sc = sigm(qt + ks[idx * 4 + h] + bh);
  int is_tgt = (idx == t) && mk;
  int nbr = mk && !is_tgt;
  unsigned long long bal = __ballot(nbr != 0);
  int degm1 = (int)(__popcll(bal) >> 2);
  float ssum = nbr ? sc : 0.f;
  for (int off = 4; off < 64; off <<= 1) ssum += __shfl_xor(ssum, off);
  ssum /= (float)(degm1 > 1 ? degm1 : 1);
  float trg = sigm(qt + ks[t * 4 + h] + bh);
  float mxv = fmaxf(ssum, trg);
  float e0 = expf(ssum - mxv), e1 = expf(trg - mxv);
  float tw0 = e0 / (e0 + e1), tw1 = e1 / (e0 + e1);
  float msc = nbr ? sc : -1e30f;
  float m = msc;
  for (int off = 4; off < 64; off <<= 1) m = fmaxf(m, __shfl_xor(m, off));
  float ex = expf(msc - m);
  float den = ex;
  for (int off = 4; off < 64; off <<= 1) den += __shfl_xor(den, off);
  float w = ex / den * tw0 * (float)mult[g];
  float res = is_tgt ? tw1 : (nbr ? w : 0.f);
  if (degm1 == 0) res = 0.f;
  ST(outv, g * 64 + k * 4 + h, f, res);
}

extern "C" void kernel_launch(void* const* d_in, const int* in_sizes, int n_in,
                              void* d_out, int out_size, void* d_ws, size_t ws_size,
                              hipStream_t stream) {
  const int* edge = (const int*)d_in[0];
  const int* esrc = edge;
  const int* edst = edge + EE;
  const int* vn_colors = (const int*)d_in[1];
  const int* group_full = (const int*)d_in[2];
  const void* group_mask = d_in[3];
  const int* group_tgt = (const int*)d_in[4];
  const int* group_mult = (const int*)d_in[5];
  const void* vn_prefix = d_in[6];
  const void* fn_embed = d_in[7];
  const void* v2f_msgs = d_in[8];
  const void* v2f_hidden = d_in[9];
  const void* f2v_msgs = d_in[10];
  const void* f2v_hidden = d_in[11];
  const void* msg_prefix = d_in[12];
  const void* emb = d_in[13];
  const void* gv_wih = d_in[14];
  const void* gv_whh = d_in[15];
  const void* gv_bih = d_in[16];
  const void* gv_bhh = d_in[17];
  const void* gf_wih = d_in[18];
  const void* gf_whh = d_in[19];
  const void* gf_bih = d_in[20];
  const void* gf_bhh = d_in[21];
  const void* W1 = d_in[22];
  const void* a1s = d_in[23];
  const void* a1d = d_in[24];
  const void* b1 = d_in[25];
  const void* W2 = d_in[26];
  const void* a2s = d_in[27];
  const void* a2d = d_in[28];
  const void* b2 = d_in[29];
  const void* W3 = d_in[30];
  const void* a3s = d_in[31];
  const void* a3d = d_in[32];
  const void* b3 = d_in[33];
  const void* W4 = d_in[34];
  const void* a4s = d_in[35];
  const void* a4d = d_in[36];
  const void* b4 = d_in[37];
  const void* att_wq = d_in[38];
  const void* att_wk = d_in[39];
  const void* att_ws = d_in[40];
  const void* att_b = d_in[41];

  char* w = (char*)d_ws;
  size_t off = 0;
  auto carve = [&](size_t bytes) -> void* {
    void* p = w + off;
    off += (bytes + 255) & ~(size_t)255;
    return p;
  };
  int* flags = (int*)carve(16);
  float* hidcat = (float*)carve((size_t)2 * NM * EMB * 4);
  float* xA = (float*)carve((size_t)NN * 64 * 4);
  float* xB = (float*)carve((size_t)NN * 64 * 4);
  float* scr = (float*)carve((size_t)NN * 128 * 4);  // xl (N x 32) or agg (N x 128)
  float* a_s = (float*)carve((size_t)NN * 4 * 4);
  float* a_d = (float*)carve((size_t)NN * 4 * 4);
  int* deg = (int*)carve((size_t)NN * 4);
  int* rowptr = (int*)carve((size_t)(NN + 1) * 4);
  int* cnt = (int*)carve((size_t)NN * 4);
  int* bsum = (int*)carve(128 * 4);
  int* boff = (int*)carve(128 * 4);
  int* col = (int*)carve((size_t)EE * 4);
  float* qs = (float*)carve((size_t)NF * 4 * 4);
  float* ks = (float*)carve((size_t)NF * 4 * 4);
  float* wqv = (float*)carve(256 * 4);
  float* wkv = (float*)carve(256 * 4);
  float* waS = (float*)carve(128 * 4);
  float* waD = (float*)carve(128 * 4);

  hipMemsetAsync(deg, 0, (size_t)NN * 4, stream);
  hipMemsetAsync(cnt, 0, (size_t)NN * 4, stream);

  k_detect<<<1, 64, 0, stream>>>(fn_embed, group_mask, flags);
  k_gru<<<2 * NM, 64, 0, stream>>>(v2f_msgs, v2f_hidden, f2v_msgs, f2v_hidden,
                                   gv_wih, gv_whh, gv_bih, gv_bhh,
                                   gf_wih, gf_whh, gf_bih, gf_bhh, hidcat, d_out, flags);
  k_assemble<<<(NN * 64) / 256, 256, 0, stream>>>(vn_prefix, vn_colors, emb, fn_embed,
                                                  msg_prefix, hidcat, xA, flags);
  k_deg<<<EE / 256, 256, 0, stream>>>(edst, deg);
  k_scan1<<<72, 512, 0, stream>>>(deg, rowptr, bsum);
  k_scan2<<<1, 128, 0, stream>>>(bsum, boff, 72);
  k_scan3<<<(NN + 256) / 256, 256, 0, stream>>>(rowptr, boff);
  k_fill<<<EE / 256, 256, 0, stream>>>(esrc, edst, rowptr, cnt, col);

  // L1: 64 -> 32
  k_xl<64><<<NN / 8, 256, 0, stream>>>(xA, W1, scr, NN, flags);
  k_coef13<<<NN * 4 / 256, 256, 0, stream>>>(scr, a1s, a1d, a_s, a_d, flags);
  k_gather13<<<NN, 64, 0, stream>>>(rowptr, col, a_s, a_d, scr, b1, xB, flags);
  // L2: 32 -> 32
  k_xl<32><<<NN / 8, 256, 0, stream>>>(xB, W2, scr, NN, flags);
  k_coef13<<<NN * 4 / 256, 256, 0, stream>>>(scr, a2s, a2d, a_s, a_d, flags);
  k_gather13<<<NN, 64, 0, stream>>>(rowptr, col, a_s, a_d, scr, b2, xA, flags);
  // L3: 32 -> 32
  k_xl<32><<<NN / 8, 256, 0, stream>>>(xA, W3, scr, NN, flags);
  k_coef13<<<NN * 4 / 256, 256, 0, stream>>>(scr, a3s, a3d, a_s, a_d, flags);
  k_gather13<<<NN, 64, 0, stream>>>(rowptr, col, a_s, a_d, scr, b3, xB, flags);
  // L4: 32 -> (4 heads x 64), mean
  k_waSD<<<1, 256, 0, stream>>>(W4, a4s, a4d, waS, waD, flags);
  k_coef4<<<NN * 4 / 256, 256, 0, stream>>>(xB, waS, waD, a_s, a_d);
  k_gather4<<<NN, 64, 0, stream>>>(rowptr, col, a_s, a_d, xB, scr);
  k_l4_out<<<NN / 4, 256, 0, stream>>>(scr, W4, b4, xA, flags);

  k_wqk<<<1, 256, 0, stream>>>(att_wq, att_wk, att_ws, wqv, wkv, flags);
  k_qk<<<(NF * 4) / 256, 256, 0, stream>>>(xA, wqv, wkv, qs, ks);
  k_groups<<<GG, 64, 0, stream>>>(group_full, group_mask, group_tgt, group_mult,
                                  qs, ks, att_b, d_out, flags);
}

// Round 3
// 829.830 us; speedup vs baseline: 1.6082x; 1.6082x over previous
//
#include <hip/hip_runtime.h>
#include <hip/hip_bf16.h>

#define NV 8192
#define NF 4096
#define NM 12288
#define PFX 3
#define DOM 16
#define EMB 61
#define NN 36864
#define EE 262144
#define GG 8192
#define KK 16
#define OUT0 524288

typedef __hip_bfloat16 bf16;
__device__ __forceinline__ float b2f(bf16 x) { return __bfloat162float(x); }
__device__ __forceinline__ float lrelu(float x, float s) { return x > 0.f ? x : s * x; }
__device__ __forceinline__ float sigm(float x) { return 1.f / (1.f + expf(-x)); }
// flag-dispatched load/store: f=1 -> float32 buffers, f=0 -> bf16 buffers
__device__ __forceinline__ float LD(const void* p, int i, int f) {
  return f ? ((const float*)p)[i] : b2f(((const bf16*)p)[i]);
}
__device__ __forceinline__ void ST(void* p, int i, int f, float v) {
  if (f) ((float*)p)[i] = v; else ((bf16*)p)[i] = __float2bfloat16(v);
}
__device__ __forceinline__ int MK(const void* p, int i, int bytey) {
  return bytey ? (int)((const signed char*)p)[i] : ((const int*)p)[i];
}

// -------- dtype detector: flags[0]=floats are f32, flags[1]=mask is byte-bool --------
__global__ void k_detect(const void* fn, const void* mask, int* flags) {
  if (threadIdx.x || blockIdx.x) return;
  int wild = 0;
  const bf16* h = (const bf16*)fn;
  for (int i = 0; i < 128; ++i) {
    float x = b2f(h[i]);
    float a = fabsf(x);
    if (a != a || a > 1e4f || (x != 0.f && a < 1e-8f)) ++wild;
  }
  flags[0] = (wild >= 8) ? 1 : 0;
  const int* mi = (const int*)mask;
  int bytey = 0;
  for (int i = 0; i < 64; ++i) {
    unsigned v = (unsigned)mi[i];
    if (v > 1u) bytey = 1;
  }
  flags[1] = bytey;
}

// -------- transpose GRU weights into Wt[dir][d][192] (d-major, o padded 183->192) --------
__global__ void k_wtr(const void* gv_wih, const void* gv_whh,
                      const void* gf_wih, const void* gf_whh, float* Wt, const int* flg) {
  int f = flg[0];
  int t = blockIdx.x * blockDim.x + threadIdx.x;
  if (t >= 2 * 77 * 192) return;
  int dir = t / (77 * 192);
  int rem = t - dir * 77 * 192;
  int d = rem / 192, o = rem - d * 192;
  const void* wih = dir ? gf_wih : gv_wih;
  const void* whh = dir ? gf_whh : gv_whh;
  float v = 0.f;
  if (o < 183) v = (d < 16) ? LD(wih, o * 16 + d, f) : LD(whh, o * 61 + (d - 16), f);
  Wt[t] = v;
}

// ---------------- GRU v2: register-tiled, 64 rows/block ----------------
// thread (og,rg): outputs o0=og*12..+11, rows r0=rg*4..+3
__global__ __launch_bounds__(256) void k_gru2(
    const void* v2f_msgs, const void* v2f_hid, const void* f2v_msgs, const void* f2v_hid,
    const void* gv_bih, const void* gv_bhh, const void* gf_bih, const void* gf_bhh,
    const float* Wt, float* hidcat, void* outv, const int* flg) {
  int f = flg[0];
  int blk = blockIdx.x;
  int dir = blk >= 192;
  int loc = dir ? blk - 192 : blk;
  int gr0 = loc * 64;
  const void* msgs = dir ? f2v_msgs : v2f_msgs;
  const void* hid = dir ? f2v_hid : v2f_hid;
  const void* bih = dir ? gf_bih : gv_bih;
  const void* bhh = dir ? gf_bhh : gv_bhh;
  const float* W = Wt + dir * 77 * 192;

  // LDS: F[77][64] (19712B) lives at start, dead after accumulate;
  // then G1[64][183] (46848B) + G2[64][61] (15616B) reuse the whole buffer.
  __shared__ float smem[15616];  // 62464 B
  float* F = smem;
  float* G1 = smem;                 // [r*183 + o], o in [0,183)
  float* G2 = smem + 64 * 183;      // [r*61 + j]

  int tid = threadIdx.x;
  // stage F: x part [d<16], h part [16+d]
  for (int idx = tid; idx < 64 * 16; idx += 256) {
    int r = idx >> 4, d = idx & 15;
    F[d * 64 + r] = LD(msgs, (gr0 + r) * DOM + d, f);
  }
  for (int idx = tid; idx < 64 * 61; idx += 256) {
    int r = idx / 61, d = idx - r * 61;
    F[(16 + d) * 64 + r] = LD(hid, gr0 * 61 + idx, f);
  }
  __syncthreads();

  int og = tid & 15, rg = tid >> 4;
  int o0 = og * 12, r0 = rg * 4;
  float accA[48], accB[48];
#pragma unroll
  for (int i = 0; i < 48; ++i) { accA[i] = 0.f; accB[i] = 0.f; }

#pragma unroll 2
  for (int d = 0; d < 16; ++d) {
    const float4 fv4 = *(const float4*)&F[d * 64 + r0];
    const float4 w0 = *(const float4*)&W[d * 192 + o0];
    const float4 w1 = *(const float4*)&W[d * 192 + o0 + 4];
    const float4 w2 = *(const float4*)&W[d * 192 + o0 + 8];
    float fv[4] = {fv4.x, fv4.y, fv4.z, fv4.w};
    float wv[12] = {w0.x, w0.y, w0.z, w0.w, w1.x, w1.y, w1.z, w1.w, w2.x, w2.y, w2.z, w2.w};
#pragma unroll
    for (int k = 0; k < 12; ++k)
#pragma unroll
      for (int m = 0; m < 4; ++m) accA[k * 4 + m] += wv[k] * fv[m];
  }
#pragma unroll 2
  for (int d = 16; d < 77; ++d) {
    const float4 fv4 = *(const float4*)&F[d * 64 + r0];
    const float4 w0 = *(const float4*)&W[d * 192 + o0];
    const float4 w1 = *(const float4*)&W[d * 192 + o0 + 4];
    const float4 w2 = *(const float4*)&W[d * 192 + o0 + 8];
    float fv[4] = {fv4.x, fv4.y, fv4.z, fv4.w};
    float wv[12] = {w0.x, w0.y, w0.z, w0.w, w1.x, w1.y, w1.z, w1.w, w2.x, w2.y, w2.z, w2.w};
#pragma unroll
    for (int k = 0; k < 12; ++k)
#pragma unroll
      for (int m = 0; m < 4; ++m) accB[k * 4 + m] += wv[k] * fv[m];
  }
  __syncthreads();  // F dead; G1/G2 may now overwrite

#pragma unroll
  for (int k = 0; k < 12; ++k) {
    int o = o0 + k;
    if (o < 183) {
      float biv = LD(bih, o, f), bhv = LD(bhh, o, f);
#pragma unroll
      for (int m = 0; m < 4; ++m) {
        int r = r0 + m;
        float gi = accA[k * 4 + m] + biv;
        float gh = accB[k * 4 + m] + bhv;
        if (o < 122) G1[r * 183 + o] = gi + gh;
        else { G1[r * 183 + o] = gi; G2[r * 61 + (o - 122)] = gh; }
      }
    }
  }
  __syncthreads();

  // epilogue: lanes j coalesced
  int j = tid & 63, rq = tid >> 6;
  if (j < 61) {
    for (int rr = 0; rr < 16; ++rr) {
      int r = rq * 16 + rr;
      float gr = sigm(G1[r * 183 + j]);
      float gz = sigm(G1[r * 183 + 61 + j]);
      float gn = tanhf(G1[r * 183 + 122 + j] + gr * G2[r * 61 + j]);
      float hold = LD(hid, (gr0 + r) * 61 + j, f);
      float hn = (1.f - gz) * gn + gz * hold;
      int b = dir * NM + gr0 + r;
      hidcat[b * 61 + j] = hn;
      ST(outv, OUT0 + b * 61 + j, f, hn);
    }
  }
}

// ---------------- assemble x (NN x 64 fp32) ----------------
__global__ void k_assemble(const void* vn_prefix, const int* vn_colors, const void* emb,
                           const void* fn_embed, const void* msg_prefix,
                           const float* hidcat, float* x, const int* flg) {
  int f = flg[0];
  int t = blockIdx.x * blockDim.x + threadIdx.x;
  if (t >= NN * 64) return;
  int i = t >> 6, c = t & 63;
  float v;
  if (i < NV) {
    v = (c < PFX) ? LD(vn_prefix, i * PFX + c, f) : LD(emb, vn_colors[i] * EMB + (c - PFX), f);
  } else if (i < NV + NF) {
    v = LD(fn_embed, (i - NV) * 64 + c, f);
  } else {
    int j = i - NV - NF;
    v = (c < PFX) ? LD(msg_prefix, j * PFX + c, f) : hidcat[j * EMB + (c - PFX)];
  }
  x[t] = v;
}

// ---------------- CSR build (by dst) ----------------
__global__ void k_deg(const int* dst, int* deg) {
  int e = blockIdx.x * blockDim.x + threadIdx.x;
  if (e < EE) atomicAdd(&deg[dst[e]], 1);
}
__global__ void k_scan1(const int* deg, int* rowptr, int* bsum) {
  __shared__ int s[512];
  int g = blockIdx.x * 512 + threadIdx.x;
  int v = (g < NN) ? deg[g] : 0;
  s[threadIdx.x] = v;
  __syncthreads();
  for (int off = 1; off < 512; off <<= 1) {
    int t = (threadIdx.x >= off) ? s[threadIdx.x - off] : 0;
    __syncthreads();
    s[threadIdx.x] += t;
    __syncthreads();
  }
  if (g < NN) rowptr[g] = s[threadIdx.x] - v;
  if (threadIdx.x == 511) bsum[blockIdx.x] = s[511];
}
__global__ void k_scan2(const int* bsum, int* boff, int nb) {
  __shared__ int s[128];
  int v = (threadIdx.x < nb) ? bsum[threadIdx.x] : 0;
  s[threadIdx.x] = v;
  __syncthreads();
  for (int off = 1; off < 128; off <<= 1) {
    int t = (threadIdx.x >= off) ? s[threadIdx.x - off] : 0;
    __syncthreads();
    s[threadIdx.x] += t;
    __syncthreads();
  }
  if (threadIdx.x < nb) boff[threadIdx.x] = s[threadIdx.x] - v;
}
__global__ void k_scan3(int* rowptr, const int* boff) {
  int g = blockIdx.x * blockDim.x + threadIdx.x;
  if (g < NN) rowptr[g] += boff[g >> 9];
  if (g == 0) rowptr[NN] = EE;
}
__global__ void k_fill(const int* src, const int* dst, const int* rowptr, int* cnt, int* col) {
  int e = blockIdx.x * blockDim.x + threadIdx.x;
  if (e < EE) {
    int d = dst[e];
    int pos = rowptr[d] + atomicAdd(&cnt[d], 1);
    col[pos] = src[e];
  }
}

// ---------------- xl = x @ W (IC -> 32), W staged in LDS ----------------
template <int IC>
__global__ void k_xl(const float* x, const void* W, float* xl, int n, const int* flg) {
  int f = flg[0];
  __shared__ float Wl[IC * 32];
  for (int t = threadIdx.x; t < IC * 32; t += blockDim.x) Wl[t] = LD(W, t, f);
  __syncthreads();
  int j = threadIdx.x & 31;
  int r = threadIdx.x >> 5;
  int i = blockIdx.x * 8 + r;
  if (i >= n) return;
  const float* xr = x + (size_t)i * IC;
  float acc = 0.f;
  for (int k = 0; k < IC; ++k) acc += xr[k] * Wl[k * 32 + j];
  xl[i * 32 + j] = acc;
}

// ---------------- attention coefficients ----------------
__global__ void k_coef13(const float* xl, const void* as_, const void* ad_,
                         float* a_s, float* a_d, const int* flg) {
  int f = flg[0];
  int t = blockIdx.x * blockDim.x + threadIdx.x;
  if (t >= NN * 4) return;
  int i = t >> 2, h = t & 3;
  float ss = 0.f, dd = 0.f;
  for (int c = 0; c < 8; ++c) {
    float v = xl[i * 32 + h * 8 + c];
    ss += v * LD(as_, h * 8 + c, f);
    dd += v * LD(ad_, h * 8 + c, f);
  }
  a_s[t] = ss;
  a_d[t] = dd;
}
__global__ void k_waSD(const void* W4, const void* a4s, const void* a4d, float* waS, float* waD,
                       const int* flg) {
  int f = flg[0];
  int t = threadIdx.x;  // 256
  int isD = t >= 128;
  int u = t & 127;
  int h = u >> 5, k = u & 31;
  const void* av = isD ? a4d : a4s;
  float acc = 0.f;
  for (int c = 0; c < 64; ++c) acc += LD(W4, k * 256 + h * 64 + c, f) * LD(av, h * 64 + c, f);
  (isD ? waD : waS)[h * 32 + k] = acc;
}
__global__ void k_coef4(const float* x, const float* waS, const float* waD, float* a_s, float* a_d) {
  int t = blockIdx.x * blockDim.x + threadIdx.x;
  if (t >= NN * 4) return;
  int i = t >> 2, h = t & 3;
  float ss = 0.f, dd = 0.f;
  for (int k = 0; k < 32; ++k) {
    float v = x[i * 32 + k];
    ss += v * waS[h * 32 + k];
    dd += v * waD[h * 32 + k];
  }
  a_s[t] = ss;
  a_d[t] = dd;
}

// ---------------- GAT gather, layers 1-3 (concat, ch=8) ----------------
__global__ void k_gather13(const int* rowptr, const int* col, const float* a_s, const float* a_d,
                           const float* xl, const void* bias, float* xout, const int* flg) {
  int f = flg[0];
  int i = blockIdx.x;
  int lane = threadIdx.x;
  int beg = rowptr[i], end = rowptr[i + 1];
  float ad[4], es[4], mx[4];
  for (int h = 0; h < 4; ++h) ad[h] = a_d[i * 4 + h];
  for (int h = 0; h < 4; ++h) {
    float e = a_s[i * 4 + h] + ad[h];
    es[h] = lrelu(e, 0.2f);
    mx[h] = es[h];
  }
  for (int p = beg + lane; p < end; p += 64) {
    int j = col[p];
    for (int h = 0; h < 4; ++h) {
      float e = lrelu(a_s[j * 4 + h] + ad[h], 0.2f);
      mx[h] = fmaxf(mx[h], e);
    }
  }
  for (int off = 1; off < 64; off <<= 1)
    for (int h = 0; h < 4; ++h) mx[h] = fmaxf(mx[h], __shfl_xor(mx[h], off));
  float den[4];
  for (int h = 0; h < 4; ++h) den[h] = expf(es[h] - mx[h]);  // self contribution
  int hl = (lane >> 3) & 3;
  float acc = 0.f;
  if (lane < 32) acc = den[hl] * xl[i * 32 + lane];
  for (int p = beg; p < end; ++p) {
    int j = col[p];
    float ex[4];
    for (int h = 0; h < 4; ++h) {
      float e = lrelu(a_s[j * 4 + h] + ad[h], 0.2f);
      ex[h] = expf(e - mx[h]);
      den[h] += ex[h];
    }
    if (lane < 32) acc += ex[hl] * xl[j * 32 + lane];
  }
  if (lane < 32) {
    float v = acc / den[hl] + LD(bias, lane, f);
    xout[i * 32 + lane] = lrelu(v, 0.01f);
  }
}

// ---------------- GAT gather, layer 4: aggregate x rows per head ----------------
__global__ void k_gather4(const int* rowptr, const int* col, const float* a_s, const float* a_d,
                          const float* x, float* agg) {
  int i = blockIdx.x;
  int lane = threadIdx.x;
  int kk = lane & 31;
  int h0 = lane >> 5;  // 0/1
  int h1 = h0 + 2;
  int beg = rowptr[i], end = rowptr[i + 1];
  float ad[4], es[4], mx[4];
  for (int h = 0; h < 4; ++h) ad[h] = a_d[i * 4 + h];
  for (int h = 0; h < 4; ++h) {
    float e = a_s[i * 4 + h] + ad[h];
    es[h] = lrelu(e, 0.2f);
    mx[h] = es[h];
  }
  for (int p = beg + lane; p < end; p += 64) {
    int j = col[p];
    for (int h = 0; h < 4; ++h) {
      float e = lrelu(a_s[j * 4 + h] + ad[h], 0.2f);
      mx[h] = fmaxf(mx[h], e);
    }
  }
  for (int off = 1; off < 64; off <<= 1)
    for (int h = 0; h < 4; ++h) mx[h] = fmaxf(mx[h], __shfl_xor(mx[h], off));
  float den[4];
  for (int h = 0; h < 4; ++h) den[h] = expf(es[h] - mx[h]);
  float xv = x[i * 32 + kk];
  float acc0 = den[h0] * xv;
  float acc1 = den[h1] * xv;
  for (int p = beg; p < end; ++p) {
    int j = col[p];
    float ex[4];
    for (int h = 0; h < 4; ++h) {
      float e = lrelu(a_s[j * 4 + h] + ad[h], 0.2f);
      ex[h] = expf(e - mx[h]);
      den[h] += ex[h];
    }
    float xj = x[j * 32 + kk];
    acc0 += ex[h0] * xj;
    acc1 += ex[h1] * xj;
  }
  agg[i * 128 + h0 * 32 + kk] = acc0 / den[h0];
  agg[i * 128 + h1 * 32 + kk] = acc1 / den[h1];
}

// out[i,c] = lrelu( 0.25 * sum_h sum_k agg[i,h,k]*W4[k, h*64+c] + b4[c], 0.01 )
__global__ void k_l4_out(const float* agg, const void* W4, const void* b4, float* xout,
                         const int* flg) {
  int f = flg[0];
  __shared__ float Wl[32 * 256];
  for (int t = threadIdx.x; t < 32 * 256; t += blockDim.x) Wl[t] = LD(W4, t, f);
  __syncthreads();
  int c = threadIdx.x & 63;
  int r = threadIdx.x >> 6;
  int i = blockIdx.x * 4 + r;
  float acc = 0.f;
  for (int h = 0; h < 4; ++h) {
    const float* ag = agg + (size_t)i * 128 + h * 32;
    for (int k = 0; k < 32; ++k) acc += ag[k] * Wl[k * 256 + h * 64 + c];
  }
  float v = 0.25f * acc + LD(b4, c, f);
  xout[i * 64 + c] = lrelu(v, 0.01f);
}

// ---------------- pooling attention head ----------------
__global__ void k_wqk(const void* wq, const void* wk, const void* ws, float* wqv, float* wkv,
                      const int* flg) {
  int f = flg[0];
  int t = threadIdx.x;  // 256
  int h = t >> 6, d = t & 63;
  float q = 0.f, k = 0.f;
  for (int e = 0; e < 64; ++e) {
    q += LD(wq, h * 4096 + d * 64 + e, f) * LD(ws, h * 128 + e, f);
    k += LD(wk, h * 4096 + d * 64 + e, f) * LD(ws, h * 128 + 64 + e, f);
  }
  wqv[h * 64 + d] = q;
  wkv[h * 64 + d] = k;
}
__global__ void k_qk(const float* xfin, const float* wqv, const float* wkv, float* qs, float* ks) {
  int t = blockIdx.x * blockDim.x + threadIdx.x;
  if (t >= NF * 4) return;
  int n = t >> 2, h = t & 3;
  const float* row = xfin + (size_t)(NV + n) * 64;
  float q = 0.f, k = 0.f;
  for (int d = 0; d < 64; ++d) {
    float v = row[d];
    q += v * wqv[h * 64 + d];
    k += v * wkv[h * 64 + d];
  }
  qs[t] = q;
  ks[t] = k;
}

__global__ void k_groups(const int* full, const void* mask, const int* tgt, const int* mult,
                         const float* qs, const float* ks, const void* att_b, void* outv,
                         const int* flg) {
  int f = flg[0], mbyte = flg[1];
  int g = blockIdx.x;
  int lane = threadIdx.x;  // 64 = 16 k * 4 h
  int k = lane >> 2, h = lane & 3;
  int t = tgt[g];
  int idx = full[g * KK + k];
  int mk = MK(mask, g * KK + k, mbyte);
  float bh = LD(att_b, h, f);
  float qt = qs[t * 4 + h];
  float sc = sigm(qt + ks[idx * 4 + h] + bh);
  int is_tgt = (idx == t) && mk;
  int nbr = mk && !is_tgt;
  unsigned long long bal = __ballot(nbr != 0);
  int degm1 = (int)(__popcll(bal) >> 2);
  float ssum = nbr ? sc : 0.f;
  for (int off = 4; off < 64; off <<= 1) ssum += __shfl_xor(ssum, off);
  ssum /= (float)(degm1 > 1 ? degm1 : 1);
  float trg = sigm(qt + ks[t * 4 + h] + bh);
  float mxv = fmaxf(ssum, trg);
  float e0 = expf(ssum - mxv), e1 = expf(trg - mxv);
  float tw0 = e0 / (e0 + e1), tw1 = e1 / (e0 + e1);
  float msc = nbr ? sc : -1e30f;
  float m = msc;
  for (int off = 4; off < 64; off <<= 1) m = fmaxf(m, __shfl_xor(m, off));
  float ex = expf(msc - m);
  float den = ex;
  for (int off = 4; off < 64; off <<= 1) den += __shfl_xor(den, off);
  float w = ex / den * tw0 * (float)mult[g];
  float res = is_tgt ? tw1 : (nbr ? w : 0.f);
  if (degm1 == 0) res = 0.f;
  ST(outv, g * 64 + k * 4 + h, f, res);
}

extern "C" void kernel_launch(void* const* d_in, const int* in_sizes, int n_in,
                              void* d_out, int out_size, void* d_ws, size_t ws_size,
                              hipStream_t stream) {
  const int* edge = (const int*)d_in[0];
  const int* esrc = edge;
  const int* edst = edge + EE;
  const int* vn_colors = (const int*)d_in[1];
  const int* group_full = (const int*)d_in[2];
  const void* group_mask = d_in[3];
  const int* group_tgt = (const int*)d_in[4];
  const int* group_mult = (const int*)d_in[5];
  const void* vn_prefix = d_in[6];
  const void* fn_embed = d_in[7];
  const void* v2f_msgs = d_in[8];
  const void* v2f_hidden = d_in[9];
  const void* f2v_msgs = d_in[10];
  const void* f2v_hidden = d_in[11];
  const void* msg_prefix = d_in[12];
  const void* emb = d_in[13];
  const void* gv_wih = d_in[14];
  const void* gv_whh = d_in[15];
  const void* gv_bih = d_in[16];
  const void* gv_bhh = d_in[17];
  const void* gf_wih = d_in[18];
  const void* gf_whh = d_in[19];
  const void* gf_bih = d_in[20];
  const void* gf_bhh = d_in[21];
  const void* W1 = d_in[22];
  const void* a1s = d_in[23];
  const void* a1d = d_in[24];
  const void* b1 = d_in[25];
  const void* W2 = d_in[26];
  const void* a2s = d_in[27];
  const void* a2d = d_in[28];
  const void* b2 = d_in[29];
  const void* W3 = d_in[30];
  const void* a3s = d_in[31];
  const void* a3d = d_in[32];
  const void* b3 = d_in[33];
  const void* W4 = d_in[34];
  const void* a4s = d_in[35];
  const void* a4d = d_in[36];
  const void* b4 = d_in[37];
  const void* att_wq = d_in[38];
  const void* att_wk = d_in[39];
  const void* att_ws = d_in[40];
  const void* att_b = d_in[41];

  char* w = (char*)d_ws;
  size_t off = 0;
  auto carve = [&](size_t bytes) -> void* {
    void* p = w + off;
    off += (bytes + 255) & ~(size_t)255;
    return p;
  };
  int* flags = (int*)carve(16);
  float* Wt = (float*)carve((size_t)2 * 77 * 192 * 4);
  float* hidcat = (float*)carve((size_t)2 * NM * EMB * 4);
  float* xA = (float*)carve((size_t)NN * 64 * 4);
  float* xB = (float*)carve((size_t)NN * 64 * 4);
  float* scr = (float*)carve((size_t)NN * 128 * 4);  // xl (N x 32) or agg (N x 128)
  float* a_s = (float*)carve((size_t)NN * 4 * 4);
  float* a_d = (float*)carve((size_t)NN * 4 * 4);
  int* deg = (int*)carve((size_t)NN * 4);
  int* rowptr = (int*)carve((size_t)(NN + 1) * 4);
  int* cnt = (int*)carve((size_t)NN * 4);
  int* bsum = (int*)carve(128 * 4);
  int* boff = (int*)carve(128 * 4);
  int* col = (int*)carve((size_t)EE * 4);
  float* qs = (float*)carve((size_t)NF * 4 * 4);
  float* ks = (float*)carve((size_t)NF * 4 * 4);
  float* wqv = (float*)carve(256 * 4);
  float* wkv = (float*)carve(256 * 4);
  float* waS = (float*)carve(128 * 4);
  float* waD = (float*)carve(128 * 4);

  hipMemsetAsync(deg, 0, (size_t)NN * 4, stream);
  hipMemsetAsync(cnt, 0, (size_t)NN * 4, stream);

  k_detect<<<1, 64, 0, stream>>>(fn_embed, group_mask, flags);
  k_wtr<<<(2 * 77 * 192 + 255) / 256, 256, 0, stream>>>(gv_wih, gv_whh, gf_wih, gf_whh, Wt, flags);
  k_gru2<<<384, 256, 0, stream>>>(v2f_msgs, v2f_hidden, f2v_msgs, f2v_hidden,
                                  gv_bih, gv_bhh, gf_bih, gf_bhh, Wt, hidcat, d_out, flags);
  k_assemble<<<(NN * 64) / 256, 256, 0, stream>>>(vn_prefix, vn_colors, emb, fn_embed,
                                                  msg_prefix, hidcat, xA, flags);
  k_deg<<<EE / 256, 256, 0, stream>>>(edst, deg);
  k_scan1<<<72, 512, 0, stream>>>(deg, rowptr, bsum);
  k_scan2<<<1, 128, 0, stream>>>(bsum, boff, 72);
  k_scan3<<<(NN + 256) / 256, 256, 0, stream>>>(rowptr, boff);
  k_fill<<<EE / 256, 256, 0, stream>>>(esrc, edst, rowptr, cnt, col);

  // L1: 64 -> 32
  k_xl<64><<<NN / 8, 256, 0, stream>>>(xA, W1, scr, NN, flags);
  k_coef13<<<NN * 4 / 256, 256, 0, stream>>>(scr, a1s, a1d, a_s, a_d, flags);
  k_gather13<<<NN, 64, 0, stream>>>(rowptr, col, a_s, a_d, scr, b1, xB, flags);
  // L2: 32 -> 32
  k_xl<32><<<NN / 8, 256, 0, stream>>>(xB, W2, scr, NN, flags);
  k_coef13<<<NN * 4 / 256, 256, 0, stream>>>(scr, a2s, a2d, a_s, a_d, flags);
  k_gather13<<<NN, 64, 0, stream>>>(rowptr, col, a_s, a_d, scr, b2, xA, flags);
  // L3: 32 -> 32
  k_xl<32><<<NN / 8, 256, 0, stream>>>(xA, W3, scr, NN, flags);
  k_coef13<<<NN * 4 / 256, 256, 0, stream>>>(scr, a3s, a3d, a_s, a_d, flags);
  k_gather13<<<NN, 64, 0, stream>>>(rowptr, col, a_s, a_d, scr, b3, xB, flags);
  // L4: 32 -> (4 heads x 64), mean
  k_waSD<<<1, 256, 0, stream>>>(W4, a4s, a4d, waS, waD, flags);
  k_coef4<<<NN * 4 / 256, 256, 0, stream>>>(xB, waS, waD, a_s, a_d);
  k_gather4<<<NN, 64, 0, stream>>>(rowptr, col, a_s, a_d, xB, scr);
  k_l4_out<<<NN / 4, 256, 0, stream>>>(scr, W4, b4, xA, flags);

  k_wqk<<<1, 256, 0, stream>>>(att_wq, att_wk, att_ws, wqv, wkv, flags);
  k_qk<<<(NF * 4) / 256, 256, 0, stream>>>(xA, wqv, wkv, qs, ks);
  k_groups<<<GG, 64, 0, stream>>>(group_full, group_mask, group_tgt, group_mult,
                                  qs, ks, att_b, d_out, flags);
}

// Round 4
// 475.901 us; speedup vs baseline: 2.8043x; 1.7437x over previous
//
#include <hip/hip_runtime.h>
#include <hip/hip_bf16.h>

#define NV 8192
#define NF 4096
#define NM 12288
#define PFX 3
#define DOM 16
#define EMB 61
#define NN 36864
#define EE 262144
#define GG 8192
#define KK 16
#define OUT0 524288

typedef __hip_bfloat16 bf16;
__device__ __forceinline__ float b2f(bf16 x) { return __bfloat162float(x); }
__device__ __forceinline__ float lrelu(float x, float s) { return x > 0.f ? x : s * x; }
__device__ __forceinline__ float sigm(float x) { return 1.f / (1.f + expf(-x)); }
// flag-dispatched load/store: f=1 -> float32 buffers, f=0 -> bf16 buffers
__device__ __forceinline__ float LD(const void* p, int i, int f) {
  return f ? ((const float*)p)[i] : b2f(((const bf16*)p)[i]);
}
__device__ __forceinline__ void ST(void* p, int i, int f, float v) {
  if (f) ((float*)p)[i] = v; else ((bf16*)p)[i] = __float2bfloat16(v);
}
__device__ __forceinline__ int MK(const void* p, int i, int bytey) {
  return bytey ? (int)((const signed char*)p)[i] : ((const int*)p)[i];
}

// -------- dtype detector: flags[0]=floats are f32, flags[1]=mask is byte-bool --------
__global__ void k_detect(const void* fn, const void* mask, int* flags) {
  if (threadIdx.x || blockIdx.x) return;
  int wild = 0;
  const bf16* h = (const bf16*)fn;
  for (int i = 0; i < 128; ++i) {
    float x = b2f(h[i]);
    float a = fabsf(x);
    if (a != a || a > 1e4f || (x != 0.f && a < 1e-8f)) ++wild;
  }
  flags[0] = (wild >= 8) ? 1 : 0;
  const int* mi = (const int*)mask;
  int bytey = 0;
  for (int i = 0; i < 64; ++i) {
    unsigned v = (unsigned)mi[i];
    if (v > 1u) bytey = 1;
  }
  flags[1] = bytey;
}

// -------- transpose GRU weights into Wt[dir][d][192] (d-major, o padded 183->192) --------
__global__ void k_wtr(const void* gv_wih, const void* gv_whh,
                      const void* gf_wih, const void* gf_whh, float* Wt, const int* flg) {
  int f = flg[0];
  int t = blockIdx.x * blockDim.x + threadIdx.x;
  if (t >= 2 * 77 * 192) return;
  int dir = t / (77 * 192);
  int rem = t - dir * 77 * 192;
  int d = rem / 192, o = rem - d * 192;
  const void* wih = dir ? gf_wih : gv_wih;
  const void* whh = dir ? gf_whh : gv_whh;
  float v = 0.f;
  if (o < 183) v = (d < 16) ? LD(wih, o * 16 + d, f) : LD(whh, o * 61 + (d - 16), f);
  Wt[t] = v;
}

// ---------------- GRU v2: register-tiled, 64 rows/block ----------------
// thread (og,rg): outputs o0=og*12..+11, rows r0=rg*4..+3
__global__ __launch_bounds__(256) void k_gru2(
    const void* v2f_msgs, const void* v2f_hid, const void* f2v_msgs, const void* f2v_hid,
    const void* gv_bih, const void* gv_bhh, const void* gf_bih, const void* gf_bhh,
    const float* Wt, float* hidcat, void* outv, const int* flg) {
  int f = flg[0];
  int blk = blockIdx.x;
  int dir = blk >= 192;
  int loc = dir ? blk - 192 : blk;
  int gr0 = loc * 64;
  const void* msgs = dir ? f2v_msgs : v2f_msgs;
  const void* hid = dir ? f2v_hid : v2f_hid;
  const void* bih = dir ? gf_bih : gv_bih;
  const void* bhh = dir ? gf_bhh : gv_bhh;
  const float* W = Wt + dir * 77 * 192;

  // LDS: F[77][64] (19712B) lives at start, dead after accumulate;
  // then G1[64][183] (46848B) + G2[64][61] (15616B) reuse the whole buffer.
  __shared__ float smem[15616];  // 62464 B
  float* F = smem;
  float* G1 = smem;                 // [r*183 + o], o in [0,183)
  float* G2 = smem + 64 * 183;      // [r*61 + j]

  int tid = threadIdx.x;
  // stage F: x part [d<16], h part [16+d]
  for (int idx = tid; idx < 64 * 16; idx += 256) {
    int r = idx >> 4, d = idx & 15;
    F[d * 64 + r] = LD(msgs, (gr0 + r) * DOM + d, f);
  }
  for (int idx = tid; idx < 64 * 61; idx += 256) {
    int r = idx / 61, d = idx - r * 61;
    F[(16 + d) * 64 + r] = LD(hid, gr0 * 61 + idx, f);
  }
  __syncthreads();

  int og = tid & 15, rg = tid >> 4;
  int o0 = og * 12, r0 = rg * 4;
  float accA[48], accB[48];
#pragma unroll
  for (int i = 0; i < 48; ++i) { accA[i] = 0.f; accB[i] = 0.f; }

#pragma unroll 2
  for (int d = 0; d < 16; ++d) {
    const float4 fv4 = *(const float4*)&F[d * 64 + r0];
    const float4 w0 = *(const float4*)&W[d * 192 + o0];
    const float4 w1 = *(const float4*)&W[d * 192 + o0 + 4];
    const float4 w2 = *(const float4*)&W[d * 192 + o0 + 8];
    float fv[4] = {fv4.x, fv4.y, fv4.z, fv4.w};
    float wv[12] = {w0.x, w0.y, w0.z, w0.w, w1.x, w1.y, w1.z, w1.w, w2.x, w2.y, w2.z, w2.w};
#pragma unroll
    for (int k = 0; k < 12; ++k)
#pragma unroll
      for (int m = 0; m < 4; ++m) accA[k * 4 + m] += wv[k] * fv[m];
  }
#pragma unroll 2
  for (int d = 16; d < 77; ++d) {
    const float4 fv4 = *(const float4*)&F[d * 64 + r0];
    const float4 w0 = *(const float4*)&W[d * 192 + o0];
    const float4 w1 = *(const float4*)&W[d * 192 + o0 + 4];
    const float4 w2 = *(const float4*)&W[d * 192 + o0 + 8];
    float fv[4] = {fv4.x, fv4.y, fv4.z, fv4.w};
    float wv[12] = {w0.x, w0.y, w0.z, w0.w, w1.x, w1.y, w1.z, w1.w, w2.x, w2.y, w2.z, w2.w};
#pragma unroll
    for (int k = 0; k < 12; ++k)
#pragma unroll
      for (int m = 0; m < 4; ++m) accB[k * 4 + m] += wv[k] * fv[m];
  }
  __syncthreads();  // F dead; G1/G2 may now overwrite

#pragma unroll
  for (int k = 0; k < 12; ++k) {
    int o = o0 + k;
    if (o < 183) {
      float biv = LD(bih, o, f), bhv = LD(bhh, o, f);
#pragma unroll
      for (int m = 0; m < 4; ++m) {
        int r = r0 + m;
        float gi = accA[k * 4 + m] + biv;
        float gh = accB[k * 4 + m] + bhv;
        if (o < 122) G1[r * 183 + o] = gi + gh;
        else { G1[r * 183 + o] = gi; G2[r * 61 + (o - 122)] = gh; }
      }
    }
  }
  __syncthreads();

  // epilogue: lanes j coalesced
  int j = tid & 63, rq = tid >> 6;
  if (j < 61) {
    for (int rr = 0; rr < 16; ++rr) {
      int r = rq * 16 + rr;
      float gr = sigm(G1[r * 183 + j]);
      float gz = sigm(G1[r * 183 + 61 + j]);
      float gn = tanhf(G1[r * 183 + 122 + j] + gr * G2[r * 61 + j]);
      float hold = LD(hid, (gr0 + r) * 61 + j, f);
      float hn = (1.f - gz) * gn + gz * hold;
      int b = dir * NM + gr0 + r;
      hidcat[b * 61 + j] = hn;
      ST(outv, OUT0 + b * 61 + j, f, hn);
    }
  }
}

// ---------------- assemble x (NN x 64 fp32) ----------------
__global__ void k_assemble(const void* vn_prefix, const int* vn_colors, const void* emb,
                           const void* fn_embed, const void* msg_prefix,
                           const float* hidcat, float* x, const int* flg) {
  int f = flg[0];
  int t = blockIdx.x * blockDim.x + threadIdx.x;
  if (t >= NN * 64) return;
  int i = t >> 6, c = t & 63;
  float v;
  if (i < NV) {
    v = (c < PFX) ? LD(vn_prefix, i * PFX + c, f) : LD(emb, vn_colors[i] * EMB + (c - PFX), f);
  } else if (i < NV + NF) {
    v = LD(fn_embed, (i - NV) * 64 + c, f);
  } else {
    int j = i - NV - NF;
    v = (c < PFX) ? LD(msg_prefix, j * PFX + c, f) : hidcat[j * EMB + (c - PFX)];
  }
  x[t] = v;
}

// ---------------- CSR build (by dst) ----------------
__global__ void k_deg(const int* dst, int* deg) {
  int e = blockIdx.x * blockDim.x + threadIdx.x;
  if (e < EE) atomicAdd(&deg[dst[e]], 1);
}
__global__ void k_scan1(const int* deg, int* rowptr, int* bsum) {
  __shared__ int s[512];
  int g = blockIdx.x * 512 + threadIdx.x;
  int v = (g < NN) ? deg[g] : 0;
  s[threadIdx.x] = v;
  __syncthreads();
  for (int off = 1; off < 512; off <<= 1) {
    int t = (threadIdx.x >= off) ? s[threadIdx.x - off] : 0;
    __syncthreads();
    s[threadIdx.x] += t;
    __syncthreads();
  }
  if (g < NN) rowptr[g] = s[threadIdx.x] - v;
  if (threadIdx.x == 511) bsum[blockIdx.x] = s[511];
}
__global__ void k_scan2(const int* bsum, int* boff, int nb) {
  __shared__ int s[128];
  int v = (threadIdx.x < nb) ? bsum[threadIdx.x] : 0;
  s[threadIdx.x] = v;
  __syncthreads();
  for (int off = 1; off < 128; off <<= 1) {
    int t = (threadIdx.x >= off) ? s[threadIdx.x - off] : 0;
    __syncthreads();
    s[threadIdx.x] += t;
    __syncthreads();
  }
  if (threadIdx.x < nb) boff[threadIdx.x] = s[threadIdx.x] - v;
}
__global__ void k_scan3(int* rowptr, const int* boff) {
  int g = blockIdx.x * blockDim.x + threadIdx.x;
  if (g < NN) rowptr[g] += boff[g >> 9];
  if (g == 0) rowptr[NN] = EE;
}
__global__ void k_fill(const int* src, const int* dst, const int* rowptr, int* cnt, int* col) {
  int e = blockIdx.x * blockDim.x + threadIdx.x;
  if (e < EE) {
    int d = dst[e];
    int pos = rowptr[d] + atomicAdd(&cnt[d], 1);
    col[pos] = src[e];
  }
}

// ---------------- xl = x @ W (IC -> 32), W staged in LDS ----------------
template <int IC>
__global__ void k_xl(const float* x, const void* W, float* xl, int n, const int* flg) {
  int f = flg[0];
  __shared__ float Wl[IC * 32];
  for (int t = threadIdx.x; t < IC * 32; t += blockDim.x) Wl[t] = LD(W, t, f);
  __syncthreads();
  int j = threadIdx.x & 31;
  int r = threadIdx.x >> 5;
  int i = blockIdx.x * 8 + r;
  if (i >= n) return;
  const float* xr = x + (size_t)i * IC;
  float acc = 0.f;
  for (int k = 0; k < IC; ++k) acc += xr[k] * Wl[k * 32 + j];
  xl[i * 32 + j] = acc;
}

// ---------------- attention coefficients ----------------
__global__ void k_coef13(const float* xl, const void* as_, const void* ad_,
                         float* a_s, float* a_d, const int* flg) {
  int f = flg[0];
  int t = blockIdx.x * blockDim.x + threadIdx.x;
  if (t >= NN * 4) return;
  int i = t >> 2, h = t & 3;
  float ss = 0.f, dd = 0.f;
  for (int c = 0; c < 8; ++c) {
    float v = xl[i * 32 + h * 8 + c];
    ss += v * LD(as_, h * 8 + c, f);
    dd += v * LD(ad_, h * 8 + c, f);
  }
  a_s[t] = ss;
  a_d[t] = dd;
}
__global__ void k_waSD(const void* W4, const void* a4s, const void* a4d, float* waS, float* waD,
                       const int* flg) {
  int f = flg[0];
  int t = threadIdx.x;  // 256
  int isD = t >= 128;
  int u = t & 127;
  int h = u >> 5, k = u & 31;
  const void* av = isD ? a4d : a4s;
  float acc = 0.f;
  for (int c = 0; c < 64; ++c) acc += LD(W4, k * 256 + h * 64 + c, f) * LD(av, h * 64 + c, f);
  (isD ? waD : waS)[h * 32 + k] = acc;
}
__global__ void k_coef4(const float* x, const float* waS, const float* waD, float* a_s, float* a_d) {
  int t = blockIdx.x * blockDim.x + threadIdx.x;
  if (t >= NN * 4) return;
  int i = t >> 2, h = t & 3;
  float ss = 0.f, dd = 0.f;
  for (int k = 0; k < 32; ++k) {
    float v = x[i * 32 + k];
    ss += v * waS[h * 32 + k];
    dd += v * waD[h * 32 + k];
  }
  a_s[t] = ss;
  a_d[t] = dd;
}

// ---------------- GAT gather, layers 1-3 (concat, ch=8) ----------------
__global__ void k_gather13(const int* rowptr, const int* col, const float* a_s, const float* a_d,
                           const float* xl, const void* bias, float* xout, const int* flg) {
  int f = flg[0];
  int i = blockIdx.x;
  int lane = threadIdx.x;
  int beg = rowptr[i], end = rowptr[i + 1];
  float ad[4], es[4], mx[4];
  for (int h = 0; h < 4; ++h) ad[h] = a_d[i * 4 + h];
  for (int h = 0; h < 4; ++h) {
    float e = a_s[i * 4 + h] + ad[h];
    es[h] = lrelu(e, 0.2f);
    mx[h] = es[h];
  }
  for (int p = beg + lane; p < end; p += 64) {
    int j = col[p];
    for (int h = 0; h < 4; ++h) {
      float e = lrelu(a_s[j * 4 + h] + ad[h], 0.2f);
      mx[h] = fmaxf(mx[h], e);
    }
  }
  for (int off = 1; off < 64; off <<= 1)
    for (int h = 0; h < 4; ++h) mx[h] = fmaxf(mx[h], __shfl_xor(mx[h], off));
  float den[4];
  for (int h = 0; h < 4; ++h) den[h] = expf(es[h] - mx[h]);  // self contribution
  int hl = (lane >> 3) & 3;
  float acc = 0.f;
  if (lane < 32) acc = den[hl] * xl[i * 32 + lane];
  for (int p = beg; p < end; ++p) {
    int j = col[p];
    float ex[4];
    for (int h = 0; h < 4; ++h) {
      float e = lrelu(a_s[j * 4 + h] + ad[h], 0.2f);
      ex[h] = expf(e - mx[h]);
      den[h] += ex[h];
    }
    if (lane < 32) acc += ex[hl] * xl[j * 32 + lane];
  }
  if (lane < 32) {
    float v = acc / den[hl] + LD(bias, lane, f);
    xout[i * 32 + lane] = lrelu(v, 0.01f);
  }
}

// ---------------- GAT gather, layer 4: aggregate x rows per head ----------------
__global__ void k_gather4(const int* rowptr, const int* col, const float* a_s, const float* a_d,
                          const float* x, float* agg) {
  int i = blockIdx.x;
  int lane = threadIdx.x;
  int kk = lane & 31;
  int h0 = lane >> 5;  // 0/1
  int h1 = h0 + 2;
  int beg = rowptr[i], end = rowptr[i + 1];
  float ad[4], es[4], mx[4];
  for (int h = 0; h < 4; ++h) ad[h] = a_d[i * 4 + h];
  for (int h = 0; h < 4; ++h) {
    float e = a_s[i * 4 + h] + ad[h];
    es[h] = lrelu(e, 0.2f);
    mx[h] = es[h];
  }
  for (int p = beg + lane; p < end; p += 64) {
    int j = col[p];
    for (int h = 0; h < 4; ++h) {
      float e = lrelu(a_s[j * 4 + h] + ad[h], 0.2f);
      mx[h] = fmaxf(mx[h], e);
    }
  }
  for (int off = 1; off < 64; off <<= 1)
    for (int h = 0; h < 4; ++h) mx[h] = fmaxf(mx[h], __shfl_xor(mx[h], off));
  float den[4];
  for (int h = 0; h < 4; ++h) den[h] = expf(es[h] - mx[h]);
  float xv = x[i * 32 + kk];
  float acc0 = den[h0] * xv;
  float acc1 = den[h1] * xv;
  for (int p = beg; p < end; ++p) {
    int j = col[p];
    float ex[4];
    for (int h = 0; h < 4; ++h) {
      float e = lrelu(a_s[j * 4 + h] + ad[h], 0.2f);
      ex[h] = expf(e - mx[h]);
      den[h] += ex[h];
    }
    float xj = x[j * 32 + kk];
    acc0 += ex[h0] * xj;
    acc1 += ex[h1] * xj;
  }
  agg[i * 128 + h0 * 32 + kk] = acc0 / den[h0];
  agg[i * 128 + h1 * 32 + kk] = acc1 / den[h1];
}

// ---------------- L4 epilogue: 64 rows/block, W4+agg staged in LDS ----------------
// out[i,c] = lrelu( 0.25 * sum_h sum_k agg[i,h,k]*W4[k, h*64+c] + b4[c], 0.01 )
__global__ __launch_bounds__(256) void k_l4_out(const float* agg, const void* W4, const void* b4,
                                                float* xout, const int* flg) {
  int f = flg[0];
  __shared__ float Wl[32 * 256];   // 32 KB
  __shared__ float Al[64 * 128];   // 32 KB
  int tid = threadIdx.x;
  int R0 = blockIdx.x * 64;
  for (int t = tid; t < 32 * 256; t += 256) Wl[t] = LD(W4, t, f);
  // agg rows R0..R0+63: 8192 floats contiguous, coalesced float4
  {
    const float4* ag4 = (const float4*)(agg + (size_t)R0 * 128);
    float4* Al4 = (float4*)Al;
    for (int t = tid; t < 2048; t += 256) Al4[t] = ag4[t];
  }
  __syncthreads();
  int c = tid & 63, q = tid >> 6;
  float bv = LD(b4, c, f);
#pragma unroll 4
  for (int rr = 0; rr < 16; ++rr) {
    int r = q * 16 + rr;
    float acc = 0.f;
#pragma unroll
    for (int h = 0; h < 4; ++h) {
      const float* al = &Al[r * 128 + h * 32];
      const float* wl = &Wl[h * 64 + c];
#pragma unroll
      for (int k = 0; k < 32; ++k) acc += al[k] * wl[k * 256];
    }
    float v = 0.25f * acc + bv;
    xout[(size_t)(R0 + r) * 64 + c] = lrelu(v, 0.01f);
  }
}

// ---------------- pooling attention head ----------------
__global__ void k_wqk(const void* wq, const void* wk, const void* ws, float* wqv, float* wkv,
                      const int* flg) {
  int f = flg[0];
  int t = threadIdx.x;  // 256
  int h = t >> 6, d = t & 63;
  float q = 0.f, k = 0.f;
  for (int e = 0; e < 64; ++e) {
    q += LD(wq, h * 4096 + d * 64 + e, f) * LD(ws, h * 128 + e, f);
    k += LD(wk, h * 4096 + d * 64 + e, f) * LD(ws, h * 128 + 64 + e, f);
  }
  wqv[h * 64 + d] = q;
  wkv[h * 64 + d] = k;
}
__global__ void k_qk(const float* xfin, const float* wqv, const float* wkv, float* qs, float* ks) {
  int t = blockIdx.x * blockDim.x + threadIdx.x;
  if (t >= NF * 4) return;
  int n = t >> 2, h = t & 3;
  const float* row = xfin + (size_t)(NV + n) * 64;
  float q = 0.f, k = 0.f;
  for (int d = 0; d < 64; ++d) {
    float v = row[d];
    q += v * wqv[h * 64 + d];
    k += v * wkv[h * 64 + d];
  }
  qs[t] = q;
  ks[t] = k;
}

__global__ void k_groups(const int* full, const void* mask, const int* tgt, const int* mult,
                         const float* qs, const float* ks, const void* att_b, void* outv,
                         const int* flg) {
  int f = flg[0], mbyte = flg[1];
  int g = blockIdx.x;
  int lane = threadIdx.x;  // 64 = 16 k * 4 h
  int k = lane >> 2, h = lane & 3;
  int t = tgt[g];
  int idx = full[g * KK + k];
  int mk = MK(mask, g * KK + k, mbyte);
  float bh = LD(att_b, h, f);
  float qt = qs[t * 4 + h];
  float sc = sigm(qt + ks[idx * 4 + h] + bh);
  int is_tgt = (idx == t) && mk;
  int nbr = mk && !is_tgt;
  unsigned long long bal = __ballot(nbr != 0);
  int degm1 = (int)(__popcll(bal) >> 2);
  float ssum = nbr ? sc : 0.f;
  for (int off = 4; off < 64; off <<= 1) ssum += __shfl_xor(ssum, off);
  ssum /= (float)(degm1 > 1 ? degm1 : 1);
  float trg = sigm(qt + ks[t * 4 + h] + bh);
  float mxv = fmaxf(ssum, trg);
  float e0 = expf(ssum - mxv), e1 = expf(trg - mxv);
  float tw0 = e0 / (e0 + e1), tw1 = e1 / (e0 + e1);
  float msc = nbr ? sc : -1e30f;
  float m = msc;
  for (int off = 4; off < 64; off <<= 1) m = fmaxf(m, __shfl_xor(m, off));
  float ex = expf(msc - m);
  float den = ex;
  for (int off = 4; off < 64; off <<= 1) den += __shfl_xor(den, off);
  float w = ex / den * tw0 * (float)mult[g];
  float res = is_tgt ? tw1 : (nbr ? w : 0.f);
  if (degm1 == 0) res = 0.f;
  ST(outv, g * 64 + k * 4 + h, f, res);
}

extern "C" void kernel_launch(void* const* d_in, const int* in_sizes, int n_in,
                              void* d_out, int out_size, void* d_ws, size_t ws_size,
                              hipStream_t stream) {
  const int* edge = (const int*)d_in[0];
  const int* esrc = edge;
  const int* edst = edge + EE;
  const int* vn_colors = (const int*)d_in[1];
  const int* group_full = (const int*)d_in[2];
  const void* group_mask = d_in[3];
  const int* group_tgt = (const int*)d_in[4];
  const int* group_mult = (const int*)d_in[5];
  const void* vn_prefix = d_in[6];
  const void* fn_embed = d_in[7];
  const void* v2f_msgs = d_in[8];
  const void* v2f_hidden = d_in[9];
  const void* f2v_msgs = d_in[10];
  const void* f2v_hidden = d_in[11];
  const void* msg_prefix = d_in[12];
  const void* emb = d_in[13];
  const void* gv_wih = d_in[14];
  const void* gv_whh = d_in[15];
  const void* gv_bih = d_in[16];
  const void* gv_bhh = d_in[17];
  const void* gf_wih = d_in[18];
  const void* gf_whh = d_in[19];
  const void* gf_bih = d_in[20];
  const void* gf_bhh = d_in[21];
  const void* W1 = d_in[22];
  const void* a1s = d_in[23];
  const void* a1d = d_in[24];
  const void* b1 = d_in[25];
  const void* W2 = d_in[26];
  const void* a2s = d_in[27];
  const void* a2d = d_in[28];
  const void* b2 = d_in[29];
  const void* W3 = d_in[30];
  const void* a3s = d_in[31];
  const void* a3d = d_in[32];
  const void* b3 = d_in[33];
  const void* W4 = d_in[34];
  const void* a4s = d_in[35];
  const void* a4d = d_in[36];
  const void* b4 = d_in[37];
  const void* att_wq = d_in[38];
  const void* att_wk = d_in[39];
  const void* att_ws = d_in[40];
  const void* att_b = d_in[41];

  char* w = (char*)d_ws;
  size_t off = 0;
  auto carve = [&](size_t bytes) -> void* {
    void* p = w + off;
    off += (bytes + 255) & ~(size_t)255;
    return p;
  };
  int* flags = (int*)carve(16);
  float* Wt = (float*)carve((size_t)2 * 77 * 192 * 4);
  float* hidcat = (float*)carve((size_t)2 * NM * EMB * 4);
  float* xA = (float*)carve((size_t)NN * 64 * 4);
  float* xB = (float*)carve((size_t)NN * 64 * 4);
  float* scr = (float*)carve((size_t)NN * 128 * 4);  // xl (N x 32) or agg (N x 128)
  float* a_s = (float*)carve((size_t)NN * 4 * 4);
  float* a_d = (float*)carve((size_t)NN * 4 * 4);
  int* deg = (int*)carve((size_t)NN * 4);
  int* rowptr = (int*)carve((size_t)(NN + 1) * 4);
  int* cnt = (int*)carve((size_t)NN * 4);
  int* bsum = (int*)carve(128 * 4);
  int* boff = (int*)carve(128 * 4);
  int* col = (int*)carve((size_t)EE * 4);
  float* qs = (float*)carve((size_t)NF * 4 * 4);
  float* ks = (float*)carve((size_t)NF * 4 * 4);
  float* wqv = (float*)carve(256 * 4);
  float* wkv = (float*)carve(256 * 4);
  float* waS = (float*)carve(128 * 4);
  float* waD = (float*)carve(128 * 4);

  hipMemsetAsync(deg, 0, (size_t)NN * 4, stream);
  hipMemsetAsync(cnt, 0, (size_t)NN * 4, stream);

  k_detect<<<1, 64, 0, stream>>>(fn_embed, group_mask, flags);
  k_wtr<<<(2 * 77 * 192 + 255) / 256, 256, 0, stream>>>(gv_wih, gv_whh, gf_wih, gf_whh, Wt, flags);
  k_gru2<<<384, 256, 0, stream>>>(v2f_msgs, v2f_hidden, f2v_msgs, f2v_hidden,
                                  gv_bih, gv_bhh, gf_bih, gf_bhh, Wt, hidcat, d_out, flags);
  k_assemble<<<(NN * 64) / 256, 256, 0, stream>>>(vn_prefix, vn_colors, emb, fn_embed,
                                                  msg_prefix, hidcat, xA, flags);
  k_deg<<<EE / 256, 256, 0, stream>>>(edst, deg);
  k_scan1<<<72, 512, 0, stream>>>(deg, rowptr, bsum);
  k_scan2<<<1, 128, 0, stream>>>(bsum, boff, 72);
  k_scan3<<<(NN + 256) / 256, 256, 0, stream>>>(rowptr, boff);
  k_fill<<<EE / 256, 256, 0, stream>>>(esrc, edst, rowptr, cnt, col);

  // L1: 64 -> 32
  k_xl<64><<<NN / 8, 256, 0, stream>>>(xA, W1, scr, NN, flags);
  k_coef13<<<NN * 4 / 256, 256, 0, stream>>>(scr, a1s, a1d, a_s, a_d, flags);
  k_gather13<<<NN, 64, 0, stream>>>(rowptr, col, a_s, a_d, scr, b1, xB, flags);
  // L2: 32 -> 32
  k_xl<32><<<NN / 8, 256, 0, stream>>>(xB, W2, scr, NN, flags);
  k_coef13<<<NN * 4 / 256, 256, 0, stream>>>(scr, a2s, a2d, a_s, a_d, flags);
  k_gather13<<<NN, 64, 0, stream>>>(rowptr, col, a_s, a_d, scr, b2, xA, flags);
  // L3: 32 -> 32
  k_xl<32><<<NN / 8, 256, 0, stream>>>(xA, W3, scr, NN, flags);
  k_coef13<<<NN * 4 / 256, 256, 0, stream>>>(scr, a3s, a3d, a_s, a_d, flags);
  k_gather13<<<NN, 64, 0, stream>>>(rowptr, col, a_s, a_d, scr, b3, xB, flags);
  // L4: 32 -> (4 heads x 64), mean
  k_waSD<<<1, 256, 0, stream>>>(W4, a4s, a4d, waS, waD, flags);
  k_coef4<<<NN * 4 / 256, 256, 0, stream>>>(xB, waS, waD, a_s, a_d);
  k_gather4<<<NN, 64, 0, stream>>>(rowptr, col, a_s, a_d, xB, scr);
  k_l4_out<<<NN / 64, 256, 0, stream>>>(scr, W4, b4, xA, flags);

  k_wqk<<<1, 256, 0, stream>>>(att_wq, att_wk, att_ws, wqv, wkv, flags);
  k_qk<<<(NF * 4) / 256, 256, 0, stream>>>(xA, wqv, wkv, qs, ks);
  k_groups<<<GG, 64, 0, stream>>>(group_full, group_mask, group_tgt, group_mult,
                                  qs, ks, att_b, d_out, flags);
}

// Round 5
// 362.855 us; speedup vs baseline: 3.6779x; 1.3115x over previous
//
#include <hip/hip_runtime.h>
#include <hip/hip_bf16.h>

#define NV 8192
#define NF 4096
#define NM 12288
#define PFX 3
#define DOM 16
#define EMB 61
#define NN 36864
#define EE 262144
#define GG 8192
#define KK 16
#define OUT0 524288

typedef __hip_bfloat16 bf16;
__device__ __forceinline__ float b2f(bf16 x) { return __bfloat162float(x); }
__device__ __forceinline__ float lrelu(float x, float s) { return x > 0.f ? x : s * x; }
__device__ __forceinline__ float sigm(float x) { return 1.f / (1.f + expf(-x)); }
// flag-dispatched load/store: f=1 -> float32 buffers, f=0 -> bf16 buffers
__device__ __forceinline__ float LD(const void* p, int i, int f) {
  return f ? ((const float*)p)[i] : b2f(((const bf16*)p)[i]);
}
__device__ __forceinline__ void ST(void* p, int i, int f, float v) {
  if (f) ((float*)p)[i] = v; else ((bf16*)p)[i] = __float2bfloat16(v);
}
__device__ __forceinline__ int MK(const void* p, int i, int bytey) {
  return bytey ? (int)((const signed char*)p)[i] : ((const int*)p)[i];
}

// -------- dtype detector: flags[0]=floats are f32, flags[1]=mask is byte-bool --------
__global__ void k_detect(const void* fn, const void* mask, int* flags) {
  if (threadIdx.x || blockIdx.x) return;
  int wild = 0;
  const bf16* h = (const bf16*)fn;
  for (int i = 0; i < 128; ++i) {
    float x = b2f(h[i]);
    float a = fabsf(x);
    if (a != a || a > 1e4f || (x != 0.f && a < 1e-8f)) ++wild;
  }
  flags[0] = (wild >= 8) ? 1 : 0;
  const int* mi = (const int*)mask;
  int bytey = 0;
  for (int i = 0; i < 64; ++i) {
    unsigned v = (unsigned)mi[i];
    if (v > 1u) bytey = 1;
  }
  flags[1] = bytey;
}

// -------- transpose GRU weights into Wt[dir][d][192] (d-major, o padded 183->192) --------
__global__ void k_wtr(const void* gv_wih, const void* gv_whh,
                      const void* gf_wih, const void* gf_whh, float* Wt, const int* flg) {
  int f = flg[0];
  int t = blockIdx.x * blockDim.x + threadIdx.x;
  if (t >= 2 * 77 * 192) return;
  int dir = t / (77 * 192);
  int rem = t - dir * 77 * 192;
  int d = rem / 192, o = rem - d * 192;
  const void* wih = dir ? gf_wih : gv_wih;
  const void* whh = dir ? gf_whh : gv_whh;
  float v = 0.f;
  if (o < 183) v = (d < 16) ? LD(wih, o * 16 + d, f) : LD(whh, o * 61 + (d - 16), f);
  Wt[t] = v;
}

// ---------------- GRU v2: register-tiled, 64 rows/block ----------------
__global__ __launch_bounds__(256) void k_gru2(
    const void* v2f_msgs, const void* v2f_hid, const void* f2v_msgs, const void* f2v_hid,
    const void* gv_bih, const void* gv_bhh, const void* gf_bih, const void* gf_bhh,
    const float* Wt, float* hidcat, void* outv, const int* flg) {
  int f = flg[0];
  int blk = blockIdx.x;
  int dir = blk >= 192;
  int loc = dir ? blk - 192 : blk;
  int gr0 = loc * 64;
  const void* msgs = dir ? f2v_msgs : v2f_msgs;
  const void* hid = dir ? f2v_hid : v2f_hid;
  const void* bih = dir ? gf_bih : gv_bih;
  const void* bhh = dir ? gf_bhh : gv_bhh;
  const float* W = Wt + dir * 77 * 192;

  __shared__ float smem[15616];  // 62464 B
  float* F = smem;
  float* G1 = smem;                 // [r*183 + o]
  float* G2 = smem + 64 * 183;      // [r*61 + j]

  int tid = threadIdx.x;
  for (int idx = tid; idx < 64 * 16; idx += 256) {
    int r = idx >> 4, d = idx & 15;
    F[d * 64 + r] = LD(msgs, (gr0 + r) * DOM + d, f);
  }
  for (int idx = tid; idx < 64 * 61; idx += 256) {
    int r = idx / 61, d = idx - r * 61;
    F[(16 + d) * 64 + r] = LD(hid, gr0 * 61 + idx, f);
  }
  __syncthreads();

  int og = tid & 15, rg = tid >> 4;
  int o0 = og * 12, r0 = rg * 4;
  float accA[48], accB[48];
#pragma unroll
  for (int i = 0; i < 48; ++i) { accA[i] = 0.f; accB[i] = 0.f; }

#pragma unroll 2
  for (int d = 0; d < 16; ++d) {
    const float4 fv4 = *(const float4*)&F[d * 64 + r0];
    const float4 w0 = *(const float4*)&W[d * 192 + o0];
    const float4 w1 = *(const float4*)&W[d * 192 + o0 + 4];
    const float4 w2 = *(const float4*)&W[d * 192 + o0 + 8];
    float fv[4] = {fv4.x, fv4.y, fv4.z, fv4.w};
    float wv[12] = {w0.x, w0.y, w0.z, w0.w, w1.x, w1.y, w1.z, w1.w, w2.x, w2.y, w2.z, w2.w};
#pragma unroll
    for (int k = 0; k < 12; ++k)
#pragma unroll
      for (int m = 0; m < 4; ++m) accA[k * 4 + m] += wv[k] * fv[m];
  }
#pragma unroll 2
  for (int d = 16; d < 77; ++d) {
    const float4 fv4 = *(const float4*)&F[d * 64 + r0];
    const float4 w0 = *(const float4*)&W[d * 192 + o0];
    const float4 w1 = *(const float4*)&W[d * 192 + o0 + 4];
    const float4 w2 = *(const float4*)&W[d * 192 + o0 + 8];
    float fv[4] = {fv4.x, fv4.y, fv4.z, fv4.w};
    float wv[12] = {w0.x, w0.y, w0.z, w0.w, w1.x, w1.y, w1.z, w1.w, w2.x, w2.y, w2.z, w2.w};
#pragma unroll
    for (int k = 0; k < 12; ++k)
#pragma unroll
      for (int m = 0; m < 4; ++m) accB[k * 4 + m] += wv[k] * fv[m];
  }
  __syncthreads();

#pragma unroll
  for (int k = 0; k < 12; ++k) {
    int o = o0 + k;
    if (o < 183) {
      float biv = LD(bih, o, f), bhv = LD(bhh, o, f);
#pragma unroll
      for (int m = 0; m < 4; ++m) {
        int r = r0 + m;
        float gi = accA[k * 4 + m] + biv;
        float gh = accB[k * 4 + m] + bhv;
        if (o < 122) G1[r * 183 + o] = gi + gh;
        else { G1[r * 183 + o] = gi; G2[r * 61 + (o - 122)] = gh; }
      }
    }
  }
  __syncthreads();

  int j = tid & 63, rq = tid >> 6;
  if (j < 61) {
    for (int rr = 0; rr < 16; ++rr) {
      int r = rq * 16 + rr;
      float gr = sigm(G1[r * 183 + j]);
      float gz = sigm(G1[r * 183 + 61 + j]);
      float gn = tanhf(G1[r * 183 + 122 + j] + gr * G2[r * 61 + j]);
      float hold = LD(hid, (gr0 + r) * 61 + j, f);
      float hn = (1.f - gz) * gn + gz * hold;
      int b = dir * NM + gr0 + r;
      hidcat[b * 61 + j] = hn;
      ST(outv, OUT0 + b * 61 + j, f, hn);
    }
  }
}

// ---------------- assemble x (NN x 64 fp32) ----------------
__global__ void k_assemble(const void* vn_prefix, const int* vn_colors, const void* emb,
                           const void* fn_embed, const void* msg_prefix,
                           const float* hidcat, float* x, const int* flg) {
  int f = flg[0];
  int t = blockIdx.x * blockDim.x + threadIdx.x;
  if (t >= NN * 64) return;
  int i = t >> 6, c = t & 63;
  float v;
  if (i < NV) {
    v = (c < PFX) ? LD(vn_prefix, i * PFX + c, f) : LD(emb, vn_colors[i] * EMB + (c - PFX), f);
  } else if (i < NV + NF) {
    v = LD(fn_embed, (i - NV) * 64 + c, f);
  } else {
    int j = i - NV - NF;
    v = (c < PFX) ? LD(msg_prefix, j * PFX + c, f) : hidcat[j * EMB + (c - PFX)];
  }
  x[t] = v;
}

// ---------------- CSR build (by dst) ----------------
__global__ void k_deg(const int* dst, int* deg) {
  int e = blockIdx.x * blockDim.x + threadIdx.x;
  if (e < EE) atomicAdd(&deg[dst[e]], 1);
}
__global__ void k_scan1(const int* deg, int* rowptr, int* bsum) {
  __shared__ int s[512];
  int g = blockIdx.x * 512 + threadIdx.x;
  int v = (g < NN) ? deg[g] : 0;
  s[threadIdx.x] = v;
  __syncthreads();
  for (int off = 1; off < 512; off <<= 1) {
    int t = (threadIdx.x >= off) ? s[threadIdx.x - off] : 0;
    __syncthreads();
    s[threadIdx.x] += t;
    __syncthreads();
  }
  if (g < NN) rowptr[g] = s[threadIdx.x] - v;
  if (threadIdx.x == 511) bsum[blockIdx.x] = s[511];
}
__global__ void k_scan2(const int* bsum, int* boff, int nb) {
  __shared__ int s[128];
  int v = (threadIdx.x < nb) ? bsum[threadIdx.x] : 0;
  s[threadIdx.x] = v;
  __syncthreads();
  for (int off = 1; off < 128; off <<= 1) {
    int t = (threadIdx.x >= off) ? s[threadIdx.x - off] : 0;
    __syncthreads();
    s[threadIdx.x] += t;
    __syncthreads();
  }
  if (threadIdx.x < nb) boff[threadIdx.x] = s[threadIdx.x] - v;
}
__global__ void k_scan3(int* rowptr, const int* boff) {
  int g = blockIdx.x * blockDim.x + threadIdx.x;
  if (g < NN) rowptr[g] += boff[g >> 9];
  if (g == 0) rowptr[NN] = EE;
}
__global__ void k_fill(const int* src, const int* dst, const int* rowptr, int* cnt, int* col) {
  int e = blockIdx.x * blockDim.x + threadIdx.x;
  if (e < EE) {
    int d = dst[e];
    int pos = rowptr[d] + atomicAdd(&cnt[d], 1);
    col[pos] = src[e];
  }
}

// ---------------- xl = x @ W (IC -> 32), W staged in LDS ----------------
template <int IC>
__global__ void k_xl(const float* x, const void* W, float* xl, int n, const int* flg) {
  int f = flg[0];
  __shared__ float Wl[IC * 32];
  for (int t = threadIdx.x; t < IC * 32; t += blockDim.x) Wl[t] = LD(W, t, f);
  __syncthreads();
  int j = threadIdx.x & 31;
  int r = threadIdx.x >> 5;
  int i = blockIdx.x * 8 + r;
  if (i >= n) return;
  const float* xr = x + (size_t)i * IC;
  float acc = 0.f;
  for (int k = 0; k < IC; ++k) acc += xr[k] * Wl[k * 32 + j];
  xl[i * 32 + j] = acc;
}

// ---------------- attention coefficients ----------------
__global__ void k_coef13(const float* xl, const void* as_, const void* ad_,
                         float* a_s, float* a_d, const int* flg) {
  int f = flg[0];
  int t = blockIdx.x * blockDim.x + threadIdx.x;
  if (t >= NN * 4) return;
  int i = t >> 2, h = t & 3;
  float ss = 0.f, dd = 0.f;
  for (int c = 0; c < 8; ++c) {
    float v = xl[i * 32 + h * 8 + c];
    ss += v * LD(as_, h * 8 + c, f);
    dd += v * LD(ad_, h * 8 + c, f);
  }
  a_s[t] = ss;
  a_d[t] = dd;
}
__global__ void k_waSD(const void* W4, const void* a4s, const void* a4d, float* waS, float* waD,
                       const int* flg) {
  int f = flg[0];
  int t = threadIdx.x;  // 256
  int isD = t >= 128;
  int u = t & 127;
  int h = u >> 5, k = u & 31;
  const void* av = isD ? a4d : a4s;
  float acc = 0.f;
  for (int c = 0; c < 64; ++c) acc += LD(W4, k * 256 + h * 64 + c, f) * LD(av, h * 64 + c, f);
  (isD ? waD : waS)[h * 32 + k] = acc;
}
__global__ void k_coef4(const float* x, const float* waS, const float* waD, float* a_s, float* a_d) {
  int t = blockIdx.x * blockDim.x + threadIdx.x;
  if (t >= NN * 4) return;
  int i = t >> 2, h = t & 3;
  float ss = 0.f, dd = 0.f;
  for (int k = 0; k < 32; ++k) {
    float v = x[i * 32 + k];
    ss += v * waS[h * 32 + k];
    dd += v * waD[h * 32 + k];
  }
  a_s[t] = ss;
  a_d[t] = dd;
}

// ---------------- GAT gather v2, layers 1-3: 16 nodes/block, 16 lanes/node ----------------
__global__ __launch_bounds__(256) void k_gather13(const int* rowptr, const int* col,
                                                  const float* a_s, const float* a_d,
                                                  const float* xl, const void* bias,
                                                  float* xout, const int* flg) {
  int f = flg[0];
  __shared__ int colb[16][64];
  __shared__ float4 eb[16][64];
  int tid = threadIdx.x;
  int g = tid >> 4, l = tid & 15;
  int i = blockIdx.x * 16 + g;
  int beg = rowptr[i], end = rowptr[i + 1];
  int deg = end - beg;
  float4 adv = *(const float4*)(a_d + (size_t)i * 4);
  float4 asv = *(const float4*)(a_s + (size_t)i * 4);
  float ad[4] = {adv.x, adv.y, adv.z, adv.w};
  float es[4], mx[4];
  {
    float asl[4] = {asv.x, asv.y, asv.z, asv.w};
#pragma unroll
    for (int h = 0; h < 4; ++h) { es[h] = lrelu(asl[h] + ad[h], 0.2f); mx[h] = es[h]; }
  }
  float den[4] = {0.f, 0.f, 0.f, 0.f};
  int c0 = l, c1 = l + 16;
  int h0 = l >> 3, h1 = 2 + (l >> 3);
  float acc0, acc1;

  if (deg <= 64) {
    // phase A: one global read of a_s per edge; cache col + e[4] in LDS
    for (int s = l; s < deg; s += 16) {
      int j = col[beg + s];
      colb[g][s] = j;
      float4 aj = *(const float4*)(a_s + (size_t)j * 4);
      float e0 = lrelu(aj.x + ad[0], 0.2f);
      float e1 = lrelu(aj.y + ad[1], 0.2f);
      float e2 = lrelu(aj.z + ad[2], 0.2f);
      float e3 = lrelu(aj.w + ad[3], 0.2f);
      eb[g][s] = make_float4(e0, e1, e2, e3);
      mx[0] = fmaxf(mx[0], e0); mx[1] = fmaxf(mx[1], e1);
      mx[2] = fmaxf(mx[2], e2); mx[3] = fmaxf(mx[3], e3);
    }
#pragma unroll
    for (int off = 1; off < 16; off <<= 1)
#pragma unroll
      for (int h = 0; h < 4; ++h) mx[h] = fmaxf(mx[h], __shfl_xor(mx[h], off));
    // phase B: exp in LDS, partial den
    for (int s = l; s < deg; s += 16) {
      float4 e4 = eb[g][s];
      float x0 = expf(e4.x - mx[0]), x1 = expf(e4.y - mx[1]);
      float x2 = expf(e4.z - mx[2]), x3 = expf(e4.w - mx[3]);
      eb[g][s] = make_float4(x0, x1, x2, x3);
      den[0] += x0; den[1] += x1; den[2] += x2; den[3] += x3;
    }
#pragma unroll
    for (int off = 1; off < 16; off <<= 1)
#pragma unroll
      for (int h = 0; h < 4; ++h) den[h] += __shfl_xor(den[h], off);
    float exS[4];
#pragma unroll
    for (int h = 0; h < 4; ++h) { exS[h] = expf(es[h] - mx[h]); den[h] += exS[h]; }
    // phase C: channel-parallel accumulate
    acc0 = exS[h0] * xl[(size_t)i * 32 + c0];
    acc1 = exS[h1] * xl[(size_t)i * 32 + c1];
    for (int s = 0; s < deg; ++s) {
      int j = colb[g][s];
      float4 e4 = eb[g][s];
      float w0 = h0 ? e4.y : e4.x;
      float w1 = (l >> 3) ? e4.w : e4.z;
      acc0 += w0 * xl[(size_t)j * 32 + c0];
      acc1 += w1 * xl[(size_t)j * 32 + c1];
    }
  } else {
    // slow generic path (recompute)
    for (int s = l; s < deg; s += 16) {
      int j = col[beg + s];
      float4 aj = *(const float4*)(a_s + (size_t)j * 4);
      mx[0] = fmaxf(mx[0], lrelu(aj.x + ad[0], 0.2f));
      mx[1] = fmaxf(mx[1], lrelu(aj.y + ad[1], 0.2f));
      mx[2] = fmaxf(mx[2], lrelu(aj.z + ad[2], 0.2f));
      mx[3] = fmaxf(mx[3], lrelu(aj.w + ad[3], 0.2f));
    }
#pragma unroll
    for (int off = 1; off < 16; off <<= 1)
#pragma unroll
      for (int h = 0; h < 4; ++h) mx[h] = fmaxf(mx[h], __shfl_xor(mx[h], off));
    for (int s = l; s < deg; s += 16) {
      int j = col[beg + s];
      float4 aj = *(const float4*)(a_s + (size_t)j * 4);
      den[0] += expf(lrelu(aj.x + ad[0], 0.2f) - mx[0]);
      den[1] += expf(lrelu(aj.y + ad[1], 0.2f) - mx[1]);
      den[2] += expf(lrelu(aj.z + ad[2], 0.2f) - mx[2]);
      den[3] += expf(lrelu(aj.w + ad[3], 0.2f) - mx[3]);
    }
#pragma unroll
    for (int off = 1; off < 16; off <<= 1)
#pragma unroll
      for (int h = 0; h < 4; ++h) den[h] += __shfl_xor(den[h], off);
    float exS[4];
#pragma unroll
    for (int h = 0; h < 4; ++h) { exS[h] = expf(es[h] - mx[h]); den[h] += exS[h]; }
    acc0 = exS[h0] * xl[(size_t)i * 32 + c0];
    acc1 = exS[h1] * xl[(size_t)i * 32 + c1];
    for (int s = 0; s < deg; ++s) {
      int j = col[beg + s];
      float e0 = lrelu(a_s[(size_t)j * 4 + h0] + ad[h0], 0.2f);
      float e1 = lrelu(a_s[(size_t)j * 4 + h1] + ad[h1], 0.2f);
      acc0 += expf(e0 - mx[h0]) * xl[(size_t)j * 32 + c0];
      acc1 += expf(e1 - mx[h1]) * xl[(size_t)j * 32 + c1];
    }
  }
  float v0 = acc0 / den[h0] + LD(bias, c0, f);
  float v1 = acc1 / den[h1] + LD(bias, c1, f);
  xout[(size_t)i * 32 + c0] = lrelu(v0, 0.01f);
  xout[(size_t)i * 32 + c1] = lrelu(v1, 0.01f);
}

// ---------------- GAT gather v2, layer 4: aggregate x rows per head ----------------
__global__ __launch_bounds__(256) void k_gather4(const int* rowptr, const int* col,
                                                 const float* a_s, const float* a_d,
                                                 const float* x, float* agg) {
  __shared__ int colb[16][64];
  __shared__ float4 eb[16][64];
  int tid = threadIdx.x;
  int g = tid >> 4, l = tid & 15;
  int i = blockIdx.x * 16 + g;
  int beg = rowptr[i], end = rowptr[i + 1];
  int deg = end - beg;
  float4 adv = *(const float4*)(a_d + (size_t)i * 4);
  float4 asv = *(const float4*)(a_s + (size_t)i * 4);
  float ad[4] = {adv.x, adv.y, adv.z, adv.w};
  float es[4], mx[4];
  {
    float asl[4] = {asv.x, asv.y, asv.z, asv.w};
#pragma unroll
    for (int h = 0; h < 4; ++h) { es[h] = lrelu(asl[h] + ad[h], 0.2f); mx[h] = es[h]; }
  }
  float den[4] = {0.f, 0.f, 0.f, 0.f};
  int k0 = l, k1 = l + 16;
  float acc[4][2];

  if (deg <= 64) {
    for (int s = l; s < deg; s += 16) {
      int j = col[beg + s];
      colb[g][s] = j;
      float4 aj = *(const float4*)(a_s + (size_t)j * 4);
      float e0 = lrelu(aj.x + ad[0], 0.2f);
      float e1 = lrelu(aj.y + ad[1], 0.2f);
      float e2 = lrelu(aj.z + ad[2], 0.2f);
      float e3 = lrelu(aj.w + ad[3], 0.2f);
      eb[g][s] = make_float4(e0, e1, e2, e3);
      mx[0] = fmaxf(mx[0], e0); mx[1] = fmaxf(mx[1], e1);
      mx[2] = fmaxf(mx[2], e2); mx[3] = fmaxf(mx[3], e3);
    }
#pragma unroll
    for (int off = 1; off < 16; off <<= 1)
#pragma unroll
      for (int h = 0; h < 4; ++h) mx[h] = fmaxf(mx[h], __shfl_xor(mx[h], off));
    for (int s = l; s < deg; s += 16) {
      float4 e4 = eb[g][s];
      float x0 = expf(e4.x - mx[0]), x1 = expf(e4.y - mx[1]);
      float x2 = expf(e4.z - mx[2]), x3 = expf(e4.w - mx[3]);
      eb[g][s] = make_float4(x0, x1, x2, x3);
      den[0] += x0; den[1] += x1; den[2] += x2; den[3] += x3;
    }
#pragma unroll
    for (int off = 1; off < 16; off <<= 1)
#pragma unroll
      for (int h = 0; h < 4; ++h) den[h] += __shfl_xor(den[h], off);
    float exS[4];
#pragma unroll
    for (int h = 0; h < 4; ++h) { exS[h] = expf(es[h] - mx[h]); den[h] += exS[h]; }
    float xs0 = x[(size_t)i * 32 + k0], xs1 = x[(size_t)i * 32 + k1];
#pragma unroll
    for (int h = 0; h < 4; ++h) { acc[h][0] = exS[h] * xs0; acc[h][1] = exS[h] * xs1; }
    for (int s = 0; s < deg; ++s) {
      int j = colb[g][s];
      float4 e4 = eb[g][s];
      float xv0 = x[(size_t)j * 32 + k0], xv1 = x[(size_t)j * 32 + k1];
      acc[0][0] += e4.x * xv0; acc[0][1] += e4.x * xv1;
      acc[1][0] += e4.y * xv0; acc[1][1] += e4.y * xv1;
      acc[2][0] += e4.z * xv0; acc[2][1] += e4.z * xv1;
      acc[3][0] += e4.w * xv0; acc[3][1] += e4.w * xv1;
    }
  } else {
    for (int s = l; s < deg; s += 16) {
      int j = col[beg + s];
      float4 aj = *(const float4*)(a_s + (size_t)j * 4);
      mx[0] = fmaxf(mx[0], lrelu(aj.x + ad[0], 0.2f));
      mx[1] = fmaxf(mx[1], lrelu(aj.y + ad[1], 0.2f));
      mx[2] = fmaxf(mx[2], lrelu(aj.z + ad[2], 0.2f));
      mx[3] = fmaxf(mx[3], lrelu(aj.w + ad[3], 0.2f));
    }
#pragma unroll
    for (int off = 1; off < 16; off <<= 1)
#pragma unroll
      for (int h = 0; h < 4; ++h) mx[h] = fmaxf(mx[h], __shfl_xor(mx[h], off));
    for (int s = l; s < deg; s += 16) {
      int j = col[beg + s];
      float4 aj = *(const float4*)(a_s + (size_t)j * 4);
      den[0] += expf(lrelu(aj.x + ad[0], 0.2f) - mx[0]);
      den[1] += expf(lrelu(aj.y + ad[1], 0.2f) - mx[1]);
      den[2] += expf(lrelu(aj.z + ad[2], 0.2f) - mx[2]);
      den[3] += expf(lrelu(aj.w + ad[3], 0.2f) - mx[3]);
    }
#pragma unroll
    for (int off = 1; off < 16; off <<= 1)
#pragma unroll
      for (int h = 0; h < 4; ++h) den[h] += __shfl_xor(den[h], off);
    float exS[4];
#pragma unroll
    for (int h = 0; h < 4; ++h) { exS[h] = expf(es[h] - mx[h]); den[h] += exS[h]; }
    float xs0 = x[(size_t)i * 32 + k0], xs1 = x[(size_t)i * 32 + k1];
#pragma unroll
    for (int h = 0; h < 4; ++h) { acc[h][0] = exS[h] * xs0; acc[h][1] = exS[h] * xs1; }
    for (int s = 0; s < deg; ++s) {
      int j = col[beg + s];
      float4 aj = *(const float4*)(a_s + (size_t)j * 4);
      float xv0 = x[(size_t)j * 32 + k0], xv1 = x[(size_t)j * 32 + k1];
      acc[0][0] += expf(lrelu(aj.x + ad[0], 0.2f) - mx[0]) * xv0;
      acc[0][1] += expf(lrelu(aj.x + ad[0], 0.2f) - mx[0]) * xv1;
      acc[1][0] += expf(lrelu(aj.y + ad[1], 0.2f) - mx[1]) * xv0;
      acc[1][1] += expf(lrelu(aj.y + ad[1], 0.2f) - mx[1]) * xv1;
      acc[2][0] += expf(lrelu(aj.z + ad[2], 0.2f) - mx[2]) * xv0;
      acc[2][1] += expf(lrelu(aj.z + ad[2], 0.2f) - mx[2]) * xv1;
      acc[3][0] += expf(lrelu(aj.w + ad[3], 0.2f) - mx[3]) * xv0;
      acc[3][1] += expf(lrelu(aj.w + ad[3], 0.2f) - mx[3]) * xv1;
    }
  }
#pragma unroll
  for (int h = 0; h < 4; ++h) {
    agg[(size_t)i * 128 + h * 32 + k0] = acc[h][0] / den[h];
    agg[(size_t)i * 128 + h * 32 + k1] = acc[h][1] / den[h];
  }
}

// ---------------- L4 epilogue v3: 16 rows/block, 4 partial accumulators ----------------
__global__ __launch_bounds__(256) void k_l4_out(const float* agg, const void* W4, const void* b4,
                                                float* xout, const int* flg) {
  int f = flg[0];
  __shared__ float Wl[32 * 256];   // 32 KB
  __shared__ float Al[16 * 128];   // 8 KB
  int tid = threadIdx.x;
  int R0 = blockIdx.x * 16;
  for (int t = tid; t < 32 * 256; t += 256) Wl[t] = LD(W4, t, f);
  {
    const float4* ag4 = (const float4*)(agg + (size_t)R0 * 128);
    float4* Al4 = (float4*)Al;
    for (int t = tid; t < 512; t += 256) Al4[t] = ag4[t];
  }
  __syncthreads();
  int c = tid & 63, q = tid >> 6;
  float bv = LD(b4, c, f);
#pragma unroll
  for (int rr = 0; rr < 4; ++rr) {
    int r = q * 4 + rr;
    float p0 = 0.f, p1 = 0.f, p2 = 0.f, p3 = 0.f;
#pragma unroll
    for (int h = 0; h < 4; ++h) {
      const float* al = &Al[r * 128 + h * 32];
      const float* wl = &Wl[h * 64 + c];
#pragma unroll
      for (int kq = 0; kq < 8; ++kq) {
        p0 += al[kq * 4 + 0] * wl[(kq * 4 + 0) * 256];
        p1 += al[kq * 4 + 1] * wl[(kq * 4 + 1) * 256];
        p2 += al[kq * 4 + 2] * wl[(kq * 4 + 2) * 256];
        p3 += al[kq * 4 + 3] * wl[(kq * 4 + 3) * 256];
      }
    }
    float v = 0.25f * ((p0 + p1) + (p2 + p3)) + bv;
    xout[(size_t)(R0 + r) * 64 + c] = lrelu(v, 0.01f);
  }
}

// ---------------- pooling attention head ----------------
__global__ void k_wqk(const void* wq, const void* wk, const void* ws, float* wqv, float* wkv,
                      const int* flg) {
  int f = flg[0];
  int t = threadIdx.x;  // 256
  int h = t >> 6, d = t & 63;
  float q = 0.f, k = 0.f;
  for (int e = 0; e < 64; ++e) {
    q += LD(wq, h * 4096 + d * 64 + e, f) * LD(ws, h * 128 + e, f);
    k += LD(wk, h * 4096 + d * 64 + e, f) * LD(ws, h * 128 + 64 + e, f);
  }
  wqv[h * 64 + d] = q;
  wkv[h * 64 + d] = k;
}
__global__ void k_qk(const float* xfin, const float* wqv, const float* wkv, float* qs, float* ks) {
  int t = blockIdx.x * blockDim.x + threadIdx.x;
  if (t >= NF * 4) return;
  int n = t >> 2, h = t & 3;
  const float* row = xfin + (size_t)(NV + n) * 64;
  float q = 0.f, k = 0.f;
  for (int d = 0; d < 64; ++d) {
    float v = row[d];
    q += v * wqv[h * 64 + d];
    k += v * wkv[h * 64 + d];
  }
  qs[t] = q;
  ks[t] = k;
}

__global__ void k_groups(const int* full, const void* mask, const int* tgt, const int* mult,
                         const float* qs, const float* ks, const void* att_b, void* outv,
                         const int* flg) {
  int f = flg[0], mbyte = flg[1];
  int g = blockIdx.x;
  int lane = threadIdx.x;  // 64 = 16 k * 4 h
  int k = lane >> 2, h = lane & 3;
  int t = tgt[g];
  int idx = full[g * KK + k];
  int mk = MK(mask, g * KK + k, mbyte);
  float bh = LD(att_b, h, f);
  float qt = qs[t * 4 + h];
  float sc = sigm(qt + ks[idx * 4 + h] + bh);
  int is_tgt = (idx == t) && mk;
  int nbr = mk && !is_tgt;
  unsigned long long bal = __ballot(nbr != 0);
  int degm1 = (int)(__popcll(bal) >> 2);
  float ssum = nbr ? sc : 0.f;
  for (int off = 4; off < 64; off <<= 1) ssum += __shfl_xor(ssum, off);
  ssum /= (float)(degm1 > 1 ? degm1 : 1);
  float trg = sigm(qt + ks[t * 4 + h] + bh);
  float mxv = fmaxf(ssum, trg);
  float e0 = expf(ssum - mxv), e1 = expf(trg - mxv);
  float tw0 = e0 / (e0 + e1), tw1 = e1 / (e0 + e1);
  float msc = nbr ? sc : -1e30f;
  float m = msc;
  for (int off = 4; off < 64; off <<= 1) m = fmaxf(m, __shfl_xor(m, off));
  float ex = expf(msc - m);
  float den = ex;
  for (int off = 4; off < 64; off <<= 1) den += __shfl_xor(den, off);
  float w = ex / den * tw0 * (float)mult[g];
  float res = is_tgt ? tw1 : (nbr ? w : 0.f);
  if (degm1 == 0) res = 0.f;
  ST(outv, g * 64 + k * 4 + h, f, res);
}

extern "C" void kernel_launch(void* const* d_in, const int* in_sizes, int n_in,
                              void* d_out, int out_size, void* d_ws, size_t ws_size,
                              hipStream_t stream) {
  const int* edge = (const int*)d_in[0];
  const int* esrc = edge;
  const int* edst = edge + EE;
  const int* vn_colors = (const int*)d_in[1];
  const int* group_full = (const int*)d_in[2];
  const void* group_mask = d_in[3];
  const int* group_tgt = (const int*)d_in[4];
  const int* group_mult = (const int*)d_in[5];
  const void* vn_prefix = d_in[6];
  const void* fn_embed = d_in[7];
  const void* v2f_msgs = d_in[8];
  const void* v2f_hidden = d_in[9];
  const void* f2v_msgs = d_in[10];
  const void* f2v_hidden = d_in[11];
  const void* msg_prefix = d_in[12];
  const void* emb = d_in[13];
  const void* gv_wih = d_in[14];
  const void* gv_whh = d_in[15];
  const void* gv_bih = d_in[16];
  const void* gv_bhh = d_in[17];
  const void* gf_wih = d_in[18];
  const void* gf_whh = d_in[19];
  const void* gf_bih = d_in[20];
  const void* gf_bhh = d_in[21];
  const void* W1 = d_in[22];
  const void* a1s = d_in[23];
  const void* a1d = d_in[24];
  const void* b1 = d_in[25];
  const void* W2 = d_in[26];
  const void* a2s = d_in[27];
  const void* a2d = d_in[28];
  const void* b2 = d_in[29];
  const void* W3 = d_in[30];
  const void* a3s = d_in[31];
  const void* a3d = d_in[32];
  const void* b3 = d_in[33];
  const void* W4 = d_in[34];
  const void* a4s = d_in[35];
  const void* a4d = d_in[36];
  const void* b4 = d_in[37];
  const void* att_wq = d_in[38];
  const void* att_wk = d_in[39];
  const void* att_ws = d_in[40];
  const void* att_b = d_in[41];

  char* w = (char*)d_ws;
  size_t off = 0;
  auto carve = [&](size_t bytes) -> void* {
    void* p = w + off;
    off += (bytes + 255) & ~(size_t)255;
    return p;
  };
  int* flags = (int*)carve(16);
  float* Wt = (float*)carve((size_t)2 * 77 * 192 * 4);
  float* hidcat = (float*)carve((size_t)2 * NM * EMB * 4);
  float* xA = (float*)carve((size_t)NN * 64 * 4);
  float* xB = (float*)carve((size_t)NN * 64 * 4);
  float* scr = (float*)carve((size_t)NN * 128 * 4);  // xl (N x 32) or agg (N x 128)
  float* a_s = (float*)carve((size_t)NN * 4 * 4);
  float* a_d = (float*)carve((size_t)NN * 4 * 4);
  int* deg = (int*)carve((size_t)NN * 4);
  int* rowptr = (int*)carve((size_t)(NN + 1) * 4);
  int* cnt = (int*)carve((size_t)NN * 4);
  int* bsum = (int*)carve(128 * 4);
  int* boff = (int*)carve(128 * 4);
  int* col = (int*)carve((size_t)EE * 4);
  float* qs = (float*)carve((size_t)NF * 4 * 4);
  float* ks = (float*)carve((size_t)NF * 4 * 4);
  float* wqv = (float*)carve(256 * 4);
  float* wkv = (float*)carve(256 * 4);
  float* waS = (float*)carve(128 * 4);
  float* waD = (float*)carve(128 * 4);

  hipMemsetAsync(deg, 0, (size_t)NN * 4, stream);
  hipMemsetAsync(cnt, 0, (size_t)NN * 4, stream);

  k_detect<<<1, 64, 0, stream>>>(fn_embed, group_mask, flags);
  k_wtr<<<(2 * 77 * 192 + 255) / 256, 256, 0, stream>>>(gv_wih, gv_whh, gf_wih, gf_whh, Wt, flags);
  k_gru2<<<384, 256, 0, stream>>>(v2f_msgs, v2f_hidden, f2v_msgs, f2v_hidden,
                                  gv_bih, gv_bhh, gf_bih, gf_bhh, Wt, hidcat, d_out, flags);
  k_assemble<<<(NN * 64) / 256, 256, 0, stream>>>(vn_prefix, vn_colors, emb, fn_embed,
                                                  msg_prefix, hidcat, xA, flags);
  k_deg<<<EE / 256, 256, 0, stream>>>(edst, deg);
  k_scan1<<<72, 512, 0, stream>>>(deg, rowptr, bsum);
  k_scan2<<<1, 128, 0, stream>>>(bsum, boff, 72);
  k_scan3<<<(NN + 256) / 256, 256, 0, stream>>>(rowptr, boff);
  k_fill<<<EE / 256, 256, 0, stream>>>(esrc, edst, rowptr, cnt, col);

  // L1: 64 -> 32
  k_xl<64><<<NN / 8, 256, 0, stream>>>(xA, W1, scr, NN, flags);
  k_coef13<<<NN * 4 / 256, 256, 0, stream>>>(scr, a1s, a1d, a_s, a_d, flags);
  k_gather13<<<NN / 16, 256, 0, stream>>>(rowptr, col, a_s, a_d, scr, b1, xB, flags);
  // L2: 32 -> 32
  k_xl<32><<<NN / 8, 256, 0, stream>>>(xB, W2, scr, NN, flags);
  k_coef13<<<NN * 4 / 256, 256, 0, stream>>>(scr, a2s, a2d, a_s, a_d, flags);
  k_gather13<<<NN / 16, 256, 0, stream>>>(rowptr, col, a_s, a_d, scr, b2, xA, flags);
  // L3: 32 -> 32
  k_xl<32><<<NN / 8, 256, 0, stream>>>(xA, W3, scr, NN, flags);
  k_coef13<<<NN * 4 / 256, 256, 0, stream>>>(scr, a3s, a3d, a_s, a_d, flags);
  k_gather13<<<NN / 16, 256, 0, stream>>>(rowptr, col, a_s, a_d, scr, b3, xB, flags);
  // L4: 32 -> (4 heads x 64), mean
  k_waSD<<<1, 256, 0, stream>>>(W4, a4s, a4d, waS, waD, flags);
  k_coef4<<<NN * 4 / 256, 256, 0, stream>>>(xB, waS, waD, a_s, a_d);
  k_gather4<<<NN / 16, 256, 0, stream>>>(rowptr, col, a_s, a_d, xB, scr);
  k_l4_out<<<NN / 16, 256, 0, stream>>>(scr, W4, b4, xA, flags);

  k_wqk<<<1, 256, 0, stream>>>(att_wq, att_wk, att_ws, wqv, wkv, flags);
  k_qk<<<(NF * 4) / 256, 256, 0, stream>>>(xA, wqv, wkv, qs, ks);
  k_groups<<<GG, 64, 0, stream>>>(group_full, group_mask, group_tgt, group_mult,
                                  qs, ks, att_b, d_out, flags);
}

// Round 6
// 297.028 us; speedup vs baseline: 4.4930x; 1.2216x over previous
//
#include <hip/hip_runtime.h>
#include <hip/hip_bf16.h>

#define NV 8192
#define NF 4096
#define NM 12288
#define PFX 3
#define DOM 16
#define EMB 61
#define NN 36864
#define EE 262144
#define GG 8192
#define KK 16
#define OUT0 524288

typedef __hip_bfloat16 bf16;
__device__ __forceinline__ float b2f(bf16 x) { return __bfloat162float(x); }
__device__ __forceinline__ float lrelu(float x, float s) { return x > 0.f ? x : s * x; }
__device__ __forceinline__ float sigm(float x) { return 1.f / (1.f + expf(-x)); }
// flag-dispatched load/store: f=1 -> float32 buffers, f=0 -> bf16 buffers
__device__ __forceinline__ float LD(const void* p, int i, int f) {
  return f ? ((const float*)p)[i] : b2f(((const bf16*)p)[i]);
}
__device__ __forceinline__ void ST(void* p, int i, int f, float v) {
  if (f) ((float*)p)[i] = v; else ((bf16*)p)[i] = __float2bfloat16(v);
}
__device__ __forceinline__ int MK(const void* p, int i, int bytey) {
  return bytey ? (int)((const signed char*)p)[i] : ((const int*)p)[i];
}

// -------- dtype detector: flags[0]=floats are f32, flags[1]=mask is byte-bool --------
__global__ void k_detect(const void* fn, const void* mask, int* flags) {
  if (threadIdx.x || blockIdx.x) return;
  int wild = 0;
  const bf16* h = (const bf16*)fn;
  for (int i = 0; i < 128; ++i) {
    float x = b2f(h[i]);
    float a = fabsf(x);
    if (a != a || a > 1e4f || (x != 0.f && a < 1e-8f)) ++wild;
  }
  flags[0] = (wild >= 8) ? 1 : 0;
  const int* mi = (const int*)mask;
  int bytey = 0;
  for (int i = 0; i < 64; ++i) {
    unsigned v = (unsigned)mi[i];
    if (v > 1u) bytey = 1;
  }
  flags[1] = bytey;
}

// -------- transpose GRU weights into Wt[dir][d][192] (d-major, o padded 183->192) --------
__global__ void k_wtr(const void* gv_wih, const void* gv_whh,
                      const void* gf_wih, const void* gf_whh, float* Wt, const int* flg) {
  int f = flg[0];
  int t = blockIdx.x * blockDim.x + threadIdx.x;
  if (t >= 2 * 77 * 192) return;
  int dir = t / (77 * 192);
  int rem = t - dir * 77 * 192;
  int d = rem / 192, o = rem - d * 192;
  const void* wih = dir ? gf_wih : gv_wih;
  const void* whh = dir ? gf_whh : gv_whh;
  float v = 0.f;
  if (o < 183) v = (d < 16) ? LD(wih, o * 16 + d, f) : LD(whh, o * 61 + (d - 16), f);
  Wt[t] = v;
}

// ---------------- GRU v2: register-tiled, 64 rows/block ----------------
__global__ __launch_bounds__(256) void k_gru2(
    const void* v2f_msgs, const void* v2f_hid, const void* f2v_msgs, const void* f2v_hid,
    const void* gv_bih, const void* gv_bhh, const void* gf_bih, const void* gf_bhh,
    const float* Wt, float* hidcat, void* outv, const int* flg) {
  int f = flg[0];
  int blk = blockIdx.x;
  int dir = blk >= 192;
  int loc = dir ? blk - 192 : blk;
  int gr0 = loc * 64;
  const void* msgs = dir ? f2v_msgs : v2f_msgs;
  const void* hid = dir ? f2v_hid : v2f_hid;
  const void* bih = dir ? gf_bih : gv_bih;
  const void* bhh = dir ? gf_bhh : gv_bhh;
  const float* W = Wt + dir * 77 * 192;

  __shared__ float smem[15616];  // 62464 B
  float* F = smem;
  float* G1 = smem;                 // [r*183 + o]
  float* G2 = smem + 64 * 183;      // [r*61 + j]

  int tid = threadIdx.x;
  for (int idx = tid; idx < 64 * 16; idx += 256) {
    int r = idx >> 4, d = idx & 15;
    F[d * 64 + r] = LD(msgs, (gr0 + r) * DOM + d, f);
  }
  for (int idx = tid; idx < 64 * 61; idx += 256) {
    int r = idx / 61, d = idx - r * 61;
    F[(16 + d) * 64 + r] = LD(hid, gr0 * 61 + idx, f);
  }
  __syncthreads();

  int og = tid & 15, rg = tid >> 4;
  int o0 = og * 12, r0 = rg * 4;
  float accA[48], accB[48];
#pragma unroll
  for (int i = 0; i < 48; ++i) { accA[i] = 0.f; accB[i] = 0.f; }

#pragma unroll 2
  for (int d = 0; d < 16; ++d) {
    const float4 fv4 = *(const float4*)&F[d * 64 + r0];
    const float4 w0 = *(const float4*)&W[d * 192 + o0];
    const float4 w1 = *(const float4*)&W[d * 192 + o0 + 4];
    const float4 w2 = *(const float4*)&W[d * 192 + o0 + 8];
    float fv[4] = {fv4.x, fv4.y, fv4.z, fv4.w};
    float wv[12] = {w0.x, w0.y, w0.z, w0.w, w1.x, w1.y, w1.z, w1.w, w2.x, w2.y, w2.z, w2.w};
#pragma unroll
    for (int k = 0; k < 12; ++k)
#pragma unroll
      for (int m = 0; m < 4; ++m) accA[k * 4 + m] += wv[k] * fv[m];
  }
#pragma unroll 2
  for (int d = 16; d < 77; ++d) {
    const float4 fv4 = *(const float4*)&F[d * 64 + r0];
    const float4 w0 = *(const float4*)&W[d * 192 + o0];
    const float4 w1 = *(const float4*)&W[d * 192 + o0 + 4];
    const float4 w2 = *(const float4*)&W[d * 192 + o0 + 8];
    float fv[4] = {fv4.x, fv4.y, fv4.z, fv4.w};
    float wv[12] = {w0.x, w0.y, w0.z, w0.w, w1.x, w1.y, w1.z, w1.w, w2.x, w2.y, w2.z, w2.w};
#pragma unroll
    for (int k = 0; k < 12; ++k)
#pragma unroll
      for (int m = 0; m < 4; ++m) accB[k * 4 + m] += wv[k] * fv[m];
  }
  __syncthreads();

#pragma unroll
  for (int k = 0; k < 12; ++k) {
    int o = o0 + k;
    if (o < 183) {
      float biv = LD(bih, o, f), bhv = LD(bhh, o, f);
#pragma unroll
      for (int m = 0; m < 4; ++m) {
        int r = r0 + m;
        float gi = accA[k * 4 + m] + biv;
        float gh = accB[k * 4 + m] + bhv;
        if (o < 122) G1[r * 183 + o] = gi + gh;
        else { G1[r * 183 + o] = gi; G2[r * 61 + (o - 122)] = gh; }
      }
    }
  }
  __syncthreads();

  int j = tid & 63, rq = tid >> 6;
  if (j < 61) {
    for (int rr = 0; rr < 16; ++rr) {
      int r = rq * 16 + rr;
      float gr = sigm(G1[r * 183 + j]);
      float gz = sigm(G1[r * 183 + 61 + j]);
      float gn = tanhf(G1[r * 183 + 122 + j] + gr * G2[r * 61 + j]);
      float hold = LD(hid, (gr0 + r) * 61 + j, f);
      float hn = (1.f - gz) * gn + gz * hold;
      int b = dir * NM + gr0 + r;
      hidcat[b * 61 + j] = hn;
      ST(outv, OUT0 + b * 61 + j, f, hn);
    }
  }
}

// ---------------- assemble x (NN x 64 fp32) ----------------
__global__ void k_assemble(const void* vn_prefix, const int* vn_colors, const void* emb,
                           const void* fn_embed, const void* msg_prefix,
                           const float* hidcat, float* x, const int* flg) {
  int f = flg[0];
  int t = blockIdx.x * blockDim.x + threadIdx.x;
  if (t >= NN * 64) return;
  int i = t >> 6, c = t & 63;
  float v;
  if (i < NV) {
    v = (c < PFX) ? LD(vn_prefix, i * PFX + c, f) : LD(emb, vn_colors[i] * EMB + (c - PFX), f);
  } else if (i < NV + NF) {
    v = LD(fn_embed, (i - NV) * 64 + c, f);
  } else {
    int j = i - NV - NF;
    v = (c < PFX) ? LD(msg_prefix, j * PFX + c, f) : hidcat[j * EMB + (c - PFX)];
  }
  x[t] = v;
}

// ---------------- CSR build (by dst) ----------------
__global__ void k_deg(const int* dst, int* deg) {
  int e = blockIdx.x * blockDim.x + threadIdx.x;
  if (e < EE) atomicAdd(&deg[dst[e]], 1);
}
__global__ void k_scan1(const int* deg, int* rowptr, int* bsum) {
  __shared__ int s[512];
  int g = blockIdx.x * 512 + threadIdx.x;
  int v = (g < NN) ? deg[g] : 0;
  s[threadIdx.x] = v;
  __syncthreads();
  for (int off = 1; off < 512; off <<= 1) {
    int t = (threadIdx.x >= off) ? s[threadIdx.x - off] : 0;
    __syncthreads();
    s[threadIdx.x] += t;
    __syncthreads();
  }
  if (g < NN) rowptr[g] = s[threadIdx.x] - v;
  if (threadIdx.x == 511) bsum[blockIdx.x] = s[511];
}
__global__ void k_scan2(const int* bsum, int* boff, int nb) {
  __shared__ int s[128];
  int v = (threadIdx.x < nb) ? bsum[threadIdx.x] : 0;
  s[threadIdx.x] = v;
  __syncthreads();
  for (int off = 1; off < 128; off <<= 1) {
    int t = (threadIdx.x >= off) ? s[threadIdx.x - off] : 0;
    __syncthreads();
    s[threadIdx.x] += t;
    __syncthreads();
  }
  if (threadIdx.x < nb) boff[threadIdx.x] = s[threadIdx.x] - v;
}
__global__ void k_scan3(int* rowptr, const int* boff) {
  int g = blockIdx.x * blockDim.x + threadIdx.x;
  if (g < NN) rowptr[g] += boff[g >> 9];
  if (g == 0) rowptr[NN] = EE;
}
__global__ void k_fill(const int* src, const int* dst, const int* rowptr, int* cnt, int* col) {
  int e = blockIdx.x * blockDim.x + threadIdx.x;
  if (e < EE) {
    int d = dst[e];
    int pos = rowptr[d] + atomicAdd(&cnt[d], 1);
    col[pos] = src[e];
  }
}

// ---------------- xl = x @ W (IC -> 32), W staged in LDS ----------------
template <int IC>
__global__ void k_xl(const float* x, const void* W, float* xl, int n, const int* flg) {
  int f = flg[0];
  __shared__ float Wl[IC * 32];
  for (int t = threadIdx.x; t < IC * 32; t += blockDim.x) Wl[t] = LD(W, t, f);
  __syncthreads();
  int j = threadIdx.x & 31;
  int r = threadIdx.x >> 5;
  int i = blockIdx.x * 8 + r;
  if (i >= n) return;
  const float* xr = x + (size_t)i * IC;
  float acc = 0.f;
  for (int k = 0; k < IC; ++k) acc += xr[k] * Wl[k * 32 + j];
  xl[i * 32 + j] = acc;
}

// ---------------- attention coefficients ----------------
__global__ void k_coef13(const float* xl, const void* as_, const void* ad_,
                         float* a_s, float* a_d, const int* flg) {
  int f = flg[0];
  int t = blockIdx.x * blockDim.x + threadIdx.x;
  if (t >= NN * 4) return;
  int i = t >> 2, h = t & 3;
  float ss = 0.f, dd = 0.f;
  for (int c = 0; c < 8; ++c) {
    float v = xl[i * 32 + h * 8 + c];
    ss += v * LD(as_, h * 8 + c, f);
    dd += v * LD(ad_, h * 8 + c, f);
  }
  a_s[t] = ss;
  a_d[t] = dd;
}
__global__ void k_waSD(const void* W4, const void* a4s, const void* a4d, float* waS, float* waD,
                       const int* flg) {
  int f = flg[0];
  int t = threadIdx.x;  // 256
  int isD = t >= 128;
  int u = t & 127;
  int h = u >> 5, k = u & 31;
  const void* av = isD ? a4d : a4s;
  float acc = 0.f;
  for (int c = 0; c < 64; ++c) acc += LD(W4, k * 256 + h * 64 + c, f) * LD(av, h * 64 + c, f);
  (isD ? waD : waS)[h * 32 + k] = acc;
}
__global__ void k_coef4(const float* x, const float* waS, const float* waD, float* a_s, float* a_d) {
  int t = blockIdx.x * blockDim.x + threadIdx.x;
  if (t >= NN * 4) return;
  int i = t >> 2, h = t & 3;
  float ss = 0.f, dd = 0.f;
  for (int k = 0; k < 32; ++k) {
    float v = x[i * 32 + k];
    ss += v * waS[h * 32 + k];
    dd += v * waD[h * 32 + k];
  }
  a_s[t] = ss;
  a_d[t] = dd;
}

// ---------------- GAT gather v2, layers 1-3: 16 nodes/block, 16 lanes/node ----------------
__global__ __launch_bounds__(256) void k_gather13(const int* rowptr, const int* col,
                                                  const float* a_s, const float* a_d,
                                                  const float* xl, const void* bias,
                                                  float* xout, const int* flg) {
  int f = flg[0];
  __shared__ int colb[16][64];
  __shared__ float4 eb[16][64];
  int tid = threadIdx.x;
  int g = tid >> 4, l = tid & 15;
  int i = blockIdx.x * 16 + g;
  int beg = rowptr[i], end = rowptr[i + 1];
  int deg = end - beg;
  float4 adv = *(const float4*)(a_d + (size_t)i * 4);
  float4 asv = *(const float4*)(a_s + (size_t)i * 4);
  float ad[4] = {adv.x, adv.y, adv.z, adv.w};
  float es[4], mx[4];
  {
    float asl[4] = {asv.x, asv.y, asv.z, asv.w};
#pragma unroll
    for (int h = 0; h < 4; ++h) { es[h] = lrelu(asl[h] + ad[h], 0.2f); mx[h] = es[h]; }
  }
  float den[4] = {0.f, 0.f, 0.f, 0.f};
  int c0 = l, c1 = l + 16;
  int h0 = l >> 3, h1 = 2 + (l >> 3);
  float acc0, acc1;

  if (deg <= 64) {
    // phase A: one global read of a_s per edge; cache col + e[4] in LDS
    for (int s = l; s < deg; s += 16) {
      int j = col[beg + s];
      colb[g][s] = j;
      float4 aj = *(const float4*)(a_s + (size_t)j * 4);
      float e0 = lrelu(aj.x + ad[0], 0.2f);
      float e1 = lrelu(aj.y + ad[1], 0.2f);
      float e2 = lrelu(aj.z + ad[2], 0.2f);
      float e3 = lrelu(aj.w + ad[3], 0.2f);
      eb[g][s] = make_float4(e0, e1, e2, e3);
      mx[0] = fmaxf(mx[0], e0); mx[1] = fmaxf(mx[1], e1);
      mx[2] = fmaxf(mx[2], e2); mx[3] = fmaxf(mx[3], e3);
    }
#pragma unroll
    for (int off = 1; off < 16; off <<= 1)
#pragma unroll
      for (int h = 0; h < 4; ++h) mx[h] = fmaxf(mx[h], __shfl_xor(mx[h], off));
    // phase B: exp in LDS, partial den
    for (int s = l; s < deg; s += 16) {
      float4 e4 = eb[g][s];
      float x0 = expf(e4.x - mx[0]), x1 = expf(e4.y - mx[1]);
      float x2 = expf(e4.z - mx[2]), x3 = expf(e4.w - mx[3]);
      eb[g][s] = make_float4(x0, x1, x2, x3);
      den[0] += x0; den[1] += x1; den[2] += x2; den[3] += x3;
    }
#pragma unroll
    for (int off = 1; off < 16; off <<= 1)
#pragma unroll
      for (int h = 0; h < 4; ++h) den[h] += __shfl_xor(den[h], off);
    float exS[4];
#pragma unroll
    for (int h = 0; h < 4; ++h) { exS[h] = expf(es[h] - mx[h]); den[h] += exS[h]; }
    // phase C: channel-parallel accumulate
    acc0 = exS[h0] * xl[(size_t)i * 32 + c0];
    acc1 = exS[h1] * xl[(size_t)i * 32 + c1];
    for (int s = 0; s < deg; ++s) {
      int j = colb[g][s];
      float4 e4 = eb[g][s];
      float w0 = h0 ? e4.y : e4.x;
      float w1 = (l >> 3) ? e4.w : e4.z;
      acc0 += w0 * xl[(size_t)j * 32 + c0];
      acc1 += w1 * xl[(size_t)j * 32 + c1];
    }
  } else {
    // slow generic path (recompute)
    for (int s = l; s < deg; s += 16) {
      int j = col[beg + s];
      float4 aj = *(const float4*)(a_s + (size_t)j * 4);
      mx[0] = fmaxf(mx[0], lrelu(aj.x + ad[0], 0.2f));
      mx[1] = fmaxf(mx[1], lrelu(aj.y + ad[1], 0.2f));
      mx[2] = fmaxf(mx[2], lrelu(aj.z + ad[2], 0.2f));
      mx[3] = fmaxf(mx[3], lrelu(aj.w + ad[3], 0.2f));
    }
#pragma unroll
    for (int off = 1; off < 16; off <<= 1)
#pragma unroll
      for (int h = 0; h < 4; ++h) mx[h] = fmaxf(mx[h], __shfl_xor(mx[h], off));
    for (int s = l; s < deg; s += 16) {
      int j = col[beg + s];
      float4 aj = *(const float4*)(a_s + (size_t)j * 4);
      den[0] += expf(lrelu(aj.x + ad[0], 0.2f) - mx[0]);
      den[1] += expf(lrelu(aj.y + ad[1], 0.2f) - mx[1]);
      den[2] += expf(lrelu(aj.z + ad[2], 0.2f) - mx[2]);
      den[3] += expf(lrelu(aj.w + ad[3], 0.2f) - mx[3]);
    }
#pragma unroll
    for (int off = 1; off < 16; off <<= 1)
#pragma unroll
      for (int h = 0; h < 4; ++h) den[h] += __shfl_xor(den[h], off);
    float exS[4];
#pragma unroll
    for (int h = 0; h < 4; ++h) { exS[h] = expf(es[h] - mx[h]); den[h] += exS[h]; }
    acc0 = exS[h0] * xl[(size_t)i * 32 + c0];
    acc1 = exS[h1] * xl[(size_t)i * 32 + c1];
    for (int s = 0; s < deg; ++s) {
      int j = col[beg + s];
      float e0 = lrelu(a_s[(size_t)j * 4 + h0] + ad[h0], 0.2f);
      float e1 = lrelu(a_s[(size_t)j * 4 + h1] + ad[h1], 0.2f);
      acc0 += expf(e0 - mx[h0]) * xl[(size_t)j * 32 + c0];
      acc1 += expf(e1 - mx[h1]) * xl[(size_t)j * 32 + c1];
    }
  }
  float v0 = acc0 / den[h0] + LD(bias, c0, f);
  float v1 = acc1 / den[h1] + LD(bias, c1, f);
  xout[(size_t)i * 32 + c0] = lrelu(v0, 0.01f);
  xout[(size_t)i * 32 + c1] = lrelu(v1, 0.01f);
}

// ---------------- GAT gather v2, layer 4: aggregate x rows per head ----------------
__global__ __launch_bounds__(256) void k_gather4(const int* rowptr, const int* col,
                                                 const float* a_s, const float* a_d,
                                                 const float* x, float* agg) {
  __shared__ int colb[16][64];
  __shared__ float4 eb[16][64];
  int tid = threadIdx.x;
  int g = tid >> 4, l = tid & 15;
  int i = blockIdx.x * 16 + g;
  int beg = rowptr[i], end = rowptr[i + 1];
  int deg = end - beg;
  float4 adv = *(const float4*)(a_d + (size_t)i * 4);
  float4 asv = *(const float4*)(a_s + (size_t)i * 4);
  float ad[4] = {adv.x, adv.y, adv.z, adv.w};
  float es[4], mx[4];
  {
    float asl[4] = {asv.x, asv.y, asv.z, asv.w};
#pragma unroll
    for (int h = 0; h < 4; ++h) { es[h] = lrelu(asl[h] + ad[h], 0.2f); mx[h] = es[h]; }
  }
  float den[4] = {0.f, 0.f, 0.f, 0.f};
  int k0 = l, k1 = l + 16;
  float acc[4][2];

  if (deg <= 64) {
    for (int s = l; s < deg; s += 16) {
      int j = col[beg + s];
      colb[g][s] = j;
      float4 aj = *(const float4*)(a_s + (size_t)j * 4);
      float e0 = lrelu(aj.x + ad[0], 0.2f);
      float e1 = lrelu(aj.y + ad[1], 0.2f);
      float e2 = lrelu(aj.z + ad[2], 0.2f);
      float e3 = lrelu(aj.w + ad[3], 0.2f);
      eb[g][s] = make_float4(e0, e1, e2, e3);
      mx[0] = fmaxf(mx[0], e0); mx[1] = fmaxf(mx[1], e1);
      mx[2] = fmaxf(mx[2], e2); mx[3] = fmaxf(mx[3], e3);
    }
#pragma unroll
    for (int off = 1; off < 16; off <<= 1)
#pragma unroll
      for (int h = 0; h < 4; ++h) mx[h] = fmaxf(mx[h], __shfl_xor(mx[h], off));
    for (int s = l; s < deg; s += 16) {
      float4 e4 = eb[g][s];
      float x0 = expf(e4.x - mx[0]), x1 = expf(e4.y - mx[1]);
      float x2 = expf(e4.z - mx[2]), x3 = expf(e4.w - mx[3]);
      eb[g][s] = make_float4(x0, x1, x2, x3);
      den[0] += x0; den[1] += x1; den[2] += x2; den[3] += x3;
    }
#pragma unroll
    for (int off = 1; off < 16; off <<= 1)
#pragma unroll
      for (int h = 0; h < 4; ++h) den[h] += __shfl_xor(den[h], off);
    float exS[4];
#pragma unroll
    for (int h = 0; h < 4; ++h) { exS[h] = expf(es[h] - mx[h]); den[h] += exS[h]; }
    float xs0 = x[(size_t)i * 32 + k0], xs1 = x[(size_t)i * 32 + k1];
#pragma unroll
    for (int h = 0; h < 4; ++h) { acc[h][0] = exS[h] * xs0; acc[h][1] = exS[h] * xs1; }
    for (int s = 0; s < deg; ++s) {
      int j = colb[g][s];
      float4 e4 = eb[g][s];
      float xv0 = x[(size_t)j * 32 + k0], xv1 = x[(size_t)j * 32 + k1];
      acc[0][0] += e4.x * xv0; acc[0][1] += e4.x * xv1;
      acc[1][0] += e4.y * xv0; acc[1][1] += e4.y * xv1;
      acc[2][0] += e4.z * xv0; acc[2][1] += e4.z * xv1;
      acc[3][0] += e4.w * xv0; acc[3][1] += e4.w * xv1;
    }
  } else {
    for (int s = l; s < deg; s += 16) {
      int j = col[beg + s];
      float4 aj = *(const float4*)(a_s + (size_t)j * 4);
      mx[0] = fmaxf(mx[0], lrelu(aj.x + ad[0], 0.2f));
      mx[1] = fmaxf(mx[1], lrelu(aj.y + ad[1], 0.2f));
      mx[2] = fmaxf(mx[2], lrelu(aj.z + ad[2], 0.2f));
      mx[3] = fmaxf(mx[3], lrelu(aj.w + ad[3], 0.2f));
    }
#pragma unroll
    for (int off = 1; off < 16; off <<= 1)
#pragma unroll
      for (int h = 0; h < 4; ++h) mx[h] = fmaxf(mx[h], __shfl_xor(mx[h], off));
    for (int s = l; s < deg; s += 16) {
      int j = col[beg + s];
      float4 aj = *(const float4*)(a_s + (size_t)j * 4);
      den[0] += expf(lrelu(aj.x + ad[0], 0.2f) - mx[0]);
      den[1] += expf(lrelu(aj.y + ad[1], 0.2f) - mx[1]);
      den[2] += expf(lrelu(aj.z + ad[2], 0.2f) - mx[2]);
      den[3] += expf(lrelu(aj.w + ad[3], 0.2f) - mx[3]);
    }
#pragma unroll
    for (int off = 1; off < 16; off <<= 1)
#pragma unroll
      for (int h = 0; h < 4; ++h) den[h] += __shfl_xor(den[h], off);
    float exS[4];
#pragma unroll
    for (int h = 0; h < 4; ++h) { exS[h] = expf(es[h] - mx[h]); den[h] += exS[h]; }
    float xs0 = x[(size_t)i * 32 + k0], xs1 = x[(size_t)i * 32 + k1];
#pragma unroll
    for (int h = 0; h < 4; ++h) { acc[h][0] = exS[h] * xs0; acc[h][1] = exS[h] * xs1; }
    for (int s = 0; s < deg; ++s) {
      int j = col[beg + s];
      float4 aj = *(const float4*)(a_s + (size_t)j * 4);
      float xv0 = x[(size_t)j * 32 + k0], xv1 = x[(size_t)j * 32 + k1];
      acc[0][0] += expf(lrelu(aj.x + ad[0], 0.2f) - mx[0]) * xv0;
      acc[0][1] += expf(lrelu(aj.x + ad[0], 0.2f) - mx[0]) * xv1;
      acc[1][0] += expf(lrelu(aj.y + ad[1], 0.2f) - mx[1]) * xv0;
      acc[1][1] += expf(lrelu(aj.y + ad[1], 0.2f) - mx[1]) * xv1;
      acc[2][0] += expf(lrelu(aj.z + ad[2], 0.2f) - mx[2]) * xv0;
      acc[2][1] += expf(lrelu(aj.z + ad[2], 0.2f) - mx[2]) * xv1;
      acc[3][0] += expf(lrelu(aj.w + ad[3], 0.2f) - mx[3]) * xv0;
      acc[3][1] += expf(lrelu(aj.w + ad[3], 0.2f) - mx[3]) * xv1;
    }
  }
#pragma unroll
  for (int h = 0; h < 4; ++h) {
    agg[(size_t)i * 128 + h * 32 + k0] = acc[h][0] / den[h];
    agg[(size_t)i * 128 + h * 32 + k1] = acc[h][1] / den[h];
  }
}

// ---------------- L4 epilogue v4: register-blocked GEMM, 64 rows/block ----------------
// out[i,c] = lrelu( 0.25 * sum_K agg[i,K]*W'[K,c] + b4[c] ), K = h*32+k, W'[K,c]=W4[k,h*64+c]
__global__ __launch_bounds__(256) void k_l4_out(const float* agg, const void* W4, const void* b4,
                                                float* xout, const int* flg) {
  int f = flg[0];
  __shared__ float Wl[128 * 64];     // [K][c]          32 KB
  __shared__ float Al[64][132];      // [r][K] pad 132  33.8 KB
  int tid = threadIdx.x;
  int R0 = blockIdx.x * 64;
  for (int t = tid; t < 128 * 64; t += 256) {
    int K = t >> 6, c = t & 63;
    int h = K >> 5, k = K & 31;
    Wl[t] = LD(W4, k * 256 + h * 64 + c, f);
  }
  {
    const float4* ag4 = (const float4*)(agg + (size_t)R0 * 128);
    for (int t = tid; t < 2048; t += 256) {
      int r = t >> 5, k4 = (t & 31) << 2;
      float4 v = ag4[t];
      *(float4*)&Al[r][k4] = v;
    }
  }
  __syncthreads();
  int c0 = (tid & 15) << 2, r0 = (tid >> 4) << 2;
  float acc[4][4];
#pragma unroll
  for (int j = 0; j < 4; ++j)
#pragma unroll
    for (int i = 0; i < 4; ++i) acc[j][i] = 0.f;
#pragma unroll 4
  for (int K = 0; K < 128; ++K) {
    float4 wv = *(const float4*)&Wl[K * 64 + c0];
    float a0 = Al[r0][K], a1 = Al[r0 + 1][K], a2 = Al[r0 + 2][K], a3 = Al[r0 + 3][K];
    acc[0][0] += a0 * wv.x; acc[0][1] += a0 * wv.y; acc[0][2] += a0 * wv.z; acc[0][3] += a0 * wv.w;
    acc[1][0] += a1 * wv.x; acc[1][1] += a1 * wv.y; acc[1][2] += a1 * wv.z; acc[1][3] += a1 * wv.w;
    acc[2][0] += a2 * wv.x; acc[2][1] += a2 * wv.y; acc[2][2] += a2 * wv.z; acc[2][3] += a2 * wv.w;
    acc[3][0] += a3 * wv.x; acc[3][1] += a3 * wv.y; acc[3][2] += a3 * wv.z; acc[3][3] += a3 * wv.w;
  }
  float bv[4];
#pragma unroll
  for (int i = 0; i < 4; ++i) bv[i] = LD(b4, c0 + i, f);
#pragma unroll
  for (int j = 0; j < 4; ++j) {
    float4 o;
    o.x = lrelu(0.25f * acc[j][0] + bv[0], 0.01f);
    o.y = lrelu(0.25f * acc[j][1] + bv[1], 0.01f);
    o.z = lrelu(0.25f * acc[j][2] + bv[2], 0.01f);
    o.w = lrelu(0.25f * acc[j][3] + bv[3], 0.01f);
    *(float4*)&xout[(size_t)(R0 + r0 + j) * 64 + c0] = o;
  }
}

// ---------------- pooling attention head ----------------
__global__ void k_wqk(const void* wq, const void* wk, const void* ws, float* wqv, float* wkv,
                      const int* flg) {
  int f = flg[0];
  int t = threadIdx.x;  // 256
  int h = t >> 6, d = t & 63;
  float q = 0.f, k = 0.f;
  for (int e = 0; e < 64; ++e) {
    q += LD(wq, h * 4096 + d * 64 + e, f) * LD(ws, h * 128 + e, f);
    k += LD(wk, h * 4096 + d * 64 + e, f) * LD(ws, h * 128 + 64 + e, f);
  }
  wqv[h * 64 + d] = q;
  wkv[h * 64 + d] = k;
}
__global__ void k_qk(const float* xfin, const float* wqv, const float* wkv, float* qs, float* ks) {
  int t = blockIdx.x * blockDim.x + threadIdx.x;
  if (t >= NF * 4) return;
  int n = t >> 2, h = t & 3;
  const float* row = xfin + (size_t)(NV + n) * 64;
  float q = 0.f, k = 0.f;
  for (int d = 0; d < 64; ++d) {
    float v = row[d];
    q += v * wqv[h * 64 + d];
    k += v * wkv[h * 64 + d];
  }
  qs[t] = q;
  ks[t] = k;
}

__global__ void k_groups(const int* full, const void* mask, const int* tgt, const int* mult,
                         const float* qs, const float* ks, const void* att_b, void* outv,
                         const int* flg) {
  int f = flg[0], mbyte = flg[1];
  int g = blockIdx.x;
  int lane = threadIdx.x;  // 64 = 16 k * 4 h
  int k = lane >> 2, h = lane & 3;
  int t = tgt[g];
  int idx = full[g * KK + k];
  int mk = MK(mask, g * KK + k, mbyte);
  float bh = LD(att_b, h, f);
  float qt = qs[t * 4 + h];
  float sc = sigm(qt + ks[idx * 4 + h] + bh);
  int is_tgt = (idx == t) && mk;
  int nbr = mk && !is_tgt;
  unsigned long long bal = __ballot(nbr != 0);
  int degm1 = (int)(__popcll(bal) >> 2);
  float ssum = nbr ? sc : 0.f;
  for (int off = 4; off < 64; off <<= 1) ssum += __shfl_xor(ssum, off);
  ssum /= (float)(degm1 > 1 ? degm1 : 1);
  float trg = sigm(qt + ks[t * 4 + h] + bh);
  float mxv = fmaxf(ssum, trg);
  float e0 = expf(ssum - mxv), e1 = expf(trg - mxv);
  float tw0 = e0 / (e0 + e1), tw1 = e1 / (e0 + e1);
  float msc = nbr ? sc : -1e30f;
  float m = msc;
  for (int off = 4; off < 64; off <<= 1) m = fmaxf(m, __shfl_xor(m, off));
  float ex = expf(msc - m);
  float den = ex;
  for (int off = 4; off < 64; off <<= 1) den += __shfl_xor(den, off);
  float w = ex / den * tw0 * (float)mult[g];
  float res = is_tgt ? tw1 : (nbr ? w : 0.f);
  if (degm1 == 0) res = 0.f;
  ST(outv, g * 64 + k * 4 + h, f, res);
}

extern "C" void kernel_launch(void* const* d_in, const int* in_sizes, int n_in,
                              void* d_out, int out_size, void* d_ws, size_t ws_size,
                              hipStream_t stream) {
  const int* edge = (const int*)d_in[0];
  const int* esrc = edge;
  const int* edst = edge + EE;
  const int* vn_colors = (const int*)d_in[1];
  const int* group_full = (const int*)d_in[2];
  const void* group_mask = d_in[3];
  const int* group_tgt = (const int*)d_in[4];
  const int* group_mult = (const int*)d_in[5];
  const void* vn_prefix = d_in[6];
  const void* fn_embed = d_in[7];
  const void* v2f_msgs = d_in[8];
  const void* v2f_hidden = d_in[9];
  const void* f2v_msgs = d_in[10];
  const void* f2v_hidden = d_in[11];
  const void* msg_prefix = d_in[12];
  const void* emb = d_in[13];
  const void* gv_wih = d_in[14];
  const void* gv_whh = d_in[15];
  const void* gv_bih = d_in[16];
  const void* gv_bhh = d_in[17];
  const void* gf_wih = d_in[18];
  const void* gf_whh = d_in[19];
  const void* gf_bih = d_in[20];
  const void* gf_bhh = d_in[21];
  const void* W1 = d_in[22];
  const void* a1s = d_in[23];
  const void* a1d = d_in[24];
  const void* b1 = d_in[25];
  const void* W2 = d_in[26];
  const void* a2s = d_in[27];
  const void* a2d = d_in[28];
  const void* b2 = d_in[29];
  const void* W3 = d_in[30];
  const void* a3s = d_in[31];
  const void* a3d = d_in[32];
  const void* b3 = d_in[33];
  const void* W4 = d_in[34];
  const void* a4s = d_in[35];
  const void* a4d = d_in[36];
  const void* b4 = d_in[37];
  const void* att_wq = d_in[38];
  const void* att_wk = d_in[39];
  const void* att_ws = d_in[40];
  const void* att_b = d_in[41];

  char* w = (char*)d_ws;
  size_t off = 0;
  auto carve = [&](size_t bytes) -> void* {
    void* p = w + off;
    off += (bytes + 255) & ~(size_t)255;
    return p;
  };
  int* flags = (int*)carve(16);
  float* Wt = (float*)carve((size_t)2 * 77 * 192 * 4);
  float* hidcat = (float*)carve((size_t)2 * NM * EMB * 4);
  float* xA = (float*)carve((size_t)NN * 64 * 4);
  float* xB = (float*)carve((size_t)NN * 64 * 4);
  float* scr = (float*)carve((size_t)NN * 128 * 4);  // xl (N x 32) or agg (N x 128)
  float* a_s = (float*)carve((size_t)NN * 4 * 4);
  float* a_d = (float*)carve((size_t)NN * 4 * 4);
  int* deg = (int*)carve((size_t)NN * 4);
  int* rowptr = (int*)carve((size_t)(NN + 1) * 4);
  int* cnt = (int*)carve((size_t)NN * 4);
  int* bsum = (int*)carve(128 * 4);
  int* boff = (int*)carve(128 * 4);
  int* col = (int*)carve((size_t)EE * 4);
  float* qs = (float*)carve((size_t)NF * 4 * 4);
  float* ks = (float*)carve((size_t)NF * 4 * 4);
  float* wqv = (float*)carve(256 * 4);
  float* wkv = (float*)carve(256 * 4);
  float* waS = (float*)carve(128 * 4);
  float* waD = (float*)carve(128 * 4);

  hipMemsetAsync(deg, 0, (size_t)NN * 4, stream);
  hipMemsetAsync(cnt, 0, (size_t)NN * 4, stream);

  k_detect<<<1, 64, 0, stream>>>(fn_embed, group_mask, flags);
  k_wtr<<<(2 * 77 * 192 + 255) / 256, 256, 0, stream>>>(gv_wih, gv_whh, gf_wih, gf_whh, Wt, flags);
  k_gru2<<<384, 256, 0, stream>>>(v2f_msgs, v2f_hidden, f2v_msgs, f2v_hidden,
                                  gv_bih, gv_bhh, gf_bih, gf_bhh, Wt, hidcat, d_out, flags);
  k_assemble<<<(NN * 64) / 256, 256, 0, stream>>>(vn_prefix, vn_colors, emb, fn_embed,
                                                  msg_prefix, hidcat, xA, flags);
  k_deg<<<EE / 256, 256, 0, stream>>>(edst, deg);
  k_scan1<<<72, 512, 0, stream>>>(deg, rowptr, bsum);
  k_scan2<<<1, 128, 0, stream>>>(bsum, boff, 72);
  k_scan3<<<(NN + 256) / 256, 256, 0, stream>>>(rowptr, boff);
  k_fill<<<EE / 256, 256, 0, stream>>>(esrc, edst, rowptr, cnt, col);

  // L1: 64 -> 32
  k_xl<64><<<NN / 8, 256, 0, stream>>>(xA, W1, scr, NN, flags);
  k_coef13<<<NN * 4 / 256, 256, 0, stream>>>(scr, a1s, a1d, a_s, a_d, flags);
  k_gather13<<<NN / 16, 256, 0, stream>>>(rowptr, col, a_s, a_d, scr, b1, xB, flags);
  // L2: 32 -> 32
  k_xl<32><<<NN / 8, 256, 0, stream>>>(xB, W2, scr, NN, flags);
  k_coef13<<<NN * 4 / 256, 256, 0, stream>>>(scr, a2s, a2d, a_s, a_d, flags);
  k_gather13<<<NN / 16, 256, 0, stream>>>(rowptr, col, a_s, a_d, scr, b2, xA, flags);
  // L3: 32 -> 32
  k_xl<32><<<NN / 8, 256, 0, stream>>>(xA, W3, scr, NN, flags);
  k_coef13<<<NN * 4 / 256, 256, 0, stream>>>(scr, a3s, a3d, a_s, a_d, flags);
  k_gather13<<<NN / 16, 256, 0, stream>>>(rowptr, col, a_s, a_d, scr, b3, xB, flags);
  // L4: 32 -> (4 heads x 64), mean
  k_waSD<<<1, 256, 0, stream>>>(W4, a4s, a4d, waS, waD, flags);
  k_coef4<<<NN * 4 / 256, 256, 0, stream>>>(xB, waS, waD, a_s, a_d);
  k_gather4<<<NN / 16, 256, 0, stream>>>(rowptr, col, a_s, a_d, xB, scr);
  k_l4_out<<<NN / 64, 256, 0, stream>>>(scr, W4, b4, xA, flags);

  k_wqk<<<1, 256, 0, stream>>>(att_wq, att_wk, att_ws, wqv, wkv, flags);
  k_qk<<<(NF * 4) / 256, 256, 0, stream>>>(xA, wqv, wkv, qs, ks);
  k_groups<<<GG, 64, 0, stream>>>(group_full, group_mask, group_tgt, group_mult,
                                  qs, ks, att_b, d_out, flags);
}

// Round 7
// 279.761 us; speedup vs baseline: 4.7703x; 1.0617x over previous
//
#include <hip/hip_runtime.h>
#include <hip/hip_bf16.h>

#define NV 8192
#define NF 4096
#define NM 12288
#define PFX 3
#define DOM 16
#define EMB 61
#define NN 36864
#define EE 262144
#define GG 8192
#define KK 16
#define OUT0 524288

typedef __hip_bfloat16 bf16;
__device__ __forceinline__ float b2f(bf16 x) { return __bfloat162float(x); }
__device__ __forceinline__ float lrelu(float x, float s) { return x > 0.f ? x : s * x; }
__device__ __forceinline__ float sigm(float x) { return 1.f / (1.f + expf(-x)); }
// flag-dispatched load/store: f=1 -> float32 buffers, f=0 -> bf16 buffers
__device__ __forceinline__ float LD(const void* p, int i, int f) {
  return f ? ((const float*)p)[i] : b2f(((const bf16*)p)[i]);
}
__device__ __forceinline__ void ST(void* p, int i, int f, float v) {
  if (f) ((float*)p)[i] = v; else ((bf16*)p)[i] = __float2bfloat16(v);
}
__device__ __forceinline__ int MK(const void* p, int i, int bytey) {
  return bytey ? (int)((const signed char*)p)[i] : ((const int*)p)[i];
}

// -------- dtype detector: flags[0]=floats are f32, flags[1]=mask is byte-bool --------
__global__ void k_detect(const void* fn, const void* mask, int* flags) {
  if (threadIdx.x || blockIdx.x) return;
  int wild = 0;
  const bf16* h = (const bf16*)fn;
  for (int i = 0; i < 128; ++i) {
    float x = b2f(h[i]);
    float a = fabsf(x);
    if (a != a || a > 1e4f || (x != 0.f && a < 1e-8f)) ++wild;
  }
  flags[0] = (wild >= 8) ? 1 : 0;
  const int* mi = (const int*)mask;
  int bytey = 0;
  for (int i = 0; i < 64; ++i) {
    unsigned v = (unsigned)mi[i];
    if (v > 1u) bytey = 1;
  }
  flags[1] = bytey;
}

// -------- transpose GRU weights into Wt[dir][d][192] (d-major, o padded 183->192) --------
__global__ void k_wtr(const void* gv_wih, const void* gv_whh,
                      const void* gf_wih, const void* gf_whh, float* Wt, const int* flg) {
  int f = flg[0];
  int t = blockIdx.x * blockDim.x + threadIdx.x;
  if (t >= 2 * 77 * 192) return;
  int dir = t / (77 * 192);
  int rem = t - dir * 77 * 192;
  int d = rem / 192, o = rem - d * 192;
  const void* wih = dir ? gf_wih : gv_wih;
  const void* whh = dir ? gf_whh : gv_whh;
  float v = 0.f;
  if (o < 183) v = (d < 16) ? LD(wih, o * 16 + d, f) : LD(whh, o * 61 + (d - 16), f);
  Wt[t] = v;
}

// ---------------- GRU v3: 32 rows/block, grid 768 (3 blocks/CU) ----------------
// thread (og,rg): outputs o0=og*12..+11, rows r0=rg*2..+1
__global__ __launch_bounds__(256) void k_gru2(
    const void* v2f_msgs, const void* v2f_hid, const void* f2v_msgs, const void* f2v_hid,
    const void* gv_bih, const void* gv_bhh, const void* gf_bih, const void* gf_bhh,
    const float* Wt, float* hidcat, void* outv, const int* flg) {
  int f = flg[0];
  int blk = blockIdx.x;
  int dir = blk >= 384;
  int loc = dir ? blk - 384 : blk;
  int gr0 = loc * 32;
  const void* msgs = dir ? f2v_msgs : v2f_msgs;
  const void* hid = dir ? f2v_hid : v2f_hid;
  const void* bih = dir ? gf_bih : gv_bih;
  const void* bhh = dir ? gf_bhh : gv_bhh;
  const float* W = Wt + dir * 77 * 192;

  // F[77][36] (11088B) lives first; G1[32][183]+G2[32][61] (31232B) reuse the buffer.
  __shared__ float smem[7808];  // 31232 B
  float* F = smem;                  // stride 36: bank=(4d+r)%32, b64 reads aligned
  float* G1 = smem;                 // [r*183 + o]
  float* G2 = smem + 32 * 183;      // [r*61 + j]

  int tid = threadIdx.x;
  for (int idx = tid; idx < 32 * 16; idx += 256) {
    int r = idx >> 4, d = idx & 15;
    F[d * 36 + r] = LD(msgs, (gr0 + r) * DOM + d, f);
  }
  for (int idx = tid; idx < 32 * 61; idx += 256) {
    int r = idx / 61, d = idx - r * 61;
    F[(16 + d) * 36 + r] = LD(hid, gr0 * 61 + idx, f);
  }
  __syncthreads();

  int og = tid & 15, rg = tid >> 4;
  int o0 = og * 12, r0 = rg * 2;
  float accA[24], accB[24];
#pragma unroll
  for (int i = 0; i < 24; ++i) { accA[i] = 0.f; accB[i] = 0.f; }

#pragma unroll 2
  for (int d = 0; d < 16; ++d) {
    const float2 fv2 = *(const float2*)&F[d * 36 + r0];
    const float4 w0 = *(const float4*)&W[d * 192 + o0];
    const float4 w1 = *(const float4*)&W[d * 192 + o0 + 4];
    const float4 w2 = *(const float4*)&W[d * 192 + o0 + 8];
    float wv[12] = {w0.x, w0.y, w0.z, w0.w, w1.x, w1.y, w1.z, w1.w, w2.x, w2.y, w2.z, w2.w};
#pragma unroll
    for (int k = 0; k < 12; ++k) {
      accA[k * 2 + 0] += wv[k] * fv2.x;
      accA[k * 2 + 1] += wv[k] * fv2.y;
    }
  }
#pragma unroll 2
  for (int d = 16; d < 77; ++d) {
    const float2 fv2 = *(const float2*)&F[d * 36 + r0];
    const float4 w0 = *(const float4*)&W[d * 192 + o0];
    const float4 w1 = *(const float4*)&W[d * 192 + o0 + 4];
    const float4 w2 = *(const float4*)&W[d * 192 + o0 + 8];
    float wv[12] = {w0.x, w0.y, w0.z, w0.w, w1.x, w1.y, w1.z, w1.w, w2.x, w2.y, w2.z, w2.w};
#pragma unroll
    for (int k = 0; k < 12; ++k) {
      accB[k * 2 + 0] += wv[k] * fv2.x;
      accB[k * 2 + 1] += wv[k] * fv2.y;
    }
  }
  __syncthreads();  // F dead; G1/G2 may overwrite

#pragma unroll
  for (int k = 0; k < 12; ++k) {
    int o = o0 + k;
    if (o < 183) {
      float biv = LD(bih, o, f), bhv = LD(bhh, o, f);
#pragma unroll
      for (int m = 0; m < 2; ++m) {
        int r = r0 + m;
        float gi = accA[k * 2 + m] + biv;
        float gh = accB[k * 2 + m] + bhv;
        if (o < 122) G1[r * 183 + o] = gi + gh;
        else { G1[r * 183 + o] = gi; G2[r * 61 + (o - 122)] = gh; }
      }
    }
  }
  __syncthreads();

  int j = tid & 63, rq = tid >> 6;
  if (j < 61) {
    for (int rr = 0; rr < 8; ++rr) {
      int r = rq * 8 + rr;
      float gr = sigm(G1[r * 183 + j]);
      float gz = sigm(G1[r * 183 + 61 + j]);
      float gn = tanhf(G1[r * 183 + 122 + j] + gr * G2[r * 61 + j]);
      float hold = LD(hid, (gr0 + r) * 61 + j, f);
      float hn = (1.f - gz) * gn + gz * hold;
      int b = dir * NM + gr0 + r;
      hidcat[b * 61 + j] = hn;
      ST(outv, OUT0 + b * 61 + j, f, hn);
    }
  }
}

// ---------------- assemble x (NN x 64 fp32) ----------------
__global__ void k_assemble(const void* vn_prefix, const int* vn_colors, const void* emb,
                           const void* fn_embed, const void* msg_prefix,
                           const float* hidcat, float* x, const int* flg) {
  int f = flg[0];
  int t = blockIdx.x * blockDim.x + threadIdx.x;
  if (t >= NN * 64) return;
  int i = t >> 6, c = t & 63;
  float v;
  if (i < NV) {
    v = (c < PFX) ? LD(vn_prefix, i * PFX + c, f) : LD(emb, vn_colors[i] * EMB + (c - PFX), f);
  } else if (i < NV + NF) {
    v = LD(fn_embed, (i - NV) * 64 + c, f);
  } else {
    int j = i - NV - NF;
    v = (c < PFX) ? LD(msg_prefix, j * PFX + c, f) : hidcat[j * EMB + (c - PFX)];
  }
  x[t] = v;
}

// ---------------- CSR build (by dst) ----------------
__global__ void k_deg(const int* dst, int* deg) {
  int e = blockIdx.x * blockDim.x + threadIdx.x;
  if (e < EE) atomicAdd(&deg[dst[e]], 1);
}
__global__ void k_scan1(const int* deg, int* rowptr, int* bsum) {
  __shared__ int s[512];
  int g = blockIdx.x * 512 + threadIdx.x;
  int v = (g < NN) ? deg[g] : 0;
  s[threadIdx.x] = v;
  __syncthreads();
  for (int off = 1; off < 512; off <<= 1) {
    int t = (threadIdx.x >= off) ? s[threadIdx.x - off] : 0;
    __syncthreads();
    s[threadIdx.x] += t;
    __syncthreads();
  }
  if (g < NN) rowptr[g] = s[threadIdx.x] - v;
  if (threadIdx.x == 511) bsum[blockIdx.x] = s[511];
}
__global__ void k_scan2(const int* bsum, int* boff, int nb) {
  __shared__ int s[128];
  int v = (threadIdx.x < nb) ? bsum[threadIdx.x] : 0;
  s[threadIdx.x] = v;
  __syncthreads();
  for (int off = 1; off < 128; off <<= 1) {
    int t = (threadIdx.x >= off) ? s[threadIdx.x - off] : 0;
    __syncthreads();
    s[threadIdx.x] += t;
    __syncthreads();
  }
  if (threadIdx.x < nb) boff[threadIdx.x] = s[threadIdx.x] - v;
}
__global__ void k_scan3(int* rowptr, const int* boff) {
  int g = blockIdx.x * blockDim.x + threadIdx.x;
  if (g < NN) rowptr[g] += boff[g >> 9];
  if (g == 0) rowptr[NN] = EE;
}
__global__ void k_fill(const int* src, const int* dst, const int* rowptr, int* cnt, int* col) {
  int e = blockIdx.x * blockDim.x + threadIdx.x;
  if (e < EE) {
    int d = dst[e];
    int pos = rowptr[d] + atomicAdd(&cnt[d], 1);
    col[pos] = src[e];
  }
}

// ---------------- xl = x @ W (IC -> 32) + fused attention coefficients ----------------
template <int IC>
__global__ void k_xl(const float* x, const void* W, const void* as_, const void* ad_,
                     float* xl, float* a_s, float* a_d, const int* flg) {
  int f = flg[0];
  __shared__ float Wl[IC * 32];
  for (int t = threadIdx.x; t < IC * 32; t += blockDim.x) Wl[t] = LD(W, t, f);
  __syncthreads();
  int j = threadIdx.x & 31;
  int r = threadIdx.x >> 5;
  int i = blockIdx.x * 8 + r;
  const float* xr = x + (size_t)i * IC;
  float acc = 0.f;
  for (int k = 0; k < IC; ++k) acc += xr[k] * Wl[k * 32 + j];
  xl[(size_t)i * 32 + j] = acc;
  // fused coef: a_s[i,h] = sum_c xl[i,h*8+c]*as[h*8+c]  (8-lane reduce, h = j>>3)
  float sw = LD(as_, j, f), dw = LD(ad_, j, f);
  float p = acc * sw, q = acc * dw;
#pragma unroll
  for (int off = 1; off < 8; off <<= 1) {
    p += __shfl_xor(p, off);
    q += __shfl_xor(q, off);
  }
  if ((j & 7) == 0) {
    a_s[(size_t)i * 4 + (j >> 3)] = p;
    a_d[(size_t)i * 4 + (j >> 3)] = q;
  }
}

__global__ void k_waSD(const void* W4, const void* a4s, const void* a4d, float* waS, float* waD,
                       const int* flg) {
  int f = flg[0];
  int t = threadIdx.x;  // 256
  int isD = t >= 128;
  int u = t & 127;
  int h = u >> 5, k = u & 31;
  const void* av = isD ? a4d : a4s;
  float acc = 0.f;
  for (int c = 0; c < 64; ++c) acc += LD(W4, k * 256 + h * 64 + c, f) * LD(av, h * 64 + c, f);
  (isD ? waD : waS)[h * 32 + k] = acc;
}
__global__ void k_coef4(const float* x, const float* waS, const float* waD, float* a_s, float* a_d) {
  int t = blockIdx.x * blockDim.x + threadIdx.x;
  if (t >= NN * 4) return;
  int i = t >> 2, h = t & 3;
  float ss = 0.f, dd = 0.f;
  for (int k = 0; k < 32; ++k) {
    float v = x[i * 32 + k];
    ss += v * waS[h * 32 + k];
    dd += v * waD[h * 32 + k];
  }
  a_s[t] = ss;
  a_d[t] = dd;
}

// ---------------- GAT gather v2, layers 1-3: 16 nodes/block, 16 lanes/node ----------------
__global__ __launch_bounds__(256) void k_gather13(const int* rowptr, const int* col,
                                                  const float* a_s, const float* a_d,
                                                  const float* xl, const void* bias,
                                                  float* xout, const int* flg) {
  int f = flg[0];
  __shared__ int colb[16][64];
  __shared__ float4 eb[16][64];
  int tid = threadIdx.x;
  int g = tid >> 4, l = tid & 15;
  int i = blockIdx.x * 16 + g;
  int beg = rowptr[i], end = rowptr[i + 1];
  int deg = end - beg;
  float4 adv = *(const float4*)(a_d + (size_t)i * 4);
  float4 asv = *(const float4*)(a_s + (size_t)i * 4);
  float ad[4] = {adv.x, adv.y, adv.z, adv.w};
  float es[4], mx[4];
  {
    float asl[4] = {asv.x, asv.y, asv.z, asv.w};
#pragma unroll
    for (int h = 0; h < 4; ++h) { es[h] = lrelu(asl[h] + ad[h], 0.2f); mx[h] = es[h]; }
  }
  float den[4] = {0.f, 0.f, 0.f, 0.f};
  int c0 = l, c1 = l + 16;
  int h0 = l >> 3, h1 = 2 + (l >> 3);
  float acc0, acc1;

  if (deg <= 64) {
    for (int s = l; s < deg; s += 16) {
      int j = col[beg + s];
      colb[g][s] = j;
      float4 aj = *(const float4*)(a_s + (size_t)j * 4);
      float e0 = lrelu(aj.x + ad[0], 0.2f);
      float e1 = lrelu(aj.y + ad[1], 0.2f);
      float e2 = lrelu(aj.z + ad[2], 0.2f);
      float e3 = lrelu(aj.w + ad[3], 0.2f);
      eb[g][s] = make_float4(e0, e1, e2, e3);
      mx[0] = fmaxf(mx[0], e0); mx[1] = fmaxf(mx[1], e1);
      mx[2] = fmaxf(mx[2], e2); mx[3] = fmaxf(mx[3], e3);
    }
#pragma unroll
    for (int off = 1; off < 16; off <<= 1)
#pragma unroll
      for (int h = 0; h < 4; ++h) mx[h] = fmaxf(mx[h], __shfl_xor(mx[h], off));
    for (int s = l; s < deg; s += 16) {
      float4 e4 = eb[g][s];
      float x0 = expf(e4.x - mx[0]), x1 = expf(e4.y - mx[1]);
      float x2 = expf(e4.z - mx[2]), x3 = expf(e4.w - mx[3]);
      eb[g][s] = make_float4(x0, x1, x2, x3);
      den[0] += x0; den[1] += x1; den[2] += x2; den[3] += x3;
    }
#pragma unroll
    for (int off = 1; off < 16; off <<= 1)
#pragma unroll
      for (int h = 0; h < 4; ++h) den[h] += __shfl_xor(den[h], off);
    float exS[4];
#pragma unroll
    for (int h = 0; h < 4; ++h) { exS[h] = expf(es[h] - mx[h]); den[h] += exS[h]; }
    acc0 = exS[h0] * xl[(size_t)i * 32 + c0];
    acc1 = exS[h1] * xl[(size_t)i * 32 + c1];
    for (int s = 0; s < deg; ++s) {
      int j = colb[g][s];
      float4 e4 = eb[g][s];
      float w0 = h0 ? e4.y : e4.x;
      float w1 = (l >> 3) ? e4.w : e4.z;
      acc0 += w0 * xl[(size_t)j * 32 + c0];
      acc1 += w1 * xl[(size_t)j * 32 + c1];
    }
  } else {
    for (int s = l; s < deg; s += 16) {
      int j = col[beg + s];
      float4 aj = *(const float4*)(a_s + (size_t)j * 4);
      mx[0] = fmaxf(mx[0], lrelu(aj.x + ad[0], 0.2f));
      mx[1] = fmaxf(mx[1], lrelu(aj.y + ad[1], 0.2f));
      mx[2] = fmaxf(mx[2], lrelu(aj.z + ad[2], 0.2f));
      mx[3] = fmaxf(mx[3], lrelu(aj.w + ad[3], 0.2f));
    }
#pragma unroll
    for (int off = 1; off < 16; off <<= 1)
#pragma unroll
      for (int h = 0; h < 4; ++h) mx[h] = fmaxf(mx[h], __shfl_xor(mx[h], off));
    for (int s = l; s < deg; s += 16) {
      int j = col[beg + s];
      float4 aj = *(const float4*)(a_s + (size_t)j * 4);
      den[0] += expf(lrelu(aj.x + ad[0], 0.2f) - mx[0]);
      den[1] += expf(lrelu(aj.y + ad[1], 0.2f) - mx[1]);
      den[2] += expf(lrelu(aj.z + ad[2], 0.2f) - mx[2]);
      den[3] += expf(lrelu(aj.w + ad[3], 0.2f) - mx[3]);
    }
#pragma unroll
    for (int off = 1; off < 16; off <<= 1)
#pragma unroll
      for (int h = 0; h < 4; ++h) den[h] += __shfl_xor(den[h], off);
    float exS[4];
#pragma unroll
    for (int h = 0; h < 4; ++h) { exS[h] = expf(es[h] - mx[h]); den[h] += exS[h]; }
    acc0 = exS[h0] * xl[(size_t)i * 32 + c0];
    acc1 = exS[h1] * xl[(size_t)i * 32 + c1];
    for (int s = 0; s < deg; ++s) {
      int j = col[beg + s];
      float e0 = lrelu(a_s[(size_t)j * 4 + h0] + ad[h0], 0.2f);
      float e1 = lrelu(a_s[(size_t)j * 4 + h1] + ad[h1], 0.2f);
      acc0 += expf(e0 - mx[h0]) * xl[(size_t)j * 32 + c0];
      acc1 += expf(e1 - mx[h1]) * xl[(size_t)j * 32 + c1];
    }
  }
  float v0 = acc0 / den[h0] + LD(bias, c0, f);
  float v1 = acc1 / den[h1] + LD(bias, c1, f);
  xout[(size_t)i * 32 + c0] = lrelu(v0, 0.01f);
  xout[(size_t)i * 32 + c1] = lrelu(v1, 0.01f);
}

// ---------------- GAT gather v2, layer 4: aggregate x rows per head ----------------
__global__ __launch_bounds__(256) void k_gather4(const int* rowptr, const int* col,
                                                 const float* a_s, const float* a_d,
                                                 const float* x, float* agg) {
  __shared__ int colb[16][64];
  __shared__ float4 eb[16][64];
  int tid = threadIdx.x;
  int g = tid >> 4, l = tid & 15;
  int i = blockIdx.x * 16 + g;
  int beg = rowptr[i], end = rowptr[i + 1];
  int deg = end - beg;
  float4 adv = *(const float4*)(a_d + (size_t)i * 4);
  float4 asv = *(const float4*)(a_s + (size_t)i * 4);
  float ad[4] = {adv.x, adv.y, adv.z, adv.w};
  float es[4], mx[4];
  {
    float asl[4] = {asv.x, asv.y, asv.z, asv.w};
#pragma unroll
    for (int h = 0; h < 4; ++h) { es[h] = lrelu(asl[h] + ad[h], 0.2f); mx[h] = es[h]; }
  }
  float den[4] = {0.f, 0.f, 0.f, 0.f};
  int k0 = l, k1 = l + 16;
  float acc[4][2];

  if (deg <= 64) {
    for (int s = l; s < deg; s += 16) {
      int j = col[beg + s];
      colb[g][s] = j;
      float4 aj = *(const float4*)(a_s + (size_t)j * 4);
      float e0 = lrelu(aj.x + ad[0], 0.2f);
      float e1 = lrelu(aj.y + ad[1], 0.2f);
      float e2 = lrelu(aj.z + ad[2], 0.2f);
      float e3 = lrelu(aj.w + ad[3], 0.2f);
      eb[g][s] = make_float4(e0, e1, e2, e3);
      mx[0] = fmaxf(mx[0], e0); mx[1] = fmaxf(mx[1], e1);
      mx[2] = fmaxf(mx[2], e2); mx[3] = fmaxf(mx[3], e3);
    }
#pragma unroll
    for (int off = 1; off < 16; off <<= 1)
#pragma unroll
      for (int h = 0; h < 4; ++h) mx[h] = fmaxf(mx[h], __shfl_xor(mx[h], off));
    for (int s = l; s < deg; s += 16) {
      float4 e4 = eb[g][s];
      float x0 = expf(e4.x - mx[0]), x1 = expf(e4.y - mx[1]);
      float x2 = expf(e4.z - mx[2]), x3 = expf(e4.w - mx[3]);
      eb[g][s] = make_float4(x0, x1, x2, x3);
      den[0] += x0; den[1] += x1; den[2] += x2; den[3] += x3;
    }
#pragma unroll
    for (int off = 1; off < 16; off <<= 1)
#pragma unroll
      for (int h = 0; h < 4; ++h) den[h] += __shfl_xor(den[h], off);
    float exS[4];
#pragma unroll
    for (int h = 0; h < 4; ++h) { exS[h] = expf(es[h] - mx[h]); den[h] += exS[h]; }
    float xs0 = x[(size_t)i * 32 + k0], xs1 = x[(size_t)i * 32 + k1];
#pragma unroll
    for (int h = 0; h < 4; ++h) { acc[h][0] = exS[h] * xs0; acc[h][1] = exS[h] * xs1; }
    for (int s = 0; s < deg; ++s) {
      int j = colb[g][s];
      float4 e4 = eb[g][s];
      float xv0 = x[(size_t)j * 32 + k0], xv1 = x[(size_t)j * 32 + k1];
      acc[0][0] += e4.x * xv0; acc[0][1] += e4.x * xv1;
      acc[1][0] += e4.y * xv0; acc[1][1] += e4.y * xv1;
      acc[2][0] += e4.z * xv0; acc[2][1] += e4.z * xv1;
      acc[3][0] += e4.w * xv0; acc[3][1] += e4.w * xv1;
    }
  } else {
    for (int s = l; s < deg; s += 16) {
      int j = col[beg + s];
      float4 aj = *(const float4*)(a_s + (size_t)j * 4);
      mx[0] = fmaxf(mx[0], lrelu(aj.x + ad[0], 0.2f));
      mx[1] = fmaxf(mx[1], lrelu(aj.y + ad[1], 0.2f));
      mx[2] = fmaxf(mx[2], lrelu(aj.z + ad[2], 0.2f));
      mx[3] = fmaxf(mx[3], lrelu(aj.w + ad[3], 0.2f));
    }
#pragma unroll
    for (int off = 1; off < 16; off <<= 1)
#pragma unroll
      for (int h = 0; h < 4; ++h) mx[h] = fmaxf(mx[h], __shfl_xor(mx[h], off));
    for (int s = l; s < deg; s += 16) {
      int j = col[beg + s];
      float4 aj = *(const float4*)(a_s + (size_t)j * 4);
      den[0] += expf(lrelu(aj.x + ad[0], 0.2f) - mx[0]);
      den[1] += expf(lrelu(aj.y + ad[1], 0.2f) - mx[1]);
      den[2] += expf(lrelu(aj.z + ad[2], 0.2f) - mx[2]);
      den[3] += expf(lrelu(aj.w + ad[3], 0.2f) - mx[3]);
    }
#pragma unroll
    for (int off = 1; off < 16; off <<= 1)
#pragma unroll
      for (int h = 0; h < 4; ++h) den[h] += __shfl_xor(den[h], off);
    float exS[4];
#pragma unroll
    for (int h = 0; h < 4; ++h) { exS[h] = expf(es[h] - mx[h]); den[h] += exS[h]; }
    float xs0 = x[(size_t)i * 32 + k0], xs1 = x[(size_t)i * 32 + k1];
#pragma unroll
    for (int h = 0; h < 4; ++h) { acc[h][0] = exS[h] * xs0; acc[h][1] = exS[h] * xs1; }
    for (int s = 0; s < deg; ++s) {
      int j = col[beg + s];
      float4 aj = *(const float4*)(a_s + (size_t)j * 4);
      float xv0 = x[(size_t)j * 32 + k0], xv1 = x[(size_t)j * 32 + k1];
      acc[0][0] += expf(lrelu(aj.x + ad[0], 0.2f) - mx[0]) * xv0;
      acc[0][1] += expf(lrelu(aj.x + ad[0], 0.2f) - mx[0]) * xv1;
      acc[1][0] += expf(lrelu(aj.y + ad[1], 0.2f) - mx[1]) * xv0;
      acc[1][1] += expf(lrelu(aj.y + ad[1], 0.2f) - mx[1]) * xv1;
      acc[2][0] += expf(lrelu(aj.z + ad[2], 0.2f) - mx[2]) * xv0;
      acc[2][1] += expf(lrelu(aj.z + ad[2], 0.2f) - mx[2]) * xv1;
      acc[3][0] += expf(lrelu(aj.w + ad[3], 0.2f) - mx[3]) * xv0;
      acc[3][1] += expf(lrelu(aj.w + ad[3], 0.2f) - mx[3]) * xv1;
    }
  }
#pragma unroll
  for (int h = 0; h < 4; ++h) {
    agg[(size_t)i * 128 + h * 32 + k0] = acc[h][0] / den[h];
    agg[(size_t)i * 128 + h * 32 + k1] = acc[h][1] / den[h];
  }
}

// ---------------- L4 epilogue v4: register-blocked GEMM, 64 rows/block ----------------
__global__ __launch_bounds__(256) void k_l4_out(const float* agg, const void* W4, const void* b4,
                                                float* xout, const int* flg) {
  int f = flg[0];
  __shared__ float Wl[128 * 64];     // [K][c]          32 KB
  __shared__ float Al[64][132];      // [r][K] pad 132
  int tid = threadIdx.x;
  int R0 = blockIdx.x * 64;
  for (int t = tid; t < 128 * 64; t += 256) {
    int K = t >> 6, c = t & 63;
    int h = K >> 5, k = K & 31;
    Wl[t] = LD(W4, k * 256 + h * 64 + c, f);
  }
  {
    const float4* ag4 = (const float4*)(agg + (size_t)R0 * 128);
    for (int t = tid; t < 2048; t += 256) {
      int r = t >> 5, k4 = (t & 31) << 2;
      float4 v = ag4[t];
      *(float4*)&Al[r][k4] = v;
    }
  }
  __syncthreads();
  int c0 = (tid & 15) << 2, r0 = (tid >> 4) << 2;
  float acc[4][4];
#pragma unroll
  for (int j = 0; j < 4; ++j)
#pragma unroll
    for (int i = 0; i < 4; ++i) acc[j][i] = 0.f;
#pragma unroll 4
  for (int K = 0; K < 128; ++K) {
    float4 wv = *(const float4*)&Wl[K * 64 + c0];
    float a0 = Al[r0][K], a1 = Al[r0 + 1][K], a2 = Al[r0 + 2][K], a3 = Al[r0 + 3][K];
    acc[0][0] += a0 * wv.x; acc[0][1] += a0 * wv.y; acc[0][2] += a0 * wv.z; acc[0][3] += a0 * wv.w;
    acc[1][0] += a1 * wv.x; acc[1][1] += a1 * wv.y; acc[1][2] += a1 * wv.z; acc[1][3] += a1 * wv.w;
    acc[2][0] += a2 * wv.x; acc[2][1] += a2 * wv.y; acc[2][2] += a2 * wv.z; acc[2][3] += a2 * wv.w;
    acc[3][0] += a3 * wv.x; acc[3][1] += a3 * wv.y; acc[3][2] += a3 * wv.z; acc[3][3] += a3 * wv.w;
  }
  float bv[4];
#pragma unroll
  for (int i = 0; i < 4; ++i) bv[i] = LD(b4, c0 + i, f);
#pragma unroll
  for (int j = 0; j < 4; ++j) {
    float4 o;
    o.x = lrelu(0.25f * acc[j][0] + bv[0], 0.01f);
    o.y = lrelu(0.25f * acc[j][1] + bv[1], 0.01f);
    o.z = lrelu(0.25f * acc[j][2] + bv[2], 0.01f);
    o.w = lrelu(0.25f * acc[j][3] + bv[3], 0.01f);
    *(float4*)&xout[(size_t)(R0 + r0 + j) * 64 + c0] = o;
  }
}

// ---------------- pooling attention head ----------------
__global__ void k_wqk(const void* wq, const void* wk, const void* ws, float* wqv, float* wkv,
                      const int* flg) {
  int f = flg[0];
  int t = threadIdx.x;  // 256
  int h = t >> 6, d = t & 63;
  float q = 0.f, k = 0.f;
  for (int e = 0; e < 64; ++e) {
    q += LD(wq, h * 4096 + d * 64 + e, f) * LD(ws, h * 128 + e, f);
    k += LD(wk, h * 4096 + d * 64 + e, f) * LD(ws, h * 128 + 64 + e, f);
  }
  wqv[h * 64 + d] = q;
  wkv[h * 64 + d] = k;
}
__global__ void k_qk(const float* xfin, const float* wqv, const float* wkv, float* qs, float* ks) {
  int t = blockIdx.x * blockDim.x + threadIdx.x;
  if (t >= NF * 4) return;
  int n = t >> 2, h = t & 3;
  const float* row = xfin + (size_t)(NV + n) * 64;
  float q = 0.f, k = 0.f;
  for (int d = 0; d < 64; ++d) {
    float v = row[d];
    q += v * wqv[h * 64 + d];
    k += v * wkv[h * 64 + d];
  }
  qs[t] = q;
  ks[t] = k;
}

__global__ void k_groups(const int* full, const void* mask, const int* tgt, const int* mult,
                         const float* qs, const float* ks, const void* att_b, void* outv,
                         const int* flg) {
  int f = flg[0], mbyte = flg[1];
  int g = blockIdx.x;
  int lane = threadIdx.x;  // 64 = 16 k * 4 h
  int k = lane >> 2, h = lane & 3;
  int t = tgt[g];
  int idx = full[g * KK + k];
  int mk = MK(mask, g * KK + k, mbyte);
  float bh = LD(att_b, h, f);
  float qt = qs[t * 4 + h];
  float sc = sigm(qt + ks[idx * 4 + h] + bh);
  int is_tgt = (idx == t) && mk;
  int nbr = mk && !is_tgt;
  unsigned long long bal = __ballot(nbr != 0);
  int degm1 = (int)(__popcll(bal) >> 2);
  float ssum = nbr ? sc : 0.f;
  for (int off = 4; off < 64; off <<= 1) ssum += __shfl_xor(ssum, off);
  ssum /= (float)(degm1 > 1 ? degm1 : 1);
  float trg = sigm(qt + ks[t * 4 + h] + bh);
  float mxv = fmaxf(ssum, trg);
  float e0 = expf(ssum - mxv), e1 = expf(trg - mxv);
  float tw0 = e0 / (e0 + e1), tw1 = e1 / (e0 + e1);
  float msc = nbr ? sc : -1e30f;
  float m = msc;
  for (int off = 4; off < 64; off <<= 1) m = fmaxf(m, __shfl_xor(m, off));
  float ex = expf(msc - m);
  float den = ex;
  for (int off = 4; off < 64; off <<= 1) den += __shfl_xor(den, off);
  float w = ex / den * tw0 * (float)mult[g];
  float res = is_tgt ? tw1 : (nbr ? w : 0.f);
  if (degm1 == 0) res = 0.f;
  ST(outv, g * 64 + k * 4 + h, f, res);
}

extern "C" void kernel_launch(void* const* d_in, const int* in_sizes, int n_in,
                              void* d_out, int out_size, void* d_ws, size_t ws_size,
                              hipStream_t stream) {
  const int* edge = (const int*)d_in[0];
  const int* esrc = edge;
  const int* edst = edge + EE;
  const int* vn_colors = (const int*)d_in[1];
  const int* group_full = (const int*)d_in[2];
  const void* group_mask = d_in[3];
  const int* group_tgt = (const int*)d_in[4];
  const int* group_mult = (const int*)d_in[5];
  const void* vn_prefix = d_in[6];
  const void* fn_embed = d_in[7];
  const void* v2f_msgs = d_in[8];
  const void* v2f_hidden = d_in[9];
  const void* f2v_msgs = d_in[10];
  const void* f2v_hidden = d_in[11];
  const void* msg_prefix = d_in[12];
  const void* emb = d_in[13];
  const void* gv_wih = d_in[14];
  const void* gv_whh = d_in[15];
  const void* gv_bih = d_in[16];
  const void* gv_bhh = d_in[17];
  const void* gf_wih = d_in[18];
  const void* gf_whh = d_in[19];
  const void* gf_bih = d_in[20];
  const void* gf_bhh = d_in[21];
  const void* W1 = d_in[22];
  const void* a1s = d_in[23];
  const void* a1d = d_in[24];
  const void* b1 = d_in[25];
  const void* W2 = d_in[26];
  const void* a2s = d_in[27];
  const void* a2d = d_in[28];
  const void* b2 = d_in[29];
  const void* W3 = d_in[30];
  const void* a3s = d_in[31];
  const void* a3d = d_in[32];
  const void* b3 = d_in[33];
  const void* W4 = d_in[34];
  const void* a4s = d_in[35];
  const void* a4d = d_in[36];
  const void* b4 = d_in[37];
  const void* att_wq = d_in[38];
  const void* att_wk = d_in[39];
  const void* att_ws = d_in[40];
  const void* att_b = d_in[41];

  char* w = (char*)d_ws;
  size_t off = 0;
  auto carve = [&](size_t bytes) -> void* {
    void* p = w + off;
    off += (bytes + 255) & ~(size_t)255;
    return p;
  };
  int* flags = (int*)carve(16);
  float* Wt = (float*)carve((size_t)2 * 77 * 192 * 4);
  float* hidcat = (float*)carve((size_t)2 * NM * EMB * 4);
  float* xA = (float*)carve((size_t)NN * 64 * 4);
  float* xB = (float*)carve((size_t)NN * 64 * 4);
  float* scr = (float*)carve((size_t)NN * 128 * 4);  // xl (N x 32) or agg (N x 128)
  float* a_s = (float*)carve((size_t)NN * 4 * 4);
  float* a_d = (float*)carve((size_t)NN * 4 * 4);
  int* deg = (int*)carve((size_t)NN * 4);
  int* rowptr = (int*)carve((size_t)(NN + 1) * 4);
  int* cnt = (int*)carve((size_t)NN * 4);
  int* bsum = (int*)carve(128 * 4);
  int* boff = (int*)carve(128 * 4);
  int* col = (int*)carve((size_t)EE * 4);
  float* qs = (float*)carve((size_t)NF * 4 * 4);
  float* ks = (float*)carve((size_t)NF * 4 * 4);
  float* wqv = (float*)carve(256 * 4);
  float* wkv = (float*)carve(256 * 4);
  float* waS = (float*)carve(128 * 4);
  float* waD = (float*)carve(128 * 4);

  hipMemsetAsync(deg, 0, (size_t)NN * 4, stream);
  hipMemsetAsync(cnt, 0, (size_t)NN * 4, stream);

  k_detect<<<1, 64, 0, stream>>>(fn_embed, group_mask, flags);
  k_wtr<<<(2 * 77 * 192 + 255) / 256, 256, 0, stream>>>(gv_wih, gv_whh, gf_wih, gf_whh, Wt, flags);
  k_gru2<<<768, 256, 0, stream>>>(v2f_msgs, v2f_hidden, f2v_msgs, f2v_hidden,
                                  gv_bih, gv_bhh, gf_bih, gf_bhh, Wt, hidcat, d_out, flags);
  k_assemble<<<(NN * 64) / 256, 256, 0, stream>>>(vn_prefix, vn_colors, emb, fn_embed,
                                                  msg_prefix, hidcat, xA, flags);
  k_deg<<<EE / 256, 256, 0, stream>>>(edst, deg);
  k_scan1<<<72, 512, 0, stream>>>(deg, rowptr, bsum);
  k_scan2<<<1, 128, 0, stream>>>(bsum, boff, 72);
  k_scan3<<<(NN + 256) / 256, 256, 0, stream>>>(rowptr, boff);
  k_fill<<<EE / 256, 256, 0, stream>>>(esrc, edst, rowptr, cnt, col);

  // L1: 64 -> 32 (+fused coef)
  k_xl<64><<<NN / 8, 256, 0, stream>>>(xA, W1, a1s, a1d, scr, a_s, a_d, flags);
  k_gather13<<<NN / 16, 256, 0, stream>>>(rowptr, col, a_s, a_d, scr, b1, xB, flags);
  // L2: 32 -> 32
  k_xl<32><<<NN / 8, 256, 0, stream>>>(xB, W2, a2s, a2d, scr, a_s, a_d, flags);
  k_gather13<<<NN / 16, 256, 0, stream>>>(rowptr, col, a_s, a_d, scr, b2, xA, flags);
  // L3: 32 -> 32
  k_xl<32><<<NN / 8, 256, 0, stream>>>(xA, W3, a3s, a3d, scr, a_s, a_d, flags);
  k_gather13<<<NN / 16, 256, 0, stream>>>(rowptr, col, a_s, a_d, scr, b3, xB, flags);
  // L4: 32 -> (4 heads x 64), mean
  k_waSD<<<1, 256, 0, stream>>>(W4, a4s, a4d, waS, waD, flags);
  k_coef4<<<NN * 4 / 256, 256, 0, stream>>>(xB, waS, waD, a_s, a_d);
  k_gather4<<<NN / 16, 256, 0, stream>>>(rowptr, col, a_s, a_d, xB, scr);
  k_l4_out<<<NN / 64, 256, 0, stream>>>(scr, W4, b4, xA, flags);

  k_wqk<<<1, 256, 0, stream>>>(att_wq, att_wk, att_ws, wqv, wkv, flags);
  k_qk<<<(NF * 4) / 256, 256, 0, stream>>>(xA, wqv, wkv, qs, ks);
  k_groups<<<GG, 64, 0, stream>>>(group_full, group_mask, group_tgt, group_mult,
                                  qs, ks, att_b, d_out, flags);
}

// Round 8
// 209.283 us; speedup vs baseline: 6.3767x; 1.3368x over previous
//
#include <hip/hip_runtime.h>
#include <hip/hip_bf16.h>

#define NV 8192
#define NF 4096
#define NM 12288
#define PFX 3
#define DOM 16
#define EMB 61
#define NN 36864
#define EE 262144
#define GG 8192
#define KK 16
#define OUT0 524288

typedef __hip_bfloat16 bf16;
__device__ __forceinline__ float b2f(bf16 x) { return __bfloat162float(x); }
__device__ __forceinline__ float lrelu(float x, float s) { return x > 0.f ? x : s * x; }
__device__ __forceinline__ float sigm(float x) { return 1.f / (1.f + expf(-x)); }
__device__ __forceinline__ float LD(const void* p, int i, int f) {
  return f ? ((const float*)p)[i] : b2f(((const bf16*)p)[i]);
}
__device__ __forceinline__ void ST(void* p, int i, int f, float v) {
  if (f) ((float*)p)[i] = v; else ((bf16*)p)[i] = __float2bfloat16(v);
}
__device__ __forceinline__ int MK(const void* p, int i, int bytey) {
  return bytey ? (int)((const signed char*)p)[i] : ((const int*)p)[i];
}

// -------- dtype detector --------
__global__ void k_detect(const void* fn, const void* mask, int* flags) {
  if (threadIdx.x || blockIdx.x) return;
  int wild = 0;
  const bf16* h = (const bf16*)fn;
  for (int i = 0; i < 128; ++i) {
    float x = b2f(h[i]);
    float a = fabsf(x);
    if (a != a || a > 1e4f || (x != 0.f && a < 1e-8f)) ++wild;
  }
  flags[0] = (wild >= 8) ? 1 : 0;
  const int* mi = (const int*)mask;
  int bytey = 0;
  for (int i = 0; i < 64; ++i) {
    unsigned v = (unsigned)mi[i];
    if (v > 1u) bytey = 1;
  }
  flags[1] = bytey;
}

// -------- fused precompute: Wt (blocks 0-115), waS/waD (block 116), wqv/wkv (block 117) ----
__global__ void k_precomp(const void* gv_wih, const void* gv_whh,
                          const void* gf_wih, const void* gf_whh,
                          const void* W4, const void* a4s, const void* a4d,
                          const void* wq, const void* wk, const void* ws,
                          float* Wt, float* waS, float* waD, float* wqv, float* wkv,
                          const int* flg) {
  int f = flg[0];
  int blk = blockIdx.x, tid = threadIdx.x;
  if (blk < 116) {
    int t = blk * 256 + tid;
    if (t < 2 * 77 * 192) {
      int dir = t / (77 * 192);
      int rem = t - dir * 77 * 192;
      int d = rem / 192, o = rem - d * 192;
      const void* wih = dir ? gf_wih : gv_wih;
      const void* whh = dir ? gf_whh : gv_whh;
      float v = 0.f;
      if (o < 183) v = (d < 16) ? LD(wih, o * 16 + d, f) : LD(whh, o * 61 + (d - 16), f);
      Wt[t] = v;
    }
  } else if (blk == 116) {
    int isD = tid >= 128;
    int u = tid & 127;
    int h = u >> 5, k = u & 31;
    const void* av = isD ? a4d : a4s;
    float acc = 0.f;
    for (int c = 0; c < 64; ++c) acc += LD(W4, k * 256 + h * 64 + c, f) * LD(av, h * 64 + c, f);
    (isD ? waD : waS)[h * 32 + k] = acc;
  } else {
    int h = tid >> 6, d = tid & 63;
    float q = 0.f, k = 0.f;
    for (int e = 0; e < 64; ++e) {
      q += LD(wq, h * 4096 + d * 64 + e, f) * LD(ws, h * 128 + e, f);
      k += LD(wk, h * 4096 + d * 64 + e, f) * LD(ws, h * 128 + 64 + e, f);
    }
    wqv[h * 64 + d] = q;
    wkv[h * 64 + d] = k;
  }
}

// ---------------- GRU v3: 32 rows/block ----------------
__global__ __launch_bounds__(256) void k_gru2(
    const void* v2f_msgs, const void* v2f_hid, const void* f2v_msgs, const void* f2v_hid,
    const void* gv_bih, const void* gv_bhh, const void* gf_bih, const void* gf_bhh,
    const float* Wt, float* hidcat, void* outv, const int* flg) {
  int f = flg[0];
  int blk = blockIdx.x;
  int dir = blk >= 384;
  int loc = dir ? blk - 384 : blk;
  int gr0 = loc * 32;
  const void* msgs = dir ? f2v_msgs : v2f_msgs;
  const void* hid = dir ? f2v_hid : v2f_hid;
  const void* bih = dir ? gf_bih : gv_bih;
  const void* bhh = dir ? gf_bhh : gv_bhh;
  const float* W = Wt + dir * 77 * 192;

  __shared__ float smem[7808];
  float* F = smem;
  float* G1 = smem;
  float* G2 = smem + 32 * 183;

  int tid = threadIdx.x;
  for (int idx = tid; idx < 32 * 16; idx += 256) {
    int r = idx >> 4, d = idx & 15;
    F[d * 36 + r] = LD(msgs, (gr0 + r) * DOM + d, f);
  }
  for (int idx = tid; idx < 32 * 61; idx += 256) {
    int r = idx / 61, d = idx - r * 61;
    F[(16 + d) * 36 + r] = LD(hid, gr0 * 61 + idx, f);
  }
  __syncthreads();

  int og = tid & 15, rg = tid >> 4;
  int o0 = og * 12, r0 = rg * 2;
  float accA[24], accB[24];
#pragma unroll
  for (int i = 0; i < 24; ++i) { accA[i] = 0.f; accB[i] = 0.f; }

#pragma unroll 2
  for (int d = 0; d < 16; ++d) {
    const float2 fv2 = *(const float2*)&F[d * 36 + r0];
    const float4 w0 = *(const float4*)&W[d * 192 + o0];
    const float4 w1 = *(const float4*)&W[d * 192 + o0 + 4];
    const float4 w2 = *(const float4*)&W[d * 192 + o0 + 8];
    float wv[12] = {w0.x, w0.y, w0.z, w0.w, w1.x, w1.y, w1.z, w1.w, w2.x, w2.y, w2.z, w2.w};
#pragma unroll
    for (int k = 0; k < 12; ++k) {
      accA[k * 2 + 0] += wv[k] * fv2.x;
      accA[k * 2 + 1] += wv[k] * fv2.y;
    }
  }
#pragma unroll 2
  for (int d = 16; d < 77; ++d) {
    const float2 fv2 = *(const float2*)&F[d * 36 + r0];
    const float4 w0 = *(const float4*)&W[d * 192 + o0];
    const float4 w1 = *(const float4*)&W[d * 192 + o0 + 4];
    const float4 w2 = *(const float4*)&W[d * 192 + o0 + 8];
    float wv[12] = {w0.x, w0.y, w0.z, w0.w, w1.x, w1.y, w1.z, w1.w, w2.x, w2.y, w2.z, w2.w};
#pragma unroll
    for (int k = 0; k < 12; ++k) {
      accB[k * 2 + 0] += wv[k] * fv2.x;
      accB[k * 2 + 1] += wv[k] * fv2.y;
    }
  }
  __syncthreads();

#pragma unroll
  for (int k = 0; k < 12; ++k) {
    int o = o0 + k;
    if (o < 183) {
      float biv = LD(bih, o, f), bhv = LD(bhh, o, f);
#pragma unroll
      for (int m = 0; m < 2; ++m) {
        int r = r0 + m;
        float gi = accA[k * 2 + m] + biv;
        float gh = accB[k * 2 + m] + bhv;
        if (o < 122) G1[r * 183 + o] = gi + gh;
        else { G1[r * 183 + o] = gi; G2[r * 61 + (o - 122)] = gh; }
      }
    }
  }
  __syncthreads();

  int j = tid & 63, rq = tid >> 6;
  if (j < 61) {
    for (int rr = 0; rr < 8; ++rr) {
      int r = rq * 8 + rr;
      float gr = sigm(G1[r * 183 + j]);
      float gz = sigm(G1[r * 183 + 61 + j]);
      float gn = tanhf(G1[r * 183 + 122 + j] + gr * G2[r * 61 + j]);
      float hold = LD(hid, (gr0 + r) * 61 + j, f);
      float hn = (1.f - gz) * gn + gz * hold;
      int b = dir * NM + gr0 + r;
      hidcat[b * 61 + j] = hn;
      ST(outv, OUT0 + b * 61 + j, f, hn);
    }
  }
}

// ---------------- CSR build ----------------
__global__ void k_deg(const int* dst, int* deg) {
  int e = blockIdx.x * blockDim.x + threadIdx.x;
  if (e < EE) atomicAdd(&deg[dst[e]], 1);
}
__global__ void k_scan1(const int* deg, int* rowptr, int* bsum) {
  __shared__ int s[512];
  int g = blockIdx.x * 512 + threadIdx.x;
  int v = (g < NN) ? deg[g] : 0;
  s[threadIdx.x] = v;
  __syncthreads();
  for (int off = 1; off < 512; off <<= 1) {
    int t = (threadIdx.x >= off) ? s[threadIdx.x - off] : 0;
    __syncthreads();
    s[threadIdx.x] += t;
    __syncthreads();
  }
  if (g < NN) rowptr[g] = s[threadIdx.x] - v;
  if (threadIdx.x == 511) bsum[blockIdx.x] = s[511];
}
__global__ void k_scan2(const int* bsum, int* boff, int nb) {
  __shared__ int s[128];
  int v = (threadIdx.x < nb) ? bsum[threadIdx.x] : 0;
  s[threadIdx.x] = v;
  __syncthreads();
  for (int off = 1; off < 128; off <<= 1) {
    int t = (threadIdx.x >= off) ? s[threadIdx.x - off] : 0;
    __syncthreads();
    s[threadIdx.x] += t;
    __syncthreads();
  }
  if (threadIdx.x < nb) boff[threadIdx.x] = s[threadIdx.x] - v;
}
__global__ void k_scan3(int* rowptr, const int* boff) {
  int g = blockIdx.x * blockDim.x + threadIdx.x;
  if (g < NN) rowptr[g] += boff[g >> 9];
  if (g == 0) rowptr[NN] = EE;
}
__global__ void k_fill(const int* src, const int* dst, const int* rowptr, int* cnt, int* col) {
  int e = blockIdx.x * blockDim.x + threadIdx.x;
  if (e < EE) {
    int d = dst[e];
    int pos = rowptr[d] + atomicAdd(&cnt[d], 1);
    col[pos] = src[e];
  }
}

// ---------------- L1: fused assemble + x@W1 + coef ----------------
__global__ __launch_bounds__(256) void k_xl1(
    const void* vn_prefix, const int* vn_colors, const void* emb, const void* fn_embed,
    const void* msg_prefix, const float* hidcat, const void* W1, const void* a1s,
    const void* a1d, float* xl, float* a_s, float* a_d, const int* flg) {
  int f = flg[0];
  __shared__ float Wl[64 * 32];
  __shared__ float X[8][64];
  int tid = threadIdx.x;
  for (int t = tid; t < 2048; t += 256) Wl[t] = LD(W1, t, f);
  for (int t = tid; t < 512; t += 256) {
    int r = t >> 6, c = t & 63;
    int i = blockIdx.x * 8 + r;
    float v;
    if (i < NV) {
      v = (c < PFX) ? LD(vn_prefix, i * PFX + c, f) : LD(emb, vn_colors[i] * EMB + (c - PFX), f);
    } else if (i < NV + NF) {
      v = LD(fn_embed, (size_t)(i - NV) * 64 + c, f);
    } else {
      int jj = i - NV - NF;
      v = (c < PFX) ? LD(msg_prefix, jj * PFX + c, f) : hidcat[jj * EMB + (c - PFX)];
    }
    X[r][c] = v;
  }
  __syncthreads();
  int j = tid & 31, r = tid >> 5;
  int i = blockIdx.x * 8 + r;
  float acc = 0.f;
#pragma unroll
  for (int k = 0; k < 64; ++k) acc += X[r][k] * Wl[k * 32 + j];
  xl[(size_t)i * 32 + j] = acc;
  float sw = LD(a1s, j, f), dw = LD(a1d, j, f);
  float p = acc * sw, q = acc * dw;
#pragma unroll
  for (int off = 1; off < 8; off <<= 1) {
    p += __shfl_xor(p, off);
    q += __shfl_xor(q, off);
  }
  if ((j & 7) == 0) {
    a_s[(size_t)i * 4 + (j >> 3)] = p;
    a_d[(size_t)i * 4 + (j >> 3)] = q;
  }
}

// ---------------- GAT gather fused: MODE0 = +next xl+coef; MODE1 = L3 (+xout, +coef4) ----
template <int MODE>
__global__ __launch_bounds__(256) void k_gather13(
    const int* rowptr, const int* col, const float* a_s, const float* a_d,
    const float* xl, const void* bias,
    const void* Wn, const void* asn_, const void* adn_,      // MODE0
    const float* waS, const float* waD,                       // MODE1
    float* xl_next, float* xout, float* as_out, float* ad_out, const int* flg) {
  int f = flg[0];
  __shared__ int colb[16][64];
  __shared__ float4 eb[16][64];
  __shared__ float Wn_l[32 * 32];
  __shared__ float an_s[32], an_d[32];
  __shared__ float Xr[16][33];
  __shared__ float SwaS[128], SwaD[128];
  int tid = threadIdx.x;
  if (MODE == 0) {
    for (int t = tid; t < 1024; t += 256) Wn_l[t] = LD(Wn, t, f);
    if (tid < 32) { an_s[tid] = LD(asn_, tid, f); an_d[tid] = LD(adn_, tid, f); }
  } else {
    if (tid < 128) { SwaS[tid] = waS[tid]; SwaD[tid] = waD[tid]; }
  }
  int g = tid >> 4, l = tid & 15;
  int i = blockIdx.x * 16 + g;
  int beg = rowptr[i], end = rowptr[i + 1];
  int deg = end - beg;
  float4 adv = *(const float4*)(a_d + (size_t)i * 4);
  float4 asv = *(const float4*)(a_s + (size_t)i * 4);
  float ad[4] = {adv.x, adv.y, adv.z, adv.w};
  float es[4], mx[4];
  {
    float asl[4] = {asv.x, asv.y, asv.z, asv.w};
#pragma unroll
    for (int h = 0; h < 4; ++h) { es[h] = lrelu(asl[h] + ad[h], 0.2f); mx[h] = es[h]; }
  }
  float den[4] = {0.f, 0.f, 0.f, 0.f};
  int c0 = l, c1 = l + 16;
  int h0 = l >> 3, h1 = 2 + (l >> 3);
  float acc0, acc1;

  if (deg <= 64) {
    for (int s = l; s < deg; s += 16) {
      int j = col[beg + s];
      colb[g][s] = j;
      float4 aj = *(const float4*)(a_s + (size_t)j * 4);
      float e0 = lrelu(aj.x + ad[0], 0.2f);
      float e1 = lrelu(aj.y + ad[1], 0.2f);
      float e2 = lrelu(aj.z + ad[2], 0.2f);
      float e3 = lrelu(aj.w + ad[3], 0.2f);
      eb[g][s] = make_float4(e0, e1, e2, e3);
      mx[0] = fmaxf(mx[0], e0); mx[1] = fmaxf(mx[1], e1);
      mx[2] = fmaxf(mx[2], e2); mx[3] = fmaxf(mx[3], e3);
    }
#pragma unroll
    for (int off = 1; off < 16; off <<= 1)
#pragma unroll
      for (int h = 0; h < 4; ++h) mx[h] = fmaxf(mx[h], __shfl_xor(mx[h], off));
    for (int s = l; s < deg; s += 16) {
      float4 e4 = eb[g][s];
      float x0 = expf(e4.x - mx[0]), x1 = expf(e4.y - mx[1]);
      float x2 = expf(e4.z - mx[2]), x3 = expf(e4.w - mx[3]);
      eb[g][s] = make_float4(x0, x1, x2, x3);
      den[0] += x0; den[1] += x1; den[2] += x2; den[3] += x3;
    }
#pragma unroll
    for (int off = 1; off < 16; off <<= 1)
#pragma unroll
      for (int h = 0; h < 4; ++h) den[h] += __shfl_xor(den[h], off);
    float exS[4];
#pragma unroll
    for (int h = 0; h < 4; ++h) { exS[h] = expf(es[h] - mx[h]); den[h] += exS[h]; }
    acc0 = exS[h0] * xl[(size_t)i * 32 + c0];
    acc1 = exS[h1] * xl[(size_t)i * 32 + c1];
    for (int s = 0; s < deg; ++s) {
      int j = colb[g][s];
      float4 e4 = eb[g][s];
      float w0 = h0 ? e4.y : e4.x;
      float w1 = (l >> 3) ? e4.w : e4.z;
      acc0 += w0 * xl[(size_t)j * 32 + c0];
      acc1 += w1 * xl[(size_t)j * 32 + c1];
    }
  } else {
    for (int s = l; s < deg; s += 16) {
      int j = col[beg + s];
      float4 aj = *(const float4*)(a_s + (size_t)j * 4);
      mx[0] = fmaxf(mx[0], lrelu(aj.x + ad[0], 0.2f));
      mx[1] = fmaxf(mx[1], lrelu(aj.y + ad[1], 0.2f));
      mx[2] = fmaxf(mx[2], lrelu(aj.z + ad[2], 0.2f));
      mx[3] = fmaxf(mx[3], lrelu(aj.w + ad[3], 0.2f));
    }
#pragma unroll
    for (int off = 1; off < 16; off <<= 1)
#pragma unroll
      for (int h = 0; h < 4; ++h) mx[h] = fmaxf(mx[h], __shfl_xor(mx[h], off));
    for (int s = l; s < deg; s += 16) {
      int j = col[beg + s];
      float4 aj = *(const float4*)(a_s + (size_t)j * 4);
      den[0] += expf(lrelu(aj.x + ad[0], 0.2f) - mx[0]);
      den[1] += expf(lrelu(aj.y + ad[1], 0.2f) - mx[1]);
      den[2] += expf(lrelu(aj.z + ad[2], 0.2f) - mx[2]);
      den[3] += expf(lrelu(aj.w + ad[3], 0.2f) - mx[3]);
    }
#pragma unroll
    for (int off = 1; off < 16; off <<= 1)
#pragma unroll
      for (int h = 0; h < 4; ++h) den[h] += __shfl_xor(den[h], off);
    float exS[4];
#pragma unroll
    for (int h = 0; h < 4; ++h) { exS[h] = expf(es[h] - mx[h]); den[h] += exS[h]; }
    acc0 = exS[h0] * xl[(size_t)i * 32 + c0];
    acc1 = exS[h1] * xl[(size_t)i * 32 + c1];
    for (int s = 0; s < deg; ++s) {
      int j = col[beg + s];
      float e0 = lrelu(a_s[(size_t)j * 4 + h0] + ad[h0], 0.2f);
      float e1 = lrelu(a_s[(size_t)j * 4 + h1] + ad[h1], 0.2f);
      acc0 += expf(e0 - mx[h0]) * xl[(size_t)j * 32 + c0];
      acc1 += expf(e1 - mx[h1]) * xl[(size_t)j * 32 + c1];
    }
  }
  float v0 = lrelu(acc0 / den[h0] + LD(bias, c0, f), 0.01f);
  float v1 = lrelu(acc1 / den[h1] + LD(bias, c1, f), 0.01f);

  if (MODE == 0) {
    Xr[g][c0] = v0;
    Xr[g][c1] = v1;
    __syncthreads();
    float n0 = 0.f, n1 = 0.f;
#pragma unroll
    for (int k = 0; k < 32; ++k) {
      float xv = Xr[g][k];
      n0 += xv * Wn_l[k * 32 + c0];
      n1 += xv * Wn_l[k * 32 + c1];
    }
    xl_next[(size_t)i * 32 + c0] = n0;
    xl_next[(size_t)i * 32 + c1] = n1;
    float p0 = n0 * an_s[c0], q0 = n0 * an_d[c0];
    float p1 = n1 * an_s[c1], q1 = n1 * an_d[c1];
#pragma unroll
    for (int off = 1; off < 8; off <<= 1) {
      p0 += __shfl_xor(p0, off); q0 += __shfl_xor(q0, off);
      p1 += __shfl_xor(p1, off); q1 += __shfl_xor(q1, off);
    }
    if ((l & 7) == 0) {
      as_out[(size_t)i * 4 + h0] = p0;
      ad_out[(size_t)i * 4 + h0] = q0;
      as_out[(size_t)i * 4 + h1] = p1;
      ad_out[(size_t)i * 4 + h1] = q1;
    }
  } else {
    xout[(size_t)i * 32 + c0] = v0;
    xout[(size_t)i * 32 + c1] = v1;
    float pS[4], pD[4];
#pragma unroll
    for (int h = 0; h < 4; ++h) {
      pS[h] = v0 * SwaS[h * 32 + c0] + v1 * SwaS[h * 32 + c1];
      pD[h] = v0 * SwaD[h * 32 + c0] + v1 * SwaD[h * 32 + c1];
    }
#pragma unroll
    for (int off = 1; off < 16; off <<= 1)
#pragma unroll
      for (int h = 0; h < 4; ++h) { pS[h] += __shfl_xor(pS[h], off); pD[h] += __shfl_xor(pD[h], off); }
    if (l == 0) {
#pragma unroll
      for (int h = 0; h < 4; ++h) {
        as_out[(size_t)i * 4 + h] = pS[h];
        ad_out[(size_t)i * 4 + h] = pD[h];
      }
    }
  }
}

// ---------------- gather4: only rows [NV, NV+NF) ----------------
__global__ __launch_bounds__(256) void k_gather4(const int* rowptr, const int* col,
                                                 const float* a_s, const float* a_d,
                                                 const float* x, float* agg) {
  __shared__ int colb[16][64];
  __shared__ float4 eb[16][64];
  int tid = threadIdx.x;
  int g = tid >> 4, l = tid & 15;
  int i = NV + blockIdx.x * 16 + g;
  int beg = rowptr[i], end = rowptr[i + 1];
  int deg = end - beg;
  float4 adv = *(const float4*)(a_d + (size_t)i * 4);
  float4 asv = *(const float4*)(a_s + (size_t)i * 4);
  float ad[4] = {adv.x, adv.y, adv.z, adv.w};
  float es[4], mx[4];
  {
    float asl[4] = {asv.x, asv.y, asv.z, asv.w};
#pragma unroll
    for (int h = 0; h < 4; ++h) { es[h] = lrelu(asl[h] + ad[h], 0.2f); mx[h] = es[h]; }
  }
  float den[4] = {0.f, 0.f, 0.f, 0.f};
  int k0 = l, k1 = l + 16;
  float acc[4][2];

  if (deg <= 64) {
    for (int s = l; s < deg; s += 16) {
      int j = col[beg + s];
      colb[g][s] = j;
      float4 aj = *(const float4*)(a_s + (size_t)j * 4);
      float e0 = lrelu(aj.x + ad[0], 0.2f);
      float e1 = lrelu(aj.y + ad[1], 0.2f);
      float e2 = lrelu(aj.z + ad[2], 0.2f);
      float e3 = lrelu(aj.w + ad[3], 0.2f);
      eb[g][s] = make_float4(e0, e1, e2, e3);
      mx[0] = fmaxf(mx[0], e0); mx[1] = fmaxf(mx[1], e1);
      mx[2] = fmaxf(mx[2], e2); mx[3] = fmaxf(mx[3], e3);
    }
#pragma unroll
    for (int off = 1; off < 16; off <<= 1)
#pragma unroll
      for (int h = 0; h < 4; ++h) mx[h] = fmaxf(mx[h], __shfl_xor(mx[h], off));
    for (int s = l; s < deg; s += 16) {
      float4 e4 = eb[g][s];
      float x0 = expf(e4.x - mx[0]), x1 = expf(e4.y - mx[1]);
      float x2 = expf(e4.z - mx[2]), x3 = expf(e4.w - mx[3]);
      eb[g][s] = make_float4(x0, x1, x2, x3);
      den[0] += x0; den[1] += x1; den[2] += x2; den[3] += x3;
    }
#pragma unroll
    for (int off = 1; off < 16; off <<= 1)
#pragma unroll
      for (int h = 0; h < 4; ++h) den[h] += __shfl_xor(den[h], off);
    float exS[4];
#pragma unroll
    for (int h = 0; h < 4; ++h) { exS[h] = expf(es[h] - mx[h]); den[h] += exS[h]; }
    float xs0 = x[(size_t)i * 32 + k0], xs1 = x[(size_t)i * 32 + k1];
#pragma unroll
    for (int h = 0; h < 4; ++h) { acc[h][0] = exS[h] * xs0; acc[h][1] = exS[h] * xs1; }
    for (int s = 0; s < deg; ++s) {
      int j = colb[g][s];
      float4 e4 = eb[g][s];
      float xv0 = x[(size_t)j * 32 + k0], xv1 = x[(size_t)j * 32 + k1];
      acc[0][0] += e4.x * xv0; acc[0][1] += e4.x * xv1;
      acc[1][0] += e4.y * xv0; acc[1][1] += e4.y * xv1;
      acc[2][0] += e4.z * xv0; acc[2][1] += e4.z * xv1;
      acc[3][0] += e4.w * xv0; acc[3][1] += e4.w * xv1;
    }
  } else {
    for (int s = l; s < deg; s += 16) {
      int j = col[beg + s];
      float4 aj = *(const float4*)(a_s + (size_t)j * 4);
      mx[0] = fmaxf(mx[0], lrelu(aj.x + ad[0], 0.2f));
      mx[1] = fmaxf(mx[1], lrelu(aj.y + ad[1], 0.2f));
      mx[2] = fmaxf(mx[2], lrelu(aj.z + ad[2], 0.2f));
      mx[3] = fmaxf(mx[3], lrelu(aj.w + ad[3], 0.2f));
    }
#pragma unroll
    for (int off = 1; off < 16; off <<= 1)
#pragma unroll
      for (int h = 0; h < 4; ++h) mx[h] = fmaxf(mx[h], __shfl_xor(mx[h], off));
    for (int s = l; s < deg; s += 16) {
      int j = col[beg + s];
      float4 aj = *(const float4*)(a_s + (size_t)j * 4);
      den[0] += expf(lrelu(aj.x + ad[0], 0.2f) - mx[0]);
      den[1] += expf(lrelu(aj.y + ad[1], 0.2f) - mx[1]);
      den[2] += expf(lrelu(aj.z + ad[2], 0.2f) - mx[2]);
      den[3] += expf(lrelu(aj.w + ad[3], 0.2f) - mx[3]);
    }
#pragma unroll
    for (int off = 1; off < 16; off <<= 1)
#pragma unroll
      for (int h = 0; h < 4; ++h) den[h] += __shfl_xor(den[h], off);
    float exS[4];
#pragma unroll
    for (int h = 0; h < 4; ++h) { exS[h] = expf(es[h] - mx[h]); den[h] += exS[h]; }
    float xs0 = x[(size_t)i * 32 + k0], xs1 = x[(size_t)i * 32 + k1];
#pragma unroll
    for (int h = 0; h < 4; ++h) { acc[h][0] = exS[h] * xs0; acc[h][1] = exS[h] * xs1; }
    for (int s = 0; s < deg; ++s) {
      int j = col[beg + s];
      float4 aj = *(const float4*)(a_s + (size_t)j * 4);
      float xv0 = x[(size_t)j * 32 + k0], xv1 = x[(size_t)j * 32 + k1];
      acc[0][0] += expf(lrelu(aj.x + ad[0], 0.2f) - mx[0]) * xv0;
      acc[0][1] += expf(lrelu(aj.x + ad[0], 0.2f) - mx[0]) * xv1;
      acc[1][0] += expf(lrelu(aj.y + ad[1], 0.2f) - mx[1]) * xv0;
      acc[1][1] += expf(lrelu(aj.y + ad[1], 0.2f) - mx[1]) * xv1;
      acc[2][0] += expf(lrelu(aj.z + ad[2], 0.2f) - mx[2]) * xv0;
      acc[2][1] += expf(lrelu(aj.z + ad[2], 0.2f) - mx[2]) * xv1;
      acc[3][0] += expf(lrelu(aj.w + ad[3], 0.2f) - mx[3]) * xv0;
      acc[3][1] += expf(lrelu(aj.w + ad[3], 0.2f) - mx[3]) * xv1;
    }
  }
#pragma unroll
  for (int h = 0; h < 4; ++h) {
    agg[(size_t)i * 128 + h * 32 + k0] = acc[h][0] / den[h];
    agg[(size_t)i * 128 + h * 32 + k1] = acc[h][1] / den[h];
  }
}

// ---------------- L4 epilogue + fused qk: only rows [NV, NV+NF) ----------------
__global__ __launch_bounds__(256) void k_l4_out(const float* agg, const void* W4, const void* b4,
                                                const float* wqv, const float* wkv,
                                                float* qs, float* ks, const int* flg) {
  int f = flg[0];
  __shared__ float Wl[128 * 64];
  __shared__ float Al[64][132];
  __shared__ float Ql[256], Kl[256];
  int tid = threadIdx.x;
  int R0 = NV + blockIdx.x * 64;
  for (int t = tid; t < 128 * 64; t += 256) {
    int K = t >> 6, c = t & 63;
    int h = K >> 5, k = K & 31;
    Wl[t] = LD(W4, k * 256 + h * 64 + c, f);
  }
  {
    const float4* ag4 = (const float4*)(agg + (size_t)R0 * 128);
    for (int t = tid; t < 2048; t += 256) {
      int r = t >> 5, k4 = (t & 31) << 2;
      float4 v = ag4[t];
      *(float4*)&Al[r][k4] = v;
    }
  }
  if (tid < 256) { Ql[tid] = wqv[tid]; Kl[tid] = wkv[tid]; }
  __syncthreads();
  int c0 = (tid & 15) << 2, r0 = (tid >> 4) << 2;
  float acc[4][4];
#pragma unroll
  for (int j = 0; j < 4; ++j)
#pragma unroll
    for (int i = 0; i < 4; ++i) acc[j][i] = 0.f;
#pragma unroll 4
  for (int K = 0; K < 128; ++K) {
    float4 wv = *(const float4*)&Wl[K * 64 + c0];
    float a0 = Al[r0][K], a1 = Al[r0 + 1][K], a2 = Al[r0 + 2][K], a3 = Al[r0 + 3][K];
    acc[0][0] += a0 * wv.x; acc[0][1] += a0 * wv.y; acc[0][2] += a0 * wv.z; acc[0][3] += a0 * wv.w;
    acc[1][0] += a1 * wv.x; acc[1][1] += a1 * wv.y; acc[1][2] += a1 * wv.z; acc[1][3] += a1 * wv.w;
    acc[2][0] += a2 * wv.x; acc[2][1] += a2 * wv.y; acc[2][2] += a2 * wv.z; acc[2][3] += a2 * wv.w;
    acc[3][0] += a3 * wv.x; acc[3][1] += a3 * wv.y; acc[3][2] += a3 * wv.z; acc[3][3] += a3 * wv.w;
  }
  float bv[4];
#pragma unroll
  for (int i = 0; i < 4; ++i) bv[i] = LD(b4, c0 + i, f);
  float o[4][4];
#pragma unroll
  for (int j = 0; j < 4; ++j)
#pragma unroll
    for (int i = 0; i < 4; ++i) o[j][i] = lrelu(0.25f * acc[j][i] + bv[i], 0.01f);
  // fused qk: dot(out_row, wqv/wkv) per head; reduce across the 16 lanes of each row
  int nbase = R0 - NV + r0;
#pragma unroll
  for (int j = 0; j < 4; ++j) {
#pragma unroll
    for (int h = 0; h < 4; ++h) {
      float pq = o[j][0] * Ql[h * 64 + c0] + o[j][1] * Ql[h * 64 + c0 + 1] +
                 o[j][2] * Ql[h * 64 + c0 + 2] + o[j][3] * Ql[h * 64 + c0 + 3];
      float pk = o[j][0] * Kl[h * 64 + c0] + o[j][1] * Kl[h * 64 + c0 + 1] +
                 o[j][2] * Kl[h * 64 + c0 + 2] + o[j][3] * Kl[h * 64 + c0 + 3];
#pragma unroll
      for (int off = 1; off < 16; off <<= 1) {
        pq += __shfl_xor(pq, off);
        pk += __shfl_xor(pk, off);
      }
      if ((tid & 15) == 0) {
        qs[(size_t)(nbase + j) * 4 + h] = pq;
        ks[(size_t)(nbase + j) * 4 + h] = pk;
      }
    }
  }
}

__global__ void k_groups(const int* full, const void* mask, const int* tgt, const int* mult,
                         const float* qs, const float* ks, const void* att_b, void* outv,
                         const int* flg) {
  int f = flg[0], mbyte = flg[1];
  int g = blockIdx.x;
  int lane = threadIdx.x;
  int k = lane >> 2, h = lane & 3;
  int t = tgt[g];
  int idx = full[g * KK + k];
  int mk = MK(mask, g * KK + k, mbyte);
  float bh = LD(att_b, h, f);
  float qt = qs[t * 4 + h];
  float sc = sigm(qt + ks[idx * 4 + h] + bh);
  int is_tgt = (idx == t) && mk;
  int nbr = mk && !is_tgt;
  unsigned long long bal = __ballot(nbr != 0);
  int degm1 = (int)(__popcll(bal) >> 2);
  float ssum = nbr ? sc : 0.f;
  for (int off = 4; off < 64; off <<= 1) ssum += __shfl_xor(ssum, off);
  ssum /= (float)(degm1 > 1 ? degm1 : 1);
  float trg = sigm(qt + ks[t * 4 + h] + bh);
  float mxv = fmaxf(ssum, trg);
  float e0 = expf(ssum - mxv), e1 = expf(trg - mxv);
  float tw0 = e0 / (e0 + e1), tw1 = e1 / (e0 + e1);
  float msc = nbr ? sc : -1e30f;
  float m = msc;
  for (int off = 4; off < 64; off <<= 1) m = fmaxf(m, __shfl_xor(m, off));
  float ex = expf(msc - m);
  float den = ex;
  for (int off = 4; off < 64; off <<= 1) den += __shfl_xor(den, off);
  float w = ex / den * tw0 * (float)mult[g];
  float res = is_tgt ? tw1 : (nbr ? w : 0.f);
  if (degm1 == 0) res = 0.f;
  ST(outv, g * 64 + k * 4 + h, f, res);
}

extern "C" void kernel_launch(void* const* d_in, const int* in_sizes, int n_in,
                              void* d_out, int out_size, void* d_ws, size_t ws_size,
                              hipStream_t stream) {
  const int* edge = (const int*)d_in[0];
  const int* esrc = edge;
  const int* edst = edge + EE;
  const int* vn_colors = (const int*)d_in[1];
  const int* group_full = (const int*)d_in[2];
  const void* group_mask = d_in[3];
  const int* group_tgt = (const int*)d_in[4];
  const int* group_mult = (const int*)d_in[5];
  const void* vn_prefix = d_in[6];
  const void* fn_embed = d_in[7];
  const void* v2f_msgs = d_in[8];
  const void* v2f_hidden = d_in[9];
  const void* f2v_msgs = d_in[10];
  const void* f2v_hidden = d_in[11];
  const void* msg_prefix = d_in[12];
  const void* emb = d_in[13];
  const void* gv_wih = d_in[14];
  const void* gv_whh = d_in[15];
  const void* gv_bih = d_in[16];
  const void* gv_bhh = d_in[17];
  const void* gf_wih = d_in[18];
  const void* gf_whh = d_in[19];
  const void* gf_bih = d_in[20];
  const void* gf_bhh = d_in[21];
  const void* W1 = d_in[22];
  const void* a1s = d_in[23];
  const void* a1d = d_in[24];
  const void* b1 = d_in[25];
  const void* W2 = d_in[26];
  const void* a2s = d_in[27];
  const void* a2d = d_in[28];
  const void* b2 = d_in[29];
  const void* W3 = d_in[30];
  const void* a3s = d_in[31];
  const void* a3d = d_in[32];
  const void* b3 = d_in[33];
  const void* W4 = d_in[34];
  const void* a4s = d_in[35];
  const void* a4d = d_in[36];
  const void* b4 = d_in[37];
  const void* att_wq = d_in[38];
  const void* att_wk = d_in[39];
  const void* att_ws = d_in[40];
  const void* att_b = d_in[41];

  char* w = (char*)d_ws;
  size_t off = 0;
  auto carve = [&](size_t bytes) -> void* {
    void* p = w + off;
    off += (bytes + 255) & ~(size_t)255;
    return p;
  };
  int* flags = (int*)carve(16);
  float* Wt = (float*)carve((size_t)2 * 77 * 192 * 4);
  float* hidcat = (float*)carve((size_t)2 * NM * EMB * 4);
  float* xB = (float*)carve((size_t)NN * 64 * 4);
  float* scr = (float*)carve((size_t)NN * 128 * 4);
  float* a_sA = (float*)carve((size_t)NN * 4 * 4);
  float* a_dA = (float*)carve((size_t)NN * 4 * 4);
  float* a_sB = (float*)carve((size_t)NN * 4 * 4);
  float* a_dB = (float*)carve((size_t)NN * 4 * 4);
  int* deg = (int*)carve((size_t)2 * NN * 4);  // deg + cnt adjacent
  int* cnt = deg + NN;
  int* rowptr = (int*)carve((size_t)(NN + 1) * 4);
  int* bsum = (int*)carve(128 * 4);
  int* boff = (int*)carve(128 * 4);
  int* col = (int*)carve((size_t)EE * 4);
  float* qs = (float*)carve((size_t)NF * 4 * 4);
  float* ks = (float*)carve((size_t)NF * 4 * 4);
  float* wqv = (float*)carve(256 * 4);
  float* wkv = (float*)carve(256 * 4);
  float* waS = (float*)carve(128 * 4);
  float* waD = (float*)carve(128 * 4);

  hipMemsetAsync(deg, 0, (size_t)2 * NN * 4, stream);

  k_detect<<<1, 64, 0, stream>>>(fn_embed, group_mask, flags);
  k_precomp<<<118, 256, 0, stream>>>(gv_wih, gv_whh, gf_wih, gf_whh, W4, a4s, a4d,
                                     att_wq, att_wk, att_ws, Wt, waS, waD, wqv, wkv, flags);
  k_gru2<<<768, 256, 0, stream>>>(v2f_msgs, v2f_hidden, f2v_msgs, f2v_hidden,
                                  gv_bih, gv_bhh, gf_bih, gf_bhh, Wt, hidcat, d_out, flags);
  k_deg<<<EE / 256, 256, 0, stream>>>(edst, deg);
  k_scan1<<<72, 512, 0, stream>>>(deg, rowptr, bsum);
  k_scan2<<<1, 128, 0, stream>>>(bsum, boff, 72);
  k_scan3<<<(NN + 256) / 256, 256, 0, stream>>>(rowptr, boff);
  k_fill<<<EE / 256, 256, 0, stream>>>(esrc, edst, rowptr, cnt, col);

  // L1: assemble + x@W1 + coef1  -> xl1 in scr, coefs in A
  k_xl1<<<NN / 8, 256, 0, stream>>>(vn_prefix, vn_colors, emb, fn_embed, msg_prefix,
                                    hidcat, W1, a1s, a1d, scr, a_sA, a_dA, flags);
  // gather L1 (+xl2+coef2): scr,A -> xB,B
  k_gather13<0><<<NN / 16, 256, 0, stream>>>(rowptr, col, a_sA, a_dA, scr, b1,
                                             W2, a2s, a2d, nullptr, nullptr,
                                             xB, nullptr, a_sB, a_dB, flags);
  // gather L2 (+xl3+coef3): xB,B -> scr,A
  k_gather13<0><<<NN / 16, 256, 0, stream>>>(rowptr, col, a_sB, a_dB, xB, b2,
                                             W3, a3s, a3d, nullptr, nullptr,
                                             scr, nullptr, a_sA, a_dA, flags);
  // gather L3 (+act out + coef4): scr,A -> xB (act), B (coef4)
  k_gather13<1><<<NN / 16, 256, 0, stream>>>(rowptr, col, a_sA, a_dA, scr, b3,
                                             nullptr, nullptr, nullptr, waS, waD,
                                             nullptr, xB, a_sB, a_dB, flags);
  // L4 (only fn rows): gather4 -> agg in scr; l4_out + fused qk -> qs/ks
  k_gather4<<<NF / 16, 256, 0, stream>>>(rowptr, col, a_sB, a_dB, xB, scr);
  k_l4_out<<<NF / 64, 256, 0, stream>>>(scr, W4, b4, wqv, wkv, qs, ks, flags);

  k_groups<<<GG, 64, 0, stream>>>(group_full, group_mask, group_tgt, group_mult,
                                  qs, ks, att_b, d_out, flags);
}

// Round 9
// 208.797 us; speedup vs baseline: 6.3916x; 1.0023x over previous
//
#include <hip/hip_runtime.h>
#include <hip/hip_bf16.h>

#define NV 8192
#define NF 4096
#define NM 12288
#define PFX 3
#define DOM 16
#define EMB 61
#define NN 36864
#define EE 262144
#define GG 8192
#define KK 16
#define OUT0 524288

typedef __hip_bfloat16 bf16;
__device__ __forceinline__ float b2f(bf16 x) { return __bfloat162float(x); }
__device__ __forceinline__ float lrelu(float x, float s) { return x > 0.f ? x : s * x; }
__device__ __forceinline__ float sigm(float x) { return 1.f / (1.f + expf(-x)); }
__device__ __forceinline__ float fexp(float x) { return __expf(fminf(x, 60.f)); }
__device__ __forceinline__ float LD(const void* p, int i, int f) {
  return f ? ((const float*)p)[i] : b2f(((const bf16*)p)[i]);
}
__device__ __forceinline__ void ST(void* p, int i, int f, float v) {
  if (f) ((float*)p)[i] = v; else ((bf16*)p)[i] = __float2bfloat16(v);
}
__device__ __forceinline__ int MK(const void* p, int i, int bytey) {
  return bytey ? (int)((const signed char*)p)[i] : ((const int*)p)[i];
}

// -------- dtype detector --------
__global__ void k_detect(const void* fn, const void* mask, int* flags) {
  if (threadIdx.x || blockIdx.x) return;
  int wild = 0;
  const bf16* h = (const bf16*)fn;
  for (int i = 0; i < 128; ++i) {
    float x = b2f(h[i]);
    float a = fabsf(x);
    if (a != a || a > 1e4f || (x != 0.f && a < 1e-8f)) ++wild;
  }
  flags[0] = (wild >= 8) ? 1 : 0;
  const int* mi = (const int*)mask;
  int bytey = 0;
  for (int i = 0; i < 64; ++i) {
    unsigned v = (unsigned)mi[i];
    if (v > 1u) bytey = 1;
  }
  flags[1] = bytey;
}

// -------- fused precompute: Wt (0-115), waS/waD (116), wqv/wkv (117), zero deg/cnt (118+) --
__global__ void k_precomp(const void* gv_wih, const void* gv_whh,
                          const void* gf_wih, const void* gf_whh,
                          const void* W4, const void* a4s, const void* a4d,
                          const void* wq, const void* wk, const void* ws,
                          float* Wt, float* waS, float* waD, float* wqv, float* wkv,
                          int* deg0, const int* flg) {
  int f = flg[0];
  int blk = blockIdx.x, tid = threadIdx.x;
  if (blk < 116) {
    int t = blk * 256 + tid;
    if (t < 2 * 77 * 192) {
      int dir = t / (77 * 192);
      int rem = t - dir * 77 * 192;
      int d = rem / 192, o = rem - d * 192;
      const void* wih = dir ? gf_wih : gv_wih;
      const void* whh = dir ? gf_whh : gv_whh;
      float v = 0.f;
      if (o < 183) v = (d < 16) ? LD(wih, o * 16 + d, f) : LD(whh, o * 61 + (d - 16), f);
      Wt[t] = v;
    }
  } else if (blk == 116) {
    int isD = tid >= 128;
    int u = tid & 127;
    int h = u >> 5, k = u & 31;
    const void* av = isD ? a4d : a4s;
    float acc = 0.f;
    for (int c = 0; c < 64; ++c) acc += LD(W4, k * 256 + h * 64 + c, f) * LD(av, h * 64 + c, f);
    (isD ? waD : waS)[h * 32 + k] = acc;
  } else if (blk == 117) {
    int h = tid >> 6, d = tid & 63;
    float q = 0.f, k = 0.f;
    for (int e = 0; e < 64; ++e) {
      q += LD(wq, h * 4096 + d * 64 + e, f) * LD(ws, h * 128 + e, f);
      k += LD(wk, h * 4096 + d * 64 + e, f) * LD(ws, h * 128 + 64 + e, f);
    }
    wqv[h * 64 + d] = q;
    wkv[h * 64 + d] = k;
  } else {
    int t = (blk - 118) * 256 + tid;
    if (t < 2 * NN) deg0[t] = 0;
  }
}

// ---------------- GRU v3: 32 rows/block ----------------
__global__ __launch_bounds__(256) void k_gru2(
    const void* v2f_msgs, const void* v2f_hid, const void* f2v_msgs, const void* f2v_hid,
    const void* gv_bih, const void* gv_bhh, const void* gf_bih, const void* gf_bhh,
    const float* Wt, float* hidcat, void* outv, const int* flg) {
  int f = flg[0];
  int blk = blockIdx.x;
  int dir = blk >= 384;
  int loc = dir ? blk - 384 : blk;
  int gr0 = loc * 32;
  const void* msgs = dir ? f2v_msgs : v2f_msgs;
  const void* hid = dir ? f2v_hid : v2f_hid;
  const void* bih = dir ? gf_bih : gv_bih;
  const void* bhh = dir ? gf_bhh : gv_bhh;
  const float* W = Wt + dir * 77 * 192;

  __shared__ float smem[7808];
  float* F = smem;
  float* G1 = smem;
  float* G2 = smem + 32 * 183;

  int tid = threadIdx.x;
  for (int idx = tid; idx < 32 * 16; idx += 256) {
    int r = idx >> 4, d = idx & 15;
    F[d * 36 + r] = LD(msgs, (gr0 + r) * DOM + d, f);
  }
  for (int idx = tid; idx < 32 * 61; idx += 256) {
    int r = idx / 61, d = idx - r * 61;
    F[(16 + d) * 36 + r] = LD(hid, gr0 * 61 + idx, f);
  }
  __syncthreads();

  int og = tid & 15, rg = tid >> 4;
  int o0 = og * 12, r0 = rg * 2;
  float accA[24], accB[24];
#pragma unroll
  for (int i = 0; i < 24; ++i) { accA[i] = 0.f; accB[i] = 0.f; }

#pragma unroll 2
  for (int d = 0; d < 16; ++d) {
    const float2 fv2 = *(const float2*)&F[d * 36 + r0];
    const float4 w0 = *(const float4*)&W[d * 192 + o0];
    const float4 w1 = *(const float4*)&W[d * 192 + o0 + 4];
    const float4 w2 = *(const float4*)&W[d * 192 + o0 + 8];
    float wv[12] = {w0.x, w0.y, w0.z, w0.w, w1.x, w1.y, w1.z, w1.w, w2.x, w2.y, w2.z, w2.w};
#pragma unroll
    for (int k = 0; k < 12; ++k) {
      accA[k * 2 + 0] += wv[k] * fv2.x;
      accA[k * 2 + 1] += wv[k] * fv2.y;
    }
  }
#pragma unroll 2
  for (int d = 16; d < 77; ++d) {
    const float2 fv2 = *(const float2*)&F[d * 36 + r0];
    const float4 w0 = *(const float4*)&W[d * 192 + o0];
    const float4 w1 = *(const float4*)&W[d * 192 + o0 + 4];
    const float4 w2 = *(const float4*)&W[d * 192 + o0 + 8];
    float wv[12] = {w0.x, w0.y, w0.z, w0.w, w1.x, w1.y, w1.z, w1.w, w2.x, w2.y, w2.z, w2.w};
#pragma unroll
    for (int k = 0; k < 12; ++k) {
      accB[k * 2 + 0] += wv[k] * fv2.x;
      accB[k * 2 + 1] += wv[k] * fv2.y;
    }
  }
  __syncthreads();

#pragma unroll
  for (int k = 0; k < 12; ++k) {
    int o = o0 + k;
    if (o < 183) {
      float biv = LD(bih, o, f), bhv = LD(bhh, o, f);
#pragma unroll
      for (int m = 0; m < 2; ++m) {
        int r = r0 + m;
        float gi = accA[k * 2 + m] + biv;
        float gh = accB[k * 2 + m] + bhv;
        if (o < 122) G1[r * 183 + o] = gi + gh;
        else { G1[r * 183 + o] = gi; G2[r * 61 + (o - 122)] = gh; }
      }
    }
  }
  __syncthreads();

  int j = tid & 63, rq = tid >> 6;
  if (j < 61) {
    for (int rr = 0; rr < 8; ++rr) {
      int r = rq * 8 + rr;
      float gr = sigm(G1[r * 183 + j]);
      float gz = sigm(G1[r * 183 + 61 + j]);
      float gn = tanhf(G1[r * 183 + 122 + j] + gr * G2[r * 61 + j]);
      float hold = LD(hid, (gr0 + r) * 61 + j, f);
      float hn = (1.f - gz) * gn + gz * hold;
      int b = dir * NM + gr0 + r;
      hidcat[b * 61 + j] = hn;
      ST(outv, OUT0 + b * 61 + j, f, hn);
    }
  }
}

// ---------------- CSR build ----------------
__global__ void k_deg(const int* dst, int* deg) {
  int e = blockIdx.x * blockDim.x + threadIdx.x;
  if (e < EE) atomicAdd(&deg[dst[e]], 1);
}
__global__ void k_scan1(const int* deg, int* rowptr, int* bsum) {
  __shared__ int s[512];
  int g = blockIdx.x * 512 + threadIdx.x;
  int v = (g < NN) ? deg[g] : 0;
  s[threadIdx.x] = v;
  __syncthreads();
  for (int off = 1; off < 512; off <<= 1) {
    int t = (threadIdx.x >= off) ? s[threadIdx.x - off] : 0;
    __syncthreads();
    s[threadIdx.x] += t;
    __syncthreads();
  }
  if (g < NN) rowptr[g] = s[threadIdx.x] - v;
  if (threadIdx.x == 511) bsum[blockIdx.x] = s[511];
}
// scan of block sums + add to rowptr, single block of 512
__global__ void k_scan23(int* rowptr, const int* bsum, int nb) {
  __shared__ int ps[128];
  int tid = threadIdx.x;
  int v = 0;
  if (tid < 128) { v = (tid < nb) ? bsum[tid] : 0; ps[tid] = v; }
  __syncthreads();
  for (int off = 1; off < 128; off <<= 1) {
    int t = 0;
    if (tid < 128 && tid >= off) t = ps[tid - off];
    __syncthreads();
    if (tid < 128) ps[tid] += t;
    __syncthreads();
  }
  if (tid < 128) ps[tid] -= v;  // exclusive
  __syncthreads();
  for (int g = tid; g < NN; g += 512) rowptr[g] += ps[g >> 9];
  if (tid == 0) rowptr[NN] = EE;
}
__global__ void k_fill(const int* src, const int* dst, const int* rowptr, int* cnt, int* col) {
  int e = blockIdx.x * blockDim.x + threadIdx.x;
  if (e < EE) {
    int d = dst[e];
    int pos = rowptr[d] + atomicAdd(&cnt[d], 1);
    col[pos] = src[e];
  }
}

// ---------------- L1: fused assemble + x@W1 + coef ----------------
__global__ __launch_bounds__(256) void k_xl1(
    const void* vn_prefix, const int* vn_colors, const void* emb, const void* fn_embed,
    const void* msg_prefix, const float* hidcat, const void* W1, const void* a1s,
    const void* a1d, float* xl, float* a_s, float* a_d, const int* flg) {
  int f = flg[0];
  __shared__ float Wl[64 * 32];
  __shared__ float X[8][64];
  int tid = threadIdx.x;
  for (int t = tid; t < 2048; t += 256) Wl[t] = LD(W1, t, f);
  for (int t = tid; t < 512; t += 256) {
    int r = t >> 6, c = t & 63;
    int i = blockIdx.x * 8 + r;
    float v;
    if (i < NV) {
      v = (c < PFX) ? LD(vn_prefix, i * PFX + c, f) : LD(emb, vn_colors[i] * EMB + (c - PFX), f);
    } else if (i < NV + NF) {
      v = LD(fn_embed, (size_t)(i - NV) * 64 + c, f);
    } else {
      int jj = i - NV - NF;
      v = (c < PFX) ? LD(msg_prefix, jj * PFX + c, f) : hidcat[jj * EMB + (c - PFX)];
    }
    X[r][c] = v;
  }
  __syncthreads();
  int j = tid & 31, r = tid >> 5;
  int i = blockIdx.x * 8 + r;
  float acc = 0.f;
#pragma unroll
  for (int k = 0; k < 64; ++k) acc += X[r][k] * Wl[k * 32 + j];
  xl[(size_t)i * 32 + j] = acc;
  float sw = LD(a1s, j, f), dw = LD(a1d, j, f);
  float p = acc * sw, q = acc * dw;
#pragma unroll
  for (int off = 1; off < 8; off <<= 1) {
    p += __shfl_xor(p, off);
    q += __shfl_xor(q, off);
  }
  if ((j & 7) == 0) {
    a_s[(size_t)i * 4 + (j >> 3)] = p;
    a_d[(size_t)i * 4 + (j >> 3)] = q;
  }
}

// ---------------- GAT gather (max-free softmax): MODE0 = +next xl+coef; MODE1 = L3 -------
template <int MODE>
__global__ __launch_bounds__(256) void k_gather13(
    const int* rowptr, const int* col, const float* a_s, const float* a_d,
    const float* xl, const void* bias,
    const void* Wn, const void* asn_, const void* adn_,      // MODE0
    const float* waS, const float* waD,                       // MODE1
    float* xl_next, float* xout, float* as_out, float* ad_out, const int* flg) {
  int f = flg[0];
  __shared__ int colb[16][64];
  __shared__ float4 eb[16][64];
  __shared__ float Wn_l[32 * 32];
  __shared__ float an_s[32], an_d[32];
  __shared__ float Xr[16][33];
  __shared__ float SwaS[128], SwaD[128];
  int tid = threadIdx.x;
  if (MODE == 0) {
    for (int t = tid; t < 1024; t += 256) Wn_l[t] = LD(Wn, t, f);
    if (tid < 32) { an_s[tid] = LD(asn_, tid, f); an_d[tid] = LD(adn_, tid, f); }
  } else {
    if (tid < 128) { SwaS[tid] = waS[tid]; SwaD[tid] = waD[tid]; }
  }
  int g = tid >> 4, l = tid & 15;
  int i = blockIdx.x * 16 + g;
  int beg = rowptr[i], end = rowptr[i + 1];
  int deg = end - beg;
  float4 adv = *(const float4*)(a_d + (size_t)i * 4);
  float4 asv = *(const float4*)(a_s + (size_t)i * 4);
  float ad[4] = {adv.x, adv.y, adv.z, adv.w};
  float exS[4];
  {
    float asl[4] = {asv.x, asv.y, asv.z, asv.w};
#pragma unroll
    for (int h = 0; h < 4; ++h) exS[h] = fexp(lrelu(asl[h] + ad[h], 0.2f));
  }
  float den[4] = {0.f, 0.f, 0.f, 0.f};
  int c0 = l, c1 = l + 16;
  int h0 = l >> 3, h1 = 2 + (l >> 3);
  float acc0, acc1;

  if (deg <= 64) {
    // single edge pass: exp directly (no max), cache col + exp-scores in LDS
    for (int s = l; s < deg; s += 16) {
      int j = col[beg + s];
      colb[g][s] = j;
      float4 aj = *(const float4*)(a_s + (size_t)j * 4);
      float x0 = fexp(lrelu(aj.x + ad[0], 0.2f));
      float x1 = fexp(lrelu(aj.y + ad[1], 0.2f));
      float x2 = fexp(lrelu(aj.z + ad[2], 0.2f));
      float x3 = fexp(lrelu(aj.w + ad[3], 0.2f));
      eb[g][s] = make_float4(x0, x1, x2, x3);
      den[0] += x0; den[1] += x1; den[2] += x2; den[3] += x3;
    }
#pragma unroll
    for (int off = 1; off < 16; off <<= 1)
#pragma unroll
      for (int h = 0; h < 4; ++h) den[h] += __shfl_xor(den[h], off);
#pragma unroll
    for (int h = 0; h < 4; ++h) den[h] += exS[h];
    acc0 = exS[h0] * xl[(size_t)i * 32 + c0];
    acc1 = exS[h1] * xl[(size_t)i * 32 + c1];
#pragma unroll 2
    for (int s = 0; s < deg; ++s) {
      int j = colb[g][s];
      float4 e4 = eb[g][s];
      float w0 = h0 ? e4.y : e4.x;
      float w1 = (l >> 3) ? e4.w : e4.z;
      acc0 += w0 * xl[(size_t)j * 32 + c0];
      acc1 += w1 * xl[(size_t)j * 32 + c1];
    }
  } else {
    // generic path: recompute exp scores
    for (int s = l; s < deg; s += 16) {
      int j = col[beg + s];
      float4 aj = *(const float4*)(a_s + (size_t)j * 4);
      den[0] += fexp(lrelu(aj.x + ad[0], 0.2f));
      den[1] += fexp(lrelu(aj.y + ad[1], 0.2f));
      den[2] += fexp(lrelu(aj.z + ad[2], 0.2f));
      den[3] += fexp(lrelu(aj.w + ad[3], 0.2f));
    }
#pragma unroll
    for (int off = 1; off < 16; off <<= 1)
#pragma unroll
      for (int h = 0; h < 4; ++h) den[h] += __shfl_xor(den[h], off);
#pragma unroll
    for (int h = 0; h < 4; ++h) den[h] += exS[h];
    acc0 = exS[h0] * xl[(size_t)i * 32 + c0];
    acc1 = exS[h1] * xl[(size_t)i * 32 + c1];
    for (int s = 0; s < deg; ++s) {
      int j = col[beg + s];
      float e0 = fexp(lrelu(a_s[(size_t)j * 4 + h0] + ad[h0], 0.2f));
      float e1 = fexp(lrelu(a_s[(size_t)j * 4 + h1] + ad[h1], 0.2f));
      acc0 += e0 * xl[(size_t)j * 32 + c0];
      acc1 += e1 * xl[(size_t)j * 32 + c1];
    }
  }
  float v0 = lrelu(acc0 / den[h0] + LD(bias, c0, f), 0.01f);
  float v1 = lrelu(acc1 / den[h1] + LD(bias, c1, f), 0.01f);

  if (MODE == 0) {
    Xr[g][c0] = v0;
    Xr[g][c1] = v1;
    __syncthreads();
    float n0 = 0.f, n1 = 0.f;
#pragma unroll
    for (int k = 0; k < 32; ++k) {
      float xv = Xr[g][k];
      n0 += xv * Wn_l[k * 32 + c0];
      n1 += xv * Wn_l[k * 32 + c1];
    }
    xl_next[(size_t)i * 32 + c0] = n0;
    xl_next[(size_t)i * 32 + c1] = n1;
    float p0 = n0 * an_s[c0], q0 = n0 * an_d[c0];
    float p1 = n1 * an_s[c1], q1 = n1 * an_d[c1];
#pragma unroll
    for (int off = 1; off < 8; off <<= 1) {
      p0 += __shfl_xor(p0, off); q0 += __shfl_xor(q0, off);
      p1 += __shfl_xor(p1, off); q1 += __shfl_xor(q1, off);
    }
    if ((l & 7) == 0) {
      as_out[(size_t)i * 4 + h0] = p0;
      ad_out[(size_t)i * 4 + h0] = q0;
      as_out[(size_t)i * 4 + h1] = p1;
      ad_out[(size_t)i * 4 + h1] = q1;
    }
  } else {
    xout[(size_t)i * 32 + c0] = v0;
    xout[(size_t)i * 32 + c1] = v1;
    float pS[4], pD[4];
#pragma unroll
    for (int h = 0; h < 4; ++h) {
      pS[h] = v0 * SwaS[h * 32 + c0] + v1 * SwaS[h * 32 + c1];
      pD[h] = v0 * SwaD[h * 32 + c0] + v1 * SwaD[h * 32 + c1];
    }
#pragma unroll
    for (int off = 1; off < 16; off <<= 1)
#pragma unroll
      for (int h = 0; h < 4; ++h) { pS[h] += __shfl_xor(pS[h], off); pD[h] += __shfl_xor(pD[h], off); }
    if (l == 0) {
#pragma unroll
      for (int h = 0; h < 4; ++h) {
        as_out[(size_t)i * 4 + h] = pS[h];
        ad_out[(size_t)i * 4 + h] = pD[h];
      }
    }
  }
}

// ---------------- gather4 (max-free): only rows [NV, NV+NF) ----------------
__global__ __launch_bounds__(256) void k_gather4(const int* rowptr, const int* col,
                                                 const float* a_s, const float* a_d,
                                                 const float* x, float* agg) {
  __shared__ int colb[16][64];
  __shared__ float4 eb[16][64];
  int tid = threadIdx.x;
  int g = tid >> 4, l = tid & 15;
  int i = NV + blockIdx.x * 16 + g;
  int beg = rowptr[i], end = rowptr[i + 1];
  int deg = end - beg;
  float4 adv = *(const float4*)(a_d + (size_t)i * 4);
  float4 asv = *(const float4*)(a_s + (size_t)i * 4);
  float ad[4] = {adv.x, adv.y, adv.z, adv.w};
  float exS[4];
  {
    float asl[4] = {asv.x, asv.y, asv.z, asv.w};
#pragma unroll
    for (int h = 0; h < 4; ++h) exS[h] = fexp(lrelu(asl[h] + ad[h], 0.2f));
  }
  float den[4] = {0.f, 0.f, 0.f, 0.f};
  int k0 = l, k1 = l + 16;
  float acc[4][2];

  if (deg <= 64) {
    for (int s = l; s < deg; s += 16) {
      int j = col[beg + s];
      colb[g][s] = j;
      float4 aj = *(const float4*)(a_s + (size_t)j * 4);
      float x0 = fexp(lrelu(aj.x + ad[0], 0.2f));
      float x1 = fexp(lrelu(aj.y + ad[1], 0.2f));
      float x2 = fexp(lrelu(aj.z + ad[2], 0.2f));
      float x3 = fexp(lrelu(aj.w + ad[3], 0.2f));
      eb[g][s] = make_float4(x0, x1, x2, x3);
      den[0] += x0; den[1] += x1; den[2] += x2; den[3] += x3;
    }
#pragma unroll
    for (int off = 1; off < 16; off <<= 1)
#pragma unroll
      for (int h = 0; h < 4; ++h) den[h] += __shfl_xor(den[h], off);
    float xs0 = x[(size_t)i * 32 + k0], xs1 = x[(size_t)i * 32 + k1];
#pragma unroll
    for (int h = 0; h < 4; ++h) {
      den[h] += exS[h];
      acc[h][0] = exS[h] * xs0;
      acc[h][1] = exS[h] * xs1;
    }
#pragma unroll 2
    for (int s = 0; s < deg; ++s) {
      int j = colb[g][s];
      float4 e4 = eb[g][s];
      float xv0 = x[(size_t)j * 32 + k0], xv1 = x[(size_t)j * 32 + k1];
      acc[0][0] += e4.x * xv0; acc[0][1] += e4.x * xv1;
      acc[1][0] += e4.y * xv0; acc[1][1] += e4.y * xv1;
      acc[2][0] += e4.z * xv0; acc[2][1] += e4.z * xv1;
      acc[3][0] += e4.w * xv0; acc[3][1] += e4.w * xv1;
    }
  } else {
    for (int s = l; s < deg; s += 16) {
      int j = col[beg + s];
      float4 aj = *(const float4*)(a_s + (size_t)j * 4);
      den[0] += fexp(lrelu(aj.x + ad[0], 0.2f));
      den[1] += fexp(lrelu(aj.y + ad[1], 0.2f));
      den[2] += fexp(lrelu(aj.z + ad[2], 0.2f));
      den[3] += fexp(lrelu(aj.w + ad[3], 0.2f));
    }
#pragma unroll
    for (int off = 1; off < 16; off <<= 1)
#pragma unroll
      for (int h = 0; h < 4; ++h) den[h] += __shfl_xor(den[h], off);
    float xs0 = x[(size_t)i * 32 + k0], xs1 = x[(size_t)i * 32 + k1];
#pragma unroll
    for (int h = 0; h < 4; ++h) {
      den[h] += exS[h];
      acc[h][0] = exS[h] * xs0;
      acc[h][1] = exS[h] * xs1;
    }
    for (int s = 0; s < deg; ++s) {
      int j = col[beg + s];
      float4 aj = *(const float4*)(a_s + (size_t)j * 4);
      float e0 = fexp(lrelu(aj.x + ad[0], 0.2f));
      float e1 = fexp(lrelu(aj.y + ad[1], 0.2f));
      float e2 = fexp(lrelu(aj.z + ad[2], 0.2f));
      float e3 = fexp(lrelu(aj.w + ad[3], 0.2f));
      float xv0 = x[(size_t)j * 32 + k0], xv1 = x[(size_t)j * 32 + k1];
      acc[0][0] += e0 * xv0; acc[0][1] += e0 * xv1;
      acc[1][0] += e1 * xv0; acc[1][1] += e1 * xv1;
      acc[2][0] += e2 * xv0; acc[2][1] += e2 * xv1;
      acc[3][0] += e3 * xv0; acc[3][1] += e3 * xv1;
    }
  }
#pragma unroll
  for (int h = 0; h < 4; ++h) {
    agg[(size_t)i * 128 + h * 32 + k0] = acc[h][0] / den[h];
    agg[(size_t)i * 128 + h * 32 + k1] = acc[h][1] / den[h];
  }
}

// ---------------- L4 epilogue + fused qk: only rows [NV, NV+NF) ----------------
__global__ __launch_bounds__(256) void k_l4_out(const float* agg, const void* W4, const void* b4,
                                                const float* wqv, const float* wkv,
                                                float* qs, float* ks, const int* flg) {
  int f = flg[0];
  __shared__ float Wl[128 * 64];
  __shared__ float Al[64][132];
  __shared__ float Ql[256], Kl[256];
  int tid = threadIdx.x;
  int R0 = NV + blockIdx.x * 64;
  for (int t = tid; t < 128 * 64; t += 256) {
    int K = t >> 6, c = t & 63;
    int h = K >> 5, k = K & 31;
    Wl[t] = LD(W4, k * 256 + h * 64 + c, f);
  }
  {
    const float4* ag4 = (const float4*)(agg + (size_t)R0 * 128);
    for (int t = tid; t < 2048; t += 256) {
      int r = t >> 5, k4 = (t & 31) << 2;
      float4 v = ag4[t];
      *(float4*)&Al[r][k4] = v;
    }
  }
  if (tid < 256) { Ql[tid] = wqv[tid]; Kl[tid] = wkv[tid]; }
  __syncthreads();
  int c0 = (tid & 15) << 2, r0 = (tid >> 4) << 2;
  float acc[4][4];
#pragma unroll
  for (int j = 0; j < 4; ++j)
#pragma unroll
    for (int i = 0; i < 4; ++i) acc[j][i] = 0.f;
#pragma unroll 4
  for (int K = 0; K < 128; ++K) {
    float4 wv = *(const float4*)&Wl[K * 64 + c0];
    float a0 = Al[r0][K], a1 = Al[r0 + 1][K], a2 = Al[r0 + 2][K], a3 = Al[r0 + 3][K];
    acc[0][0] += a0 * wv.x; acc[0][1] += a0 * wv.y; acc[0][2] += a0 * wv.z; acc[0][3] += a0 * wv.w;
    acc[1][0] += a1 * wv.x; acc[1][1] += a1 * wv.y; acc[1][2] += a1 * wv.z; acc[1][3] += a1 * wv.w;
    acc[2][0] += a2 * wv.x; acc[2][1] += a2 * wv.y; acc[2][2] += a2 * wv.z; acc[2][3] += a2 * wv.w;
    acc[3][0] += a3 * wv.x; acc[3][1] += a3 * wv.y; acc[3][2] += a3 * wv.z; acc[3][3] += a3 * wv.w;
  }
  float bv[4];
#pragma unroll
  for (int i = 0; i < 4; ++i) bv[i] = LD(b4, c0 + i, f);
  float o[4][4];
#pragma unroll
  for (int j = 0; j < 4; ++j)
#pragma unroll
    for (int i = 0; i < 4; ++i) o[j][i] = lrelu(0.25f * acc[j][i] + bv[i], 0.01f);
  int nbase = R0 - NV + r0;
#pragma unroll
  for (int j = 0; j < 4; ++j) {
#pragma unroll
    for (int h = 0; h < 4; ++h) {
      float pq = o[j][0] * Ql[h * 64 + c0] + o[j][1] * Ql[h * 64 + c0 + 1] +
                 o[j][2] * Ql[h * 64 + c0 + 2] + o[j][3] * Ql[h * 64 + c0 + 3];
      float pk = o[j][0] * Kl[h * 64 + c0] + o[j][1] * Kl[h * 64 + c0 + 1] +
                 o[j][2] * Kl[h * 64 + c0 + 2] + o[j][3] * Kl[h * 64 + c0 + 3];
#pragma unroll
      for (int off = 1; off < 16; off <<= 1) {
        pq += __shfl_xor(pq, off);
        pk += __shfl_xor(pk, off);
      }
      if ((tid & 15) == 0) {
        qs[(size_t)(nbase + j) * 4 + h] = pq;
        ks[(size_t)(nbase + j) * 4 + h] = pk;
      }
    }
  }
}

__global__ void k_groups(const int* full, const void* mask, const int* tgt, const int* mult,
                         const float* qs, const float* ks, const void* att_b, void* outv,
                         const int* flg) {
  int f = flg[0], mbyte = flg[1];
  int g = blockIdx.x;
  int lane = threadIdx.x;
  int k = lane >> 2, h = lane & 3;
  int t = tgt[g];
  int idx = full[g * KK + k];
  int mk = MK(mask, g * KK + k, mbyte);
  float bh = LD(att_b, h, f);
  float qt = qs[t * 4 + h];
  float sc = sigm(qt + ks[idx * 4 + h] + bh);
  int is_tgt = (idx == t) && mk;
  int nbr = mk && !is_tgt;
  unsigned long long bal = __ballot(nbr != 0);
  int degm1 = (int)(__popcll(bal) >> 2);
  float ssum = nbr ? sc : 0.f;
  for (int off = 4; off < 64; off <<= 1) ssum += __shfl_xor(ssum, off);
  ssum /= (float)(degm1 > 1 ? degm1 : 1);
  float trg = sigm(qt + ks[t * 4 + h] + bh);
  float mxv = fmaxf(ssum, trg);
  float e0 = expf(ssum - mxv), e1 = expf(trg - mxv);
  float tw0 = e0 / (e0 + e1), tw1 = e1 / (e0 + e1);
  float msc = nbr ? sc : -1e30f;
  float m = msc;
  for (int off = 4; off < 64; off <<= 1) m = fmaxf(m, __shfl_xor(m, off));
  float ex = expf(msc - m);
  float den = ex;
  for (int off = 4; off < 64; off <<= 1) den += __shfl_xor(den, off);
  float w = ex / den * tw0 * (float)mult[g];
  float res = is_tgt ? tw1 : (nbr ? w : 0.f);
  if (degm1 == 0) res = 0.f;
  ST(outv, g * 64 + k * 4 + h, f, res);
}

extern "C" void kernel_launch(void* const* d_in, const int* in_sizes, int n_in,
                              void* d_out, int out_size, void* d_ws, size_t ws_size,
                              hipStream_t stream) {
  const int* edge = (const int*)d_in[0];
  const int* esrc = edge;
  const int* edst = edge + EE;
  const int* vn_colors = (const int*)d_in[1];
  const int* group_full = (const int*)d_in[2];
  const void* group_mask = d_in[3];
  const int* group_tgt = (const int*)d_in[4];
  const int* group_mult = (const int*)d_in[5];
  const void* vn_prefix = d_in[6];
  const void* fn_embed = d_in[7];
  const void* v2f_msgs = d_in[8];
  const void* v2f_hidden = d_in[9];
  const void* f2v_msgs = d_in[10];
  const void* f2v_hidden = d_in[11];
  const void* msg_prefix = d_in[12];
  const void* emb = d_in[13];
  const void* gv_wih = d_in[14];
  const void* gv_whh = d_in[15];
  const void* gv_bih = d_in[16];
  const void* gv_bhh = d_in[17];
  const void* gf_wih = d_in[18];
  const void* gf_whh = d_in[19];
  const void* gf_bih = d_in[20];
  const void* gf_bhh = d_in[21];
  const void* W1 = d_in[22];
  const void* a1s = d_in[23];
  const void* a1d = d_in[24];
  const void* b1 = d_in[25];
  const void* W2 = d_in[26];
  const void* a2s = d_in[27];
  const void* a2d = d_in[28];
  const void* b2 = d_in[29];
  const void* W3 = d_in[30];
  const void* a3s = d_in[31];
  const void* a3d = d_in[32];
  const void* b3 = d_in[33];
  const void* W4 = d_in[34];
  const void* a4s = d_in[35];
  const void* a4d = d_in[36];
  const void* b4 = d_in[37];
  const void* att_wq = d_in[38];
  const void* att_wk = d_in[39];
  const void* att_ws = d_in[40];
  const void* att_b = d_in[41];

  char* w = (char*)d_ws;
  size_t off = 0;
  auto carve = [&](size_t bytes) -> void* {
    void* p = w + off;
    off += (bytes + 255) & ~(size_t)255;
    return p;
  };
  int* flags = (int*)carve(16);
  float* Wt = (float*)carve((size_t)2 * 77 * 192 * 4);
  float* hidcat = (float*)carve((size_t)2 * NM * EMB * 4);
  float* xB = (float*)carve((size_t)NN * 64 * 4);
  float* scr = (float*)carve((size_t)NN * 128 * 4);
  float* a_sA = (float*)carve((size_t)NN * 4 * 4);
  float* a_dA = (float*)carve((size_t)NN * 4 * 4);
  float* a_sB = (float*)carve((size_t)NN * 4 * 4);
  float* a_dB = (float*)carve((size_t)NN * 4 * 4);
  int* deg = (int*)carve((size_t)2 * NN * 4);  // deg + cnt adjacent, zeroed in k_precomp
  int* cnt = deg + NN;
  int* rowptr = (int*)carve((size_t)(NN + 1) * 4);
  int* bsum = (int*)carve(128 * 4);
  int* col = (int*)carve((size_t)EE * 4);
  float* qs = (float*)carve((size_t)NF * 4 * 4);
  float* ks = (float*)carve((size_t)NF * 4 * 4);
  float* wqv = (float*)carve(256 * 4);
  float* wkv = (float*)carve(256 * 4);
  float* waS = (float*)carve(128 * 4);
  float* waD = (float*)carve(128 * 4);

  k_detect<<<1, 64, 0, stream>>>(fn_embed, group_mask, flags);
  k_precomp<<<118 + (2 * NN + 255) / 256, 256, 0, stream>>>(
      gv_wih, gv_whh, gf_wih, gf_whh, W4, a4s, a4d,
      att_wq, att_wk, att_ws, Wt, waS, waD, wqv, wkv, deg, flags);
  k_gru2<<<768, 256, 0, stream>>>(v2f_msgs, v2f_hidden, f2v_msgs, f2v_hidden,
                                  gv_bih, gv_bhh, gf_bih, gf_bhh, Wt, hidcat, d_out, flags);
  k_deg<<<EE / 256, 256, 0, stream>>>(edst, deg);
  k_scan1<<<72, 512, 0, stream>>>(deg, rowptr, bsum);
  k_scan23<<<1, 512, 0, stream>>>(rowptr, bsum, 72);
  k_fill<<<EE / 256, 256, 0, stream>>>(esrc, edst, rowptr, cnt, col);

  // L1: assemble + x@W1 + coef1 -> xl1 in scr, coefs in A
  k_xl1<<<NN / 8, 256, 0, stream>>>(vn_prefix, vn_colors, emb, fn_embed, msg_prefix,
                                    hidcat, W1, a1s, a1d, scr, a_sA, a_dA, flags);
  // gather L1 (+xl2+coef2): scr,A -> xB,B
  k_gather13<0><<<NN / 16, 256, 0, stream>>>(rowptr, col, a_sA, a_dA, scr, b1,
                                             W2, a2s, a2d, nullptr, nullptr,
                                             xB, nullptr, a_sB, a_dB, flags);
  // gather L2 (+xl3+coef3): xB,B -> scr,A
  k_gather13<0><<<NN / 16, 256, 0, stream>>>(rowptr, col, a_sB, a_dB, xB, b2,
                                             W3, a3s, a3d, nullptr, nullptr,
                                             scr, nullptr, a_sA, a_dA, flags);
  // gather L3 (+act out + coef4): scr,A -> xB (act), B (coef4)
  k_gather13<1><<<NN / 16, 256, 0, stream>>>(rowptr, col, a_sA, a_dA, scr, b3,
                                             nullptr, nullptr, nullptr, waS, waD,
                                             nullptr, xB, a_sB, a_dB, flags);
  // L4 (only fn rows): gather4 -> agg in scr; l4_out + fused qk -> qs/ks
  k_gather4<<<NF / 16, 256, 0, stream>>>(rowptr, col, a_sB, a_dB, xB, scr);
  k_l4_out<<<NF / 64, 256, 0, stream>>>(scr, W4, b4, wqv, wkv, qs, ks, flags);

  k_groups<<<GG, 64, 0, stream>>>(group_full, group_mask, group_tgt, group_mult,
                                  qs, ks, att_b, d_out, flags);
}